// Round 12
// baseline (987.472 us; speedup 1.0000x reference)
//
#include <hip/hip_runtime.h>
#include <hip/hip_bf16.h>

// Dims
#define BB 256
#define LL 128
#define AA 39
#define BDD 10
#define KK 6
#define MM 256
#define FP 256
#define RR 3
#define TT 2

using short8  = __attribute__((ext_vector_type(8))) short;
using short4v = __attribute__((ext_vector_type(4))) short;
using f32x4   = __attribute__((ext_vector_type(4))) float;
using f32x2   = __attribute__((ext_vector_type(2))) float;

__device__ __forceinline__ short f2bf(float f) {
    union { float f; unsigned u; } v; v.f = f;
    unsigned u = v.u;
    u += 0x7fffu + ((u >> 16) & 1u);   // round-to-nearest-even
    return (short)(u >> 16);
}
__device__ __forceinline__ float bf2f(short s) {
    union { unsigned u; float f; } v; v.u = ((unsigned)(unsigned short)s) << 16;
    return v.f;
}
__device__ __forceinline__ float wred64(float v) {
#pragma unroll
    for (int off = 32; off >= 1; off >>= 1) v += __shfl_xor(v, off);
    return v;
}

#define GLL(gp, lp) __builtin_amdgcn_global_load_lds( \
    (const __attribute__((address_space(1))) void*)(gp), \
    (__attribute__((address_space(3))) void*)(lp), 16, 0, 0)

// ---------------- transpose ----------------
__global__ __launch_bounds__(256) void k_transpose(const float* __restrict__ src,
                                                   float* __restrict__ dst, int O, int I) {
    int idx = blockIdx.x * 256 + threadIdx.x;
    if (idx >= O * I) return;
    int o = idx / I, i = idx - o * I;
    dst[i * O + o] = src[idx];
}

// ---------------- pack GRU weights: [d][mat][ks(8)][nt(48)][lane][8] ----------------
__global__ __launch_bounds__(256) void k_prep_gruw(const float* __restrict__ gwih,
                                                   const float* __restrict__ gwhh,
                                                   short* __restrict__ out) {
    int idx = blockIdx.x * 256 + threadIdx.x;
    if (idx >= RR * 2 * 8 * 48 * 512) return;
    int j = idx & 7;
    int lane = (idx >> 3) & 63;
    int blk = idx >> 9;
    int nt = blk % 48;
    int ks = (blk / 48) % 8;
    int mat = (blk / (48 * 8)) % 2;
    int d = blk / (48 * 8 * 2);
    int n = nt * 16 + (lane & 15);
    int k = ks * 32 + (lane >> 4) * 8 + j;
    const float* W = mat ? gwhh : gwih;
    out[idx] = f2bf(W[((size_t)d * 768 + n) * FP + k]);
}

// ---------------- pack attend weights: [d][ks(8)][nt(16)][lane][8] ----------------
__global__ __launch_bounds__(256) void k_prep_waf(const float* __restrict__ atW,
                                                  short* __restrict__ out) {
    int idx = blockIdx.x * 256 + threadIdx.x;
    if (idx >= RR * 8 * 16 * 512) return;
    int j = idx & 7;
    int lane = (idx >> 3) & 63;
    int blk = idx >> 9;
    int nt = blk % 16;
    int ks = (blk / 16) % 8;
    int d = blk / 128;
    int n = nt * 16 + (lane & 15);
    int k = ks * 32 + (lane >> 4) * 8 + j;
    out[idx] = f2bf(atW[(size_t)d * FP * FP + (size_t)n * FP + k]);
}

// ---------------- pack mol GRU weights transposed bf16 ----------------
__global__ __launch_bounds__(256) void k_prep_molw(const float* __restrict__ mih,
                                                   const float* __restrict__ mhh,
                                                   short* __restrict__ outih,
                                                   short* __restrict__ outhh) {
    int idx = blockIdx.x * 256 + threadIdx.x;
    if (idx >= FP * 768) return;
    int i = idx / 768, n = idx % 768;
    outih[idx] = f2bf(mih[(size_t)n * FP + i]);
    outhh[idx] = f2bf(mhh[(size_t)n * FP + i]);
}

// ---------------- fused atom fc + neighbor-fc atom part ----------------
__global__ __launch_bounds__(256) void k_atom_pre(const float* __restrict__ atom_list,
                                                  const float* __restrict__ WafcT,
                                                  const float* __restrict__ afc_b,
                                                  const float* __restrict__ WnT,
                                                  const float* __restrict__ bn,
                                                  float* __restrict__ out_pre,
                                                  short* __restrict__ hb16,
                                                  short* __restrict__ ApreB) {
    int g0 = blockIdx.x * 8;
    int t = threadIdx.x;
    __shared__ float x[8][AA];
    for (int i = t; i < 8 * AA; i += 256) x[i / AA][i % AA] = atom_list[(size_t)g0 * AA + i];
    __syncthreads();
    float a1[8], a2[8];
    float b1 = afc_b[t], b2 = bn[t];
#pragma unroll
    for (int a = 0; a < 8; ++a) { a1[a] = b1; a2[a] = b2; }
    for (int i = 0; i < AA; ++i) {
        float w1 = WafcT[i * FP + t];
        float w2 = WnT[i * FP + t];
#pragma unroll
        for (int a = 0; a < 8; ++a) { a1[a] += x[a][i] * w1; a2[a] += x[a][i] * w2; }
    }
#pragma unroll
    for (int a = 0; a < 8; ++a) {
        size_t idx = (size_t)(g0 + a) * FP + t;
        out_pre[idx] = a1[a];
        hb16[idx] = f2bf(fmaxf(a1[a], 0.f));    // h0 = relu(pre)
        ApreB[idx] = f2bf(a2[a]);
    }
}

// ---------------- d0 attention (bond terms) -> wn(XB), sumaw(SW), awv(O2 d0) ----
template<int IS_D0>
__global__ __launch_bounds__(512) void k_awn2(
        const short* __restrict__ ACTB,
        const short* __restrict__ SRC,
        const float* __restrict__ bond_list,
        const int* __restrict__ adeg, const int* __restrict__ bdeg,
        const float* __restrict__ WnT,
        const float* __restrict__ alignW, const float* __restrict__ alignBp,
        short* __restrict__ wn_out, float* __restrict__ sw_out,
        float* __restrict__ awv_out) {
    __shared__ short snb[LL * FP];          // 64 KB
    const int b = blockIdx.x >> 1;
    const int half = blockIdx.x & 1;
    const int t = threadIdx.x;
    const int wave = t >> 6, lane = t & 63;

    {
        const char* src = (const char*)(SRC + (size_t)b * LL * FP);
#pragma unroll
        for (int it = 0; it < 8; ++it) {
            int off = it * 8192 + wave * 1024 + lane * 16;
            GLL(src + off, (char*)snb + it * 8192 + wave * 1024);
        }
    }

    f32x4 w0 = *(const f32x4*)(alignW + lane * 4);
    f32x4 w1 = *(const f32x4*)(alignW + FP + lane * 4);
    float bias = alignBp[0];

    float wnt[IS_D0 ? BDD : 1][4];
    if constexpr (IS_D0) {
#pragma unroll
        for (int i = 0; i < BDD; ++i) {
            f32x4 v = *(const f32x4*)(WnT + (AA + i) * FP + lane * 4);
#pragma unroll
            for (int q = 0; q < 4; ++q) wnt[i][q] = v[q];
        }
    }

    __syncthreads();

#pragma unroll
    for (int ai = 0; ai < 8; ++ai) {
        const int al = half * 64 + wave * 8 + ai;
        const int ga = b * LL + al;

        short4v sv = *(const short4v*)(ACTB + (size_t)ga * FP + lane * 4);
        float ss = wred64(bf2f(sv[0]) * w0[0] + bf2f(sv[1]) * w0[1] +
                          bf2f(sv[2]) * w0[2] + bf2f(sv[3]) * w0[3]);

        int jx[KK];
#pragma unroll
        for (int k = 0; k < KK; ++k) jx[k] = adeg[ga * KK + k];

        float nf[KK][4];
        float sc[KK];
#pragma unroll
        for (int k = 0; k < KK; ++k) {
            short4v nv = *(const short4v*)(snb + jx[k] * FP + lane * 4);
            float f0 = bf2f(nv[0]), f1 = bf2f(nv[1]), f2 = bf2f(nv[2]), f3 = bf2f(nv[3]);
            if constexpr (IS_D0) {
                int bi = bdeg[ga * KK + k];
                const float* bp = bond_list + ((size_t)b * MM + bi) * BDD;
                float bb[BDD];
#pragma unroll
                for (int i = 0; i < 5; ++i) {
                    f32x2 v2 = *(const f32x2*)(bp + 2 * i);
                    bb[2 * i] = v2[0]; bb[2 * i + 1] = v2[1];
                }
                float b0 = 0.f, b1 = 0.f, b2 = 0.f, b3 = 0.f;
#pragma unroll
                for (int i = 0; i < BDD; ++i) {
                    b0 += bb[i] * wnt[i][0]; b1 += bb[i] * wnt[i][1];
                    b2 += bb[i] * wnt[i][2]; b3 += bb[i] * wnt[i][3];
                }
                f0 = fmaxf(f0 + b0, 0.f); f1 = fmaxf(f1 + b1, 0.f);
                f2 = fmaxf(f2 + b2, 0.f); f3 = fmaxf(f3 + b3, 0.f);
            }
            nf[k][0] = f0; nf[k][1] = f1; nf[k][2] = f2; nf[k][3] = f3;
            float s2 = wred64(f0 * w1[0] + f1 * w1[1] + f2 * w1[2] + f3 * w1[3]);
            float s = fmaxf(ss + s2 + bias, 0.f);
            if (jx[k] == LL - 1) s -= 9.0f;
            sc[k] = s;
        }

        float m = sc[0];
#pragma unroll
        for (int k = 1; k < KK; ++k) m = fmaxf(m, sc[k]);
        float e[KK], den = 0.f;
#pragma unroll
        for (int k = 0; k < KK; ++k) { e[k] = expf(sc[k] - m); den += e[k]; }
        float aw[KK], sumaw = 0.f;
#pragma unroll
        for (int k = 0; k < KK; ++k) {
            aw[k] = (jx[k] == LL - 1) ? 0.f : e[k] / den;
            sumaw += aw[k];
        }
        if (lane < KK) {
            float av = aw[0];
#pragma unroll
            for (int k = 1; k < KK; ++k) if (lane == k) av = aw[k];
            awv_out[(size_t)ga * KK + lane] = av;
        }
        if (lane == 0) sw_out[ga] = sumaw;

        short4v wo;
#pragma unroll
        for (int q = 0; q < 4; ++q) {
            float w = 0.f;
#pragma unroll
            for (int k = 0; k < KK; ++k) w += aw[k] * nf[k][q];
            wo[q] = f2bf(w);
        }
        *(short4v*)(wn_out + (size_t)ga * FP + lane * 4) = wo;
    }
}

// ================= MEGA: per-molecule fused rounds (ctx+GRU d0; full d1,d2) ======
// 256 blocks x 512 thr, 1 block/CU. hS = h slab (bf16, swizzled); cS = wn/ctx.
__global__ __launch_bounds__(512) void k_mp(
        const short* __restrict__ HB0,     // h0 bf16
        const short* __restrict__ XB0,     // wn d0 bf16
        const float* __restrict__ SW0,     // sumaw d0
        const int* __restrict__ adeg,
        const float* __restrict__ alW, const float* __restrict__ alb,
        const short* __restrict__ WaF, const float* __restrict__ atb,
        const short* __restrict__ GW,
        const float* __restrict__ gbih, const float* __restrict__ gbhh,
        float* __restrict__ O1,            // afv base (writes slots 1..3)
        float* __restrict__ O2,            // awv base (writes d=1,2)
        float* __restrict__ O0) {          // final h fp32
    __shared__ __align__(16) short hS[32768];     // 64 KB
    __shared__ __align__(16) short cS[32768];     // 64 KB
    __shared__ __align__(16) short bS[2][6144];   // 2 x 12 KB
    __shared__ int   jxS[LL * KK];                // 3 KB
    __shared__ float awS[LL * KK];                // 3 KB
    __shared__ float swS[LL];                     // 0.5 KB

    const int b = blockIdx.x;
    const int t = threadIdx.x;
    const int wave = t >> 6, lane = t & 63;
    const int lr = lane & 15, lk = lane >> 4;
    const int kofs = b & 7;

#define SLAB_OFF(r, cb) ((((r) * 512 + (cb))) ^ ((((r) & 7)) << 4))
#define H8R(r, c)  (*(const short8*)((const char*)hS + SLAB_OFF(r, (c) * 2)))
#define C8R(r, c)  (*(const short8*)((const char*)cS + SLAB_OFF(r, (c) * 2)))
#define H4R(r, c)  (*(const short4v*)((const char*)hS + SLAB_OFF(r, (c) * 2)))
#define CW4(r, c, v) (*(short4v*)((char*)cS + SLAB_OFF(r, (c) * 2)) = (v))
#define CW1(r, c, v) (*(short*)((char*)cS + SLAB_OFF(r, (c) * 2)) = (v))
#define HW1(r, c, v) (*(short*)((char*)hS + SLAB_OFF(r, (c) * 2)) = (v))
#define H1R(r, c)  (*(const short*)((const char*)hS + SLAB_OFF(r, (c) * 2)))

    // prologue: stage h0 -> hS, wn_d0 -> cS (pre-swizzled source, linear dest)
    {
        const char* hsrc = (const char*)(HB0 + (size_t)b * LL * FP);
        const char* xsrc = (const char*)(XB0 + (size_t)b * LL * FP);
#pragma unroll
        for (int it = 0; it < 8; ++it) {
            int off = it * 8192 + wave * 1024 + lane * 16;
            int src = off ^ (((off >> 9) & 7) << 4);
            GLL(hsrc + src, (char*)hS + off);
            GLL(xsrc + src, (char*)cS + off);
        }
        for (int i = t; i < LL * KK; i += 512) jxS[i] = adeg[b * LL * KK + i];
        if (t < LL) swS[t] = SW0[b * LL + t];
    }
    __syncthreads();

    for (int d = 0; d < RR; ++d) {
        if (d > 0) {
            // ---- scores pass: wave handles atoms wave*16..+15 ----
            f32x4 w0 = *(const f32x4*)(alW + (size_t)d * 2 * FP + lane * 4);
            f32x4 w1 = *(const f32x4*)(alW + (size_t)d * 2 * FP + FP + lane * 4);
            float bias = alb[d];
            for (int ai = 0; ai < 16; ++ai) {
                int a = wave * 16 + ai;
                short4v sv = H4R(a, lane * 4);
                float ss = wred64(fmaxf(bf2f(sv[0]), 0.f) * w0[0] + fmaxf(bf2f(sv[1]), 0.f) * w0[1] +
                                  fmaxf(bf2f(sv[2]), 0.f) * w0[2] + fmaxf(bf2f(sv[3]), 0.f) * w0[3]);
                float sc[KK]; int jx[KK];
#pragma unroll
                for (int k = 0; k < KK; ++k) {
                    int j = jxS[a * KK + k]; jx[k] = j;
                    short4v nv = H4R(j, lane * 4);
                    float s2 = wred64(fmaxf(bf2f(nv[0]), 0.f) * w1[0] + fmaxf(bf2f(nv[1]), 0.f) * w1[1] +
                                      fmaxf(bf2f(nv[2]), 0.f) * w1[2] + fmaxf(bf2f(nv[3]), 0.f) * w1[3]);
                    float s = fmaxf(ss + s2 + bias, 0.f);
                    if (j == LL - 1) s -= 9.0f;
                    sc[k] = s;
                }
                float m = sc[0];
#pragma unroll
                for (int k = 1; k < KK; ++k) m = fmaxf(m, sc[k]);
                float e[KK], den = 0.f;
#pragma unroll
                for (int k = 0; k < KK; ++k) { e[k] = expf(sc[k] - m); den += e[k]; }
                float aw[KK], sumaw = 0.f;
#pragma unroll
                for (int k = 0; k < KK; ++k) {
                    aw[k] = (jx[k] == LL - 1) ? 0.f : e[k] / den;
                    sumaw += aw[k];
                }
                if (lane < KK) {
                    float av = aw[0];
#pragma unroll
                    for (int k = 1; k < KK; ++k) if (lane == k) av = aw[k];
                    awS[a * KK + lane] = av;
                    O2[(size_t)d * (BB * LL * KK) + ((size_t)b * LL + a) * KK + lane] = av;
                }
                if (lane == 0) swS[a] = sumaw;
            }
            __syncthreads();
            // ---- wn pass: write weighted neighbor sums into cS ----
            for (int ai = 0; ai < 16; ++ai) {
                int a = wave * 16 + ai;
                float a0 = 0.f, a1 = 0.f, a2 = 0.f, a3 = 0.f;
#pragma unroll
                for (int k = 0; k < KK; ++k) {
                    float awv = awS[a * KK + k];
                    short4v nv = H4R(jxS[a * KK + k], lane * 4);
                    a0 += awv * fmaxf(bf2f(nv[0]), 0.f);
                    a1 += awv * fmaxf(bf2f(nv[1]), 0.f);
                    a2 += awv * fmaxf(bf2f(nv[2]), 0.f);
                    a3 += awv * fmaxf(bf2f(nv[3]), 0.f);
                }
                short4v wo; wo[0] = f2bf(a0); wo[1] = f2bf(a1); wo[2] = f2bf(a2); wo[3] = f2bf(a3);
                CW4(a, lane * 4, wo);
            }
            __syncthreads();
        }

        // ---- ctx GEMM: cS(wn) @ Wa^T + sumaw*ab -> relu -> cS in-place ----
        {
            const int rg = wave >> 1, csl = wave & 1;
            f32x4 acc[2][8] = {};
            const short8* wb = (const short8*)(WaF + (size_t)d * 8 * 16 * 512);
            for (int ks = 0; ks < 8; ++ks) {
                short8 a0 = C8R(rg * 32 + lr, ks * 32 + lk * 8);
                short8 a1 = C8R(rg * 32 + 16 + lr, ks * 32 + lk * 8);
#pragma unroll
                for (int nt2 = 0; nt2 < 8; ++nt2) {
                    short8 bf = wb[(size_t)(ks * 16 + csl * 8 + nt2) * 64 + lane];
                    acc[0][nt2] = __builtin_amdgcn_mfma_f32_16x16x32_bf16(a0, bf, acc[0][nt2], 0, 0, 0);
                    acc[1][nt2] = __builtin_amdgcn_mfma_f32_16x16x32_bf16(a1, bf, acc[1][nt2], 0, 0, 0);
                }
            }
            __syncthreads();   // all cS reads done before in-place overwrite
#pragma unroll
            for (int rt = 0; rt < 2; ++rt)
#pragma unroll
            for (int nt2 = 0; nt2 < 8; ++nt2) {
                int col = csl * 128 + nt2 * 16 + lr;
                float abv = atb[d * FP + col];
#pragma unroll
                for (int q = 0; q < 4; ++q) {
                    int row = rg * 32 + rt * 16 + lk * 4 + q;
                    float v = acc[rt][nt2][q] + swS[row] * abv;
                    CW1(row, col, f2bf(fmaxf(v, 0.f)));
                }
            }
            __syncthreads();
        }

        // ---- GRU: two 64-atom sub-batches ----
        const short* Bih = GW + (size_t)(d * 2 + 0) * (8 * 48 * 512);
        const short* Bhh = GW + (size_t)(d * 2 + 1) * (8 * 48 * 512);
        const int rh = wave >> 2, wn = wave & 3;
        float* afv_d = O1 + (size_t)(d + 1) * ((size_t)BB * LL * FP);

#define GSTAGE(p) do { \
        const int sub_ = (p) & 3, mat_ = ((p) >> 2) & 1, ks_ = ((((p) >> 3)) + kofs) & 7; \
        const short* base_ = (mat_ ? Bhh : Bih) + (size_t)ks_ * (48 * 512); \
        { const int f_ = wave; const int nt_ = (f_ >> 2) * 16 + (f_ & 3) * 4 + sub_; \
          GLL(base_ + (size_t)nt_ * 512 + lane * 8, &bS[(p) & 1][f_ * 512]); } \
        if (wave < 4) { const int f_ = wave + 8; const int nt_ = (f_ >> 2) * 16 + (f_ & 3) * 4 + sub_; \
          GLL(base_ + (size_t)nt_ * 512 + lane * 8, &bS[(p) & 1][f_ * 512]); } \
    } while (0)

        for (int sb = 0; sb < 2; ++sb) {
            f32x4 acc_rz[2][8] = {};
            f32x4 acc_in[2][4] = {};
            f32x4 acc_hn[2][4] = {};
            short8 ax0{}, ah0{}, ax1{}, ah1{};
            GSTAGE(0);
#pragma unroll
            for (int p = 0; p < 64; ++p) {
                __syncthreads();                 // bS[p&1] staged; prev reads of other buf done
                if (p < 63) GSTAGE(p + 1);
                const int sub = p & 3;
                const int mat = (p >> 2) & 1;
                if ((p & 7) == 0) {
                    int ks = ((p >> 3) + kofs) & 7;
                    int c = ks * 32 + lk * 8;
                    ax0 = C8R(sb * 64 + rh * 32 + lr, c);
                    ah0 = H8R(sb * 64 + rh * 32 + lr, c);
                    ax1 = C8R(sb * 64 + rh * 32 + 16 + lr, c);
                    ah1 = H8R(sb * 64 + rh * 32 + 16 + lr, c);
                }
#pragma unroll
                for (int rg = 0; rg < 2; ++rg) {
                    const short8 a8 = mat ? (rg ? ah1 : ah0) : (rg ? ax1 : ax0);
#pragma unroll
                    for (int g = 0; g < 3; ++g) {
                        const int f = g * 4 + wn;
                        short8 bf = *(const short8*)(&bS[p & 1][f * 512 + lane * 8]);
                        if (g < 2)
                            acc_rz[rg][g * 4 + sub] = __builtin_amdgcn_mfma_f32_16x16x32_bf16(a8, bf, acc_rz[rg][g * 4 + sub], 0, 0, 0);
                        else if (mat)
                            acc_hn[rg][sub] = __builtin_amdgcn_mfma_f32_16x16x32_bf16(a8, bf, acc_hn[rg][sub], 0, 0, 0);
                        else
                            acc_in[rg][sub] = __builtin_amdgcn_mfma_f32_16x16x32_bf16(a8, bf, acc_in[rg][sub], 0, 0, 0);
                    }
                }
            }
            // epilogue: this sub-batch's rows only (disjoint from other waves/sub)
#pragma unroll
            for (int sub = 0; sub < 4; ++sub) {
                int c = wn * 64 + sub * 16 + lr;
                float brz_r = gbih[d * 768 + c] + gbhh[d * 768 + c];
                float brz_z = gbih[d * 768 + FP + c] + gbhh[d * 768 + FP + c];
                float bin_ = gbih[d * 768 + 2 * FP + c];
                float bhn = gbhh[d * 768 + 2 * FP + c];
#pragma unroll
                for (int rg = 0; rg < 2; ++rg)
#pragma unroll
                for (int q = 0; q < 4; ++q) {
                    int row = sb * 64 + rh * 32 + rg * 16 + lk * 4 + q;
                    float hold = bf2f(H1R(row, c));
                    float r = 1.f / (1.f + expf(-(acc_rz[rg][0 * 4 + sub][q] + brz_r)));
                    float z = 1.f / (1.f + expf(-(acc_rz[rg][1 * 4 + sub][q] + brz_z)));
                    float n = tanhf(acc_in[rg][sub][q] + bin_ + r * (acc_hn[rg][sub][q] + bhn));
                    float hn = (1.f - z) * n + z * hold;
                    size_t gidx = ((size_t)(b * LL) + row) * FP + c;
                    afv_d[gidx] = fmaxf(hn, 0.f);
                    if (d == RR - 1) O0[gidx] = hn;
                    HW1(row, c, f2bf(hn));
                }
            }
        }
#undef GSTAGE
        __syncthreads();   // hS updates visible before next round's gathers
    }
#undef SLAB_OFF
#undef H8R
#undef C8R
#undef H4R
#undef CW4
#undef CW1
#undef HW1
#undef H1R
}

// ---------------- mol reductions ----------------
__global__ __launch_bounds__(256) void k_mol_reduce(const float* __restrict__ hbuf,
                                                    const float* __restrict__ act,
                                                    const float* __restrict__ mask,
                                                    float* __restrict__ o_unb0,
                                                    float* __restrict__ o_mfv0,
                                                    float* __restrict__ molF) {
    int b = blockIdx.x, t = threadIdx.x;
    float s1 = 0.f, s2 = 0.f;
    for (int l = 0; l < LL; ++l) {
        float mk = mask[b * LL + l];
        s1 += hbuf[((size_t)b * LL + l) * FP + t] * mk;
        s2 += act[((size_t)b * LL + l) * FP + t] * mk;
    }
    o_unb0[b * FP + t] = s1;
    o_mfv0[b * FP + t] = s2;
    molF[b * FP + t] = s2;
}

// ---------------- AV = act @ mol_attend_W.T + b ----------------
__global__ __launch_bounds__(256) void k_av(const float* __restrict__ act,
                                            const float* __restrict__ MWaT,
                                            const float* __restrict__ mab,
                                            float* __restrict__ AV) {
    int g0 = blockIdx.x * 8;
    int t = threadIdx.x;
    __shared__ float xs[8][FP];
    for (int a = 0; a < 8; ++a) xs[a][t] = act[(size_t)(g0 + a) * FP + t];
    __syncthreads();
    float acc[8];
    float bb2 = mab[t];
#pragma unroll
    for (int a = 0; a < 8; ++a) acc[a] = bb2;
    for (int i = 0; i < FP; ++i) {
        float w = MWaT[i * FP + t];
#pragma unroll
        for (int a = 0; a < 8; ++a) acc[a] += xs[a][i] * w;
    }
    for (int a = 0; a < 8; ++a) AV[(size_t)(g0 + a) * FP + t] = acc[a];
}

// ---------------- mol attention + mol GRU (bf16 weights) ----------------
__global__ __launch_bounds__(256) void k_mol_step(int step,
        const float* __restrict__ act,
        const float* __restrict__ AV,
        float* __restrict__ molF,
        const float* __restrict__ mask,
        const float* __restrict__ mAw, const float* __restrict__ mAb,
        const short* __restrict__ MihB, const short* __restrict__ MhhB,
        const float* __restrict__ mbih, const float* __restrict__ mbhh,
        float* __restrict__ o_mfv, float* __restrict__ o_unb,
        float* __restrict__ o_mawv, float* __restrict__ o_molfeat) {
    int b = blockIdx.x, t = threadIdx.x;
    int wave = t >> 6, lane = t & 63;
    __shared__ float am[FP], hh[FP], cx[FP];
    __shared__ float S2[LL], mw[LL];
    __shared__ float red[4];

    float hprev = molF[b * FP + t];
    hh[t] = hprev;
    am[t] = fmaxf(hprev, 0.f);
    __syncthreads();

    float v = am[t] * mAw[t];
#pragma unroll
    for (int off = 32; off >= 1; off >>= 1) v += __shfl_xor(v, off);
    if (lane == 0) red[wave] = v;
    __syncthreads();
    float s_self = red[0] + red[1] + red[2] + red[3];

    for (int l = wave; l < LL; l += 4) {
        float v2 = 0.f;
#pragma unroll
        for (int q = 0; q < 4; ++q) {
            int i = lane + 64 * q;
            v2 += act[((size_t)b * LL + l) * FP + i] * mAw[FP + i];
        }
#pragma unroll
        for (int off = 32; off >= 1; off >>= 1) v2 += __shfl_xor(v2, off);
        if (lane == 0) S2[l] = v2;
    }
    __syncthreads();

    if (t < LL) {
        float s = fmaxf(s_self + S2[t] + mAb[0], 0.f);
        if (mask[b * LL + t] == 0.f) s += -9e8f;
        S2[t] = s;
    }
    __syncthreads();

    float m = -1e30f;
    for (int l = 0; l < LL; ++l) m = fmaxf(m, S2[l]);
    float den = 0.f;
    for (int l = 0; l < LL; ++l) den += expf(S2[l] - m);
    if (t < LL) {
        float w = expf(S2[t] - m) / den * mask[b * LL + t];
        mw[t] = w;
        o_mawv[(size_t)step * (BB * LL) + b * LL + t] = w;
    }
    __syncthreads();

    float acc = 0.f;
    for (int l = 0; l < LL; ++l) acc += mw[l] * AV[((size_t)b * LL + l) * FP + t];
    cx[t] = fmaxf(acc, 0.f);
    __syncthreads();

    float air = mbih[t], aiz = mbih[FP + t], ain = mbih[2 * FP + t];
    float ahr = mbhh[t], ahz = mbhh[FP + t], ahn = mbhh[2 * FP + t];
    for (int i = 0; i < FP; ++i) {
        float c = cx[i], h = hh[i];
        air += c * bf2f(MihB[i * 768 + t]);
        aiz += c * bf2f(MihB[i * 768 + FP + t]);
        ain += c * bf2f(MihB[i * 768 + 2 * FP + t]);
        ahr += h * bf2f(MhhB[i * 768 + t]);
        ahz += h * bf2f(MhhB[i * 768 + FP + t]);
        ahn += h * bf2f(MhhB[i * 768 + 2 * FP + t]);
    }
    float r = 1.f / (1.f + expf(-(air + ahr)));
    float z = 1.f / (1.f + expf(-(aiz + ahz)));
    float n = tanhf(ain + r * ahn);
    float hn = (1.f - z) * n + z * hprev;

    molF[b * FP + t] = hn;
    o_unb[(size_t)(step + 1) * (BB * FP) + b * FP + t] = hn;
    o_mfv[(size_t)(step + 1) * (BB * FP) + b * FP + t] = fmaxf(hn, 0.f);
    if (step == TT - 1) o_molfeat[b * FP + t] = hn;
}

extern "C" void kernel_launch(void* const* d_in, const int* in_sizes, int n_in,
                              void* d_out, int out_size, void* d_ws, size_t ws_size,
                              hipStream_t stream) {
    const float* atom_list = (const float*)d_in[0];
    const float* bond_list = (const float*)d_in[1];
    const int*   adeg      = (const int*)d_in[2];
    const int*   bdeg      = (const int*)d_in[3];
    const float* amask     = (const float*)d_in[4];
    const float* atom_fc_W = (const float*)d_in[5];
    const float* atom_fc_b = (const float*)d_in[6];
    const float* nfc_W     = (const float*)d_in[7];
    const float* nfc_b     = (const float*)d_in[8];
    const float* gwih      = (const float*)d_in[9];
    const float* gwhh      = (const float*)d_in[10];
    const float* gbih      = (const float*)d_in[11];
    const float* gbhh      = (const float*)d_in[12];
    const float* alW       = (const float*)d_in[13];
    const float* alb       = (const float*)d_in[14];
    const float* atW       = (const float*)d_in[15];
    const float* atb       = (const float*)d_in[16];
    const float* mgwih     = (const float*)d_in[17];
    const float* mgwhh     = (const float*)d_in[18];
    const float* mgbih     = (const float*)d_in[19];
    const float* mgbhh     = (const float*)d_in[20];
    const float* malW      = (const float*)d_in[21];
    const float* malb      = (const float*)d_in[22];
    const float* matW      = (const float*)d_in[23];
    const float* matb      = (const float*)d_in[24];

    const size_t BLF = (size_t)BB * LL * FP;
    float* out = (float*)d_out;
    float* O0 = out;                                 // atom_feature / h (fp32)
    float* O1 = out + BLF;                           // afv (4,B,L,FP)
    float* O2 = O1 + 4 * BLF;                        // awv (3,B,L,K)
    float* O3 = O2 + (size_t)RR * BB * LL * KK;      // mfv
    float* O4 = O3 + (size_t)(TT + 1) * BB * FP;     // mol_unb
    float* O5 = O4 + (size_t)(TT + 1) * BB * FP;     // mawv
    float* O6 = O5 + (size_t)TT * BB * LL;           // mol_feature

    // ws layout
    float* ws = (float*)d_ws;
    short* XB   = (short*)ws;                        // BLF shorts: wn d0 bf16
    short* HBb  = XB + 2 * BLF;                      // BLF shorts: h0 bf16
    float* AV   = ws;                                // aliases XB region (mol phase only)
    float* rest = ws + 2 * BLF;
    short* ApreB = (short*)rest;                     // BLF shorts
    float* SW    = rest + BLF / 2;                   // B*L floats
    float* MOLF  = SW + (size_t)BB * LL;
    float* WafcT = MOLF + (size_t)BB * FP;
    float* WnT   = WafcT + AA * FP;
    float* MWaT  = WnT + (AA + BDD) * FP;
    short* MihB  = (short*)(MWaT + (size_t)FP * FP);
    short* MhhB  = MihB + (size_t)FP * 768;
    short* GW    = MhhB + (size_t)FP * 768;             // RR*2*(8*48*512) shorts
    short* WaF   = GW + (size_t)RR * 2 * 8 * 48 * 512;  // RR*(8*16*512) shorts
    (void)ws_size; (void)in_sizes; (void)n_in; (void)out_size;

    auto tr = [&](const float* src, float* dst, int O, int I) {
        int n = O * I;
        k_transpose<<<(n + 255) / 256, 256, 0, stream>>>(src, dst, O, I);
    };
    tr(atom_fc_W, WafcT, FP, AA);
    tr(nfc_W, WnT, FP, AA + BDD);
    tr(matW, MWaT, FP, FP);

    {
        int n = RR * 2 * 8 * 48 * 512;
        k_prep_gruw<<<(n + 255) / 256, 256, 0, stream>>>(gwih, gwhh, GW);
        int n2 = RR * 8 * 16 * 512;
        k_prep_waf<<<(n2 + 255) / 256, 256, 0, stream>>>(atW, WaF);
        int n3 = FP * 768;
        k_prep_molw<<<(n3 + 255) / 256, 256, 0, stream>>>(mgwih, mgwhh, MihB, MhhB);
    }

    k_atom_pre<<<BB * LL / 8, 256, 0, stream>>>(atom_list, WafcT, atom_fc_b,
                                                WnT, nfc_b, O1, HBb, ApreB);

    // d0 attention (bond terms) -> wn(XB), sumaw(SW), awv(O2[0])
    k_awn2<1><<<BB * 2, 512, 0, stream>>>(HBb, ApreB, bond_list, adeg, bdeg,
            WnT, alW, alb, XB, SW, O2);

    // fused per-molecule rounds: d0 ctx+GRU, d1/d2 full
    k_mp<<<BB, 512, 0, stream>>>(HBb, XB, SW, adeg,
            alW, alb, WaF, atb, GW, gbih, gbhh,
            O1, O2, O0);

    const float* actFin = O1 + (size_t)RR * BLF;
    k_mol_reduce<<<BB, 256, 0, stream>>>(O0, actFin, amask, O4, O3, MOLF);
    k_av<<<BB * LL / 8, 256, 0, stream>>>(actFin, MWaT, matb, AV);
    for (int st = 0; st < TT; ++st) {
        k_mol_step<<<BB, 256, 0, stream>>>(st, actFin, AV, MOLF, amask,
                malW, malb, MihB, MhhB, mgbih, mgbhh,
                O3, O4, O5, O6);
    }
}

// Round 13
// 632.112 us; speedup vs baseline: 1.5622x; 1.5622x over previous
//
#include <hip/hip_runtime.h>
#include <hip/hip_bf16.h>

// Dims
#define BB 256
#define LL 128
#define AA 39
#define BDD 10
#define KK 6
#define MM 256
#define FP 256
#define RR 3
#define TT 2

using short8  = __attribute__((ext_vector_type(8))) short;
using short4v = __attribute__((ext_vector_type(4))) short;
using f32x4   = __attribute__((ext_vector_type(4))) float;
using f32x2   = __attribute__((ext_vector_type(2))) float;

__device__ __forceinline__ short f2bf(float f) {
    union { float f; unsigned u; } v; v.f = f;
    unsigned u = v.u;
    u += 0x7fffu + ((u >> 16) & 1u);   // round-to-nearest-even
    return (short)(u >> 16);
}
__device__ __forceinline__ float bf2f(short s) {
    union { unsigned u; float f; } v; v.u = ((unsigned)(unsigned short)s) << 16;
    return v.f;
}
__device__ __forceinline__ float wred64(float v) {
#pragma unroll
    for (int off = 32; off >= 1; off >>= 1) v += __shfl_xor(v, off);
    return v;
}

#define GLL(gp, lp) __builtin_amdgcn_global_load_lds( \
    (const __attribute__((address_space(1))) void*)(gp), \
    (__attribute__((address_space(3))) void*)(lp), 16, 0, 0)

// ---------------- transpose ----------------
__global__ __launch_bounds__(256) void k_transpose(const float* __restrict__ src,
                                                   float* __restrict__ dst, int O, int I) {
    int idx = blockIdx.x * 256 + threadIdx.x;
    if (idx >= O * I) return;
    int o = idx / I, i = idx - o * I;
    dst[i * O + o] = src[idx];
}

// ---------------- pack GRU weights: [d][mat][ks(8)][nt(48)][lane][8] ----------------
__global__ __launch_bounds__(256) void k_prep_gruw(const float* __restrict__ gwih,
                                                   const float* __restrict__ gwhh,
                                                   short* __restrict__ out) {
    int idx = blockIdx.x * 256 + threadIdx.x;
    if (idx >= RR * 2 * 8 * 48 * 512) return;
    int j = idx & 7;
    int lane = (idx >> 3) & 63;
    int blk = idx >> 9;
    int nt = blk % 48;
    int ks = (blk / 48) % 8;
    int mat = (blk / (48 * 8)) % 2;
    int d = blk / (48 * 8 * 2);
    int n = nt * 16 + (lane & 15);
    int k = ks * 32 + (lane >> 4) * 8 + j;
    const float* W = mat ? gwhh : gwih;
    out[idx] = f2bf(W[((size_t)d * 768 + n) * FP + k]);
}

// ---------------- pack attend weights: [d][ks(8)][nt(16)][lane][8] ----------------
__global__ __launch_bounds__(256) void k_prep_waf(const float* __restrict__ atW,
                                                  short* __restrict__ out) {
    int idx = blockIdx.x * 256 + threadIdx.x;
    if (idx >= RR * 8 * 16 * 512) return;
    int j = idx & 7;
    int lane = (idx >> 3) & 63;
    int blk = idx >> 9;
    int nt = blk % 16;
    int ks = (blk / 16) % 8;
    int d = blk / 128;
    int n = nt * 16 + (lane & 15);
    int k = ks * 32 + (lane >> 4) * 8 + j;
    out[idx] = f2bf(atW[(size_t)d * FP * FP + (size_t)n * FP + k]);
}

// ---------------- pack mol GRU weights transposed bf16 ----------------
__global__ __launch_bounds__(256) void k_prep_molw(const float* __restrict__ mih,
                                                   const float* __restrict__ mhh,
                                                   short* __restrict__ outih,
                                                   short* __restrict__ outhh) {
    int idx = blockIdx.x * 256 + threadIdx.x;
    if (idx >= FP * 768) return;
    int i = idx / 768, n = idx % 768;
    outih[idx] = f2bf(mih[(size_t)n * FP + i]);
    outhh[idx] = f2bf(mhh[(size_t)n * FP + i]);
}

// ---------------- fused atom fc + neighbor-fc atom part ----------------
__global__ __launch_bounds__(256) void k_atom_pre(const float* __restrict__ atom_list,
                                                  const float* __restrict__ WafcT,
                                                  const float* __restrict__ afc_b,
                                                  const float* __restrict__ WnT,
                                                  const float* __restrict__ bn,
                                                  float* __restrict__ out_pre,
                                                  float* __restrict__ hbuf,
                                                  short* __restrict__ hb16,
                                                  short* __restrict__ ApreB) {
    int g0 = blockIdx.x * 8;
    int t = threadIdx.x;
    __shared__ float x[8][AA];
    for (int i = t; i < 8 * AA; i += 256) x[i / AA][i % AA] = atom_list[(size_t)g0 * AA + i];
    __syncthreads();
    float a1[8], a2[8];
    float b1 = afc_b[t], b2 = bn[t];
#pragma unroll
    for (int a = 0; a < 8; ++a) { a1[a] = b1; a2[a] = b2; }
    for (int i = 0; i < AA; ++i) {
        float w1 = WafcT[i * FP + t];
        float w2 = WnT[i * FP + t];
#pragma unroll
        for (int a = 0; a < 8; ++a) { a1[a] += x[a][i] * w1; a2[a] += x[a][i] * w2; }
    }
#pragma unroll
    for (int a = 0; a < 8; ++a) {
        size_t idx = (size_t)(g0 + a) * FP + t;
        out_pre[idx] = a1[a];
        float rl = fmaxf(a1[a], 0.f);
        hbuf[idx] = rl;
        hb16[idx] = f2bf(rl);   // h0 = relu(pre)
        ApreB[idx] = f2bf(a2[a]);
    }
}

// ---------------- d0 attention (bond terms) -> wn(XB), sumaw(SW), awv(O2 d0) ----
__global__ __launch_bounds__(512) void k_awn_d0(
        const short* __restrict__ ACTB,
        const short* __restrict__ SRC,
        const float* __restrict__ bond_list,
        const int* __restrict__ adeg, const int* __restrict__ bdeg,
        const float* __restrict__ WnT,
        const float* __restrict__ alignW, const float* __restrict__ alignBp,
        short* __restrict__ wn_out, float* __restrict__ sw_out,
        float* __restrict__ awv_out) {
    __shared__ short snb[LL * FP];          // 64 KB
    const int b = blockIdx.x >> 1;
    const int half = blockIdx.x & 1;
    const int t = threadIdx.x;
    const int wave = t >> 6, lane = t & 63;

    {
        const char* src = (const char*)(SRC + (size_t)b * LL * FP);
#pragma unroll
        for (int it = 0; it < 8; ++it) {
            int off = it * 8192 + wave * 1024 + lane * 16;
            GLL(src + off, (char*)snb + it * 8192 + wave * 1024);
        }
    }

    f32x4 w0 = *(const f32x4*)(alignW + lane * 4);
    f32x4 w1 = *(const f32x4*)(alignW + FP + lane * 4);
    float bias = alignBp[0];

    float wnt[BDD][4];
#pragma unroll
    for (int i = 0; i < BDD; ++i) {
        f32x4 v = *(const f32x4*)(WnT + (AA + i) * FP + lane * 4);
#pragma unroll
        for (int q = 0; q < 4; ++q) wnt[i][q] = v[q];
    }

    __syncthreads();

#pragma unroll
    for (int ai = 0; ai < 8; ++ai) {
        const int al = half * 64 + wave * 8 + ai;
        const int ga = b * LL + al;

        short4v sv = *(const short4v*)(ACTB + (size_t)ga * FP + lane * 4);
        float ss = wred64(bf2f(sv[0]) * w0[0] + bf2f(sv[1]) * w0[1] +
                          bf2f(sv[2]) * w0[2] + bf2f(sv[3]) * w0[3]);

        int jx[KK];
#pragma unroll
        for (int k = 0; k < KK; ++k) jx[k] = adeg[ga * KK + k];

        float nf[KK][4];
        float sc[KK];
#pragma unroll
        for (int k = 0; k < KK; ++k) {
            short4v nv = *(const short4v*)(snb + jx[k] * FP + lane * 4);
            float f0 = bf2f(nv[0]), f1 = bf2f(nv[1]), f2 = bf2f(nv[2]), f3 = bf2f(nv[3]);
            int bi = bdeg[ga * KK + k];
            const float* bp = bond_list + ((size_t)b * MM + bi) * BDD;
            float bb[BDD];
#pragma unroll
            for (int i = 0; i < 5; ++i) {
                f32x2 v2 = *(const f32x2*)(bp + 2 * i);
                bb[2 * i] = v2[0]; bb[2 * i + 1] = v2[1];
            }
            float b0 = 0.f, b1 = 0.f, b2 = 0.f, b3 = 0.f;
#pragma unroll
            for (int i = 0; i < BDD; ++i) {
                b0 += bb[i] * wnt[i][0]; b1 += bb[i] * wnt[i][1];
                b2 += bb[i] * wnt[i][2]; b3 += bb[i] * wnt[i][3];
            }
            f0 = fmaxf(f0 + b0, 0.f); f1 = fmaxf(f1 + b1, 0.f);
            f2 = fmaxf(f2 + b2, 0.f); f3 = fmaxf(f3 + b3, 0.f);
            nf[k][0] = f0; nf[k][1] = f1; nf[k][2] = f2; nf[k][3] = f3;
            float s2 = wred64(f0 * w1[0] + f1 * w1[1] + f2 * w1[2] + f3 * w1[3]);
            float s = fmaxf(ss + s2 + bias, 0.f);
            if (jx[k] == LL - 1) s -= 9.0f;
            sc[k] = s;
        }

        float m = sc[0];
#pragma unroll
        for (int k = 1; k < KK; ++k) m = fmaxf(m, sc[k]);
        float e[KK], den = 0.f;
#pragma unroll
        for (int k = 0; k < KK; ++k) { e[k] = expf(sc[k] - m); den += e[k]; }
        float aw[KK], sumaw = 0.f;
#pragma unroll
        for (int k = 0; k < KK; ++k) {
            aw[k] = (jx[k] == LL - 1) ? 0.f : e[k] / den;
            sumaw += aw[k];
        }
        if (lane < KK) {
            float av = aw[0];
#pragma unroll
            for (int k = 1; k < KK; ++k) if (lane == k) av = aw[k];
            awv_out[(size_t)ga * KK + lane] = av;
        }
        if (lane == 0) sw_out[ga] = sumaw;

        short4v wo;
#pragma unroll
        for (int q = 0; q < 4; ++q) {
            float w = 0.f;
#pragma unroll
            for (int k = 0; k < KK; ++k) w += aw[k] * nf[k][q];
            wo[q] = f2bf(w);
        }
        *(short4v*)(wn_out + (size_t)ga * FP + lane * 4) = wo;
    }
}

// ---------------- ctx = relu(WN @ Wa^T + sumaw*ab), LDS-staged B (d0 path) ----
__global__ __launch_bounds__(512) void k_ctx_mfma(
        const short* __restrict__ XB,      // wn bf16
        const float* __restrict__ SW,
        const short* __restrict__ WaF,     // frag-major (8,16,64,8)
        const float* __restrict__ ab,
        short* __restrict__ ctx_out) {
    __shared__ short lds[2][8192];         // 2 x 16KB
    const int t = threadIdx.x;
    const int wave = t >> 6, lane = t & 63;
    const int abase = blockIdx.x * 32 + (wave >> 2) * 16;
    const int wn4 = wave & 3;
    const int lr = lane & 15, lk = lane >> 4;
    const int kofs = blockIdx.x & 7;

#define CSTAGE(i) do { \
        int ke_ = ((i) + kofs) & 7; \
        _Pragma("unroll") \
        for (int e = 0; e < 2; ++e) { \
            int f = wave * 2 + e; \
            GLL(WaF + (size_t)(ke_ * 16 + f) * 512 + lane * 8, &lds[(i) & 1][f * 512]); \
        } } while (0)

    f32x4 acc[4] = {};
    const short8* xrow = (const short8*)(XB + (size_t)(abase + lr) * FP);

    CSTAGE(0);
#pragma unroll
    for (int i = 0; i < 8; ++i) {
        int ke = (i + kofs) & 7;
        short8 ax = xrow[ke * 4 + lk];
        __syncthreads();
        if (i < 7) CSTAGE(i + 1);
#pragma unroll
        for (int sub = 0; sub < 4; ++sub) {
            int nt = wn4 * 4 + sub;
            short8 bf = *(const short8*)(&lds[i & 1][nt * 512 + lane * 8]);
            acc[sub] = __builtin_amdgcn_mfma_f32_16x16x32_bf16(ax, bf, acc[sub], 0, 0, 0);
        }
    }
#undef CSTAGE

#pragma unroll
    for (int sub = 0; sub < 4; ++sub) {
        int c = wn4 * 64 + sub * 16 + lr;
        float abc = ab[c];
#pragma unroll
        for (int q = 0; q < 4; ++q) {
            int atom = abase + lk * 4 + q;
            float v = acc[sub][q] + SW[atom] * abc;
            ctx_out[(size_t)atom * FP + c] = f2bf(fmaxf(v, 0.f));
        }
    }
}

// ---------- fused attention+ctx for d>0: 1 block/molecule, LDS slab + wn ----------
// Components verified in round-12's k_mp (scores/wn passes + ctx GEMM), minus the
// GRU fusion that caused its regression. Input ACTB is already relu'd.
__global__ __launch_bounds__(512) void k_actx(int d,
        const short* __restrict__ ACTB,
        const int* __restrict__ adeg,
        const float* __restrict__ alW, const float* __restrict__ alb,
        const short* __restrict__ WaF, const float* __restrict__ atb,
        short* __restrict__ ctx_out, float* __restrict__ awv_out) {
    __shared__ __align__(16) short aS[32768];     // 64 KB act slab (swizzled)
    __shared__ __align__(16) short cS[32768];     // 64 KB wn slab (swizzled)
    __shared__ int   jxS[LL * KK];
    __shared__ float awS[LL * KK];
    __shared__ float swS[LL];

    const int b = blockIdx.x;
    const int t = threadIdx.x;
    const int wave = t >> 6, lane = t & 63;
    const int lr = lane & 15, lk = lane >> 4;

#define SLAB_OFF(r, cb) ((((r) * 512 + (cb))) ^ ((((r) & 7)) << 4))
#define A8R(r, c)  (*(const short8*)((const char*)aS + SLAB_OFF(r, (c) * 2)))
#define A4R(r, c)  (*(const short4v*)((const char*)aS + SLAB_OFF(r, (c) * 2)))
#define C8R(r, c)  (*(const short8*)((const char*)cS + SLAB_OFF(r, (c) * 2)))
#define CW4(r, c, v) (*(short4v*)((char*)cS + SLAB_OFF(r, (c) * 2)) = (v))

    // stage act slab (pre-swizzled source, linear dest)
    {
        const char* src = (const char*)(ACTB + (size_t)b * LL * FP);
#pragma unroll
        for (int it = 0; it < 8; ++it) {
            int off = it * 8192 + wave * 1024 + lane * 16;
            int so = off ^ (((off >> 9) & 7) << 4);
            GLL(src + so, (char*)aS + off);
        }
        for (int i = t; i < LL * KK; i += 512) jxS[i] = adeg[b * LL * KK + i];
    }
    __syncthreads();

    // ---- scores pass: wave handles atoms wave*16..+15 ----
    {
        f32x4 w0 = *(const f32x4*)(alW + (size_t)d * 2 * FP + lane * 4);
        f32x4 w1 = *(const f32x4*)(alW + (size_t)d * 2 * FP + FP + lane * 4);
        float bias = alb[d];
        for (int ai = 0; ai < 16; ++ai) {
            int a = wave * 16 + ai;
            short4v sv = A4R(a, lane * 4);
            float ss = wred64(bf2f(sv[0]) * w0[0] + bf2f(sv[1]) * w0[1] +
                              bf2f(sv[2]) * w0[2] + bf2f(sv[3]) * w0[3]);
            float sc[KK]; int jx[KK];
#pragma unroll
            for (int k = 0; k < KK; ++k) {
                int j = jxS[a * KK + k]; jx[k] = j;
                short4v nv = A4R(j, lane * 4);
                float s2 = wred64(bf2f(nv[0]) * w1[0] + bf2f(nv[1]) * w1[1] +
                                  bf2f(nv[2]) * w1[2] + bf2f(nv[3]) * w1[3]);
                float s = fmaxf(ss + s2 + bias, 0.f);
                if (j == LL - 1) s -= 9.0f;
                sc[k] = s;
            }
            float m = sc[0];
#pragma unroll
            for (int k = 1; k < KK; ++k) m = fmaxf(m, sc[k]);
            float e[KK], den = 0.f;
#pragma unroll
            for (int k = 0; k < KK; ++k) { e[k] = expf(sc[k] - m); den += e[k]; }
            float aw[KK], sumaw = 0.f;
#pragma unroll
            for (int k = 0; k < KK; ++k) {
                aw[k] = (jx[k] == LL - 1) ? 0.f : e[k] / den;
                sumaw += aw[k];
            }
            if (lane < KK) {
                float av = aw[0];
#pragma unroll
                for (int k = 1; k < KK; ++k) if (lane == k) av = aw[k];
                awS[a * KK + lane] = av;
                awv_out[((size_t)b * LL + a) * KK + lane] = av;
            }
            if (lane == 0) swS[a] = sumaw;
        }
    }
    __syncthreads();

    // ---- wn pass -> cS ----
    for (int ai = 0; ai < 16; ++ai) {
        int a = wave * 16 + ai;
        float a0 = 0.f, a1 = 0.f, a2 = 0.f, a3 = 0.f;
#pragma unroll
        for (int k = 0; k < KK; ++k) {
            float awv = awS[a * KK + k];
            short4v nv = A4R(jxS[a * KK + k], lane * 4);
            a0 += awv * bf2f(nv[0]);
            a1 += awv * bf2f(nv[1]);
            a2 += awv * bf2f(nv[2]);
            a3 += awv * bf2f(nv[3]);
        }
        short4v wo; wo[0] = f2bf(a0); wo[1] = f2bf(a1); wo[2] = f2bf(a2); wo[3] = f2bf(a3);
        CW4(a, lane * 4, wo);
    }
    __syncthreads();

    // ---- ctx GEMM: cS(wn) @ Wa^T + sumaw*ab -> relu -> ctx_out (global bf16) ----
    {
        const int rg = wave >> 1, csl = wave & 1;
        f32x4 acc[2][8] = {};
        const short8* wb = (const short8*)(WaF + (size_t)d * 8 * 16 * 512);
        for (int ks = 0; ks < 8; ++ks) {
            short8 a0 = C8R(rg * 32 + lr, ks * 32 + lk * 8);
            short8 a1 = C8R(rg * 32 + 16 + lr, ks * 32 + lk * 8);
#pragma unroll
            for (int nt2 = 0; nt2 < 8; ++nt2) {
                short8 bf = wb[(size_t)(ks * 16 + csl * 8 + nt2) * 64 + lane];
                acc[0][nt2] = __builtin_amdgcn_mfma_f32_16x16x32_bf16(a0, bf, acc[0][nt2], 0, 0, 0);
                acc[1][nt2] = __builtin_amdgcn_mfma_f32_16x16x32_bf16(a1, bf, acc[1][nt2], 0, 0, 0);
            }
        }
#pragma unroll
        for (int rt = 0; rt < 2; ++rt)
#pragma unroll
        for (int nt2 = 0; nt2 < 8; ++nt2) {
            int col = csl * 128 + nt2 * 16 + lr;
            float abv = atb[d * FP + col];
#pragma unroll
            for (int q = 0; q < 4; ++q) {
                int row = rg * 32 + rt * 16 + lk * 4 + q;
                float v = acc[rt][nt2][q] + swS[row] * abv;
                ctx_out[((size_t)b * LL + row) * FP + col] = f2bf(fmaxf(v, 0.f));
            }
        }
    }
#undef SLAB_OFF
#undef A8R
#undef A4R
#undef C8R
#undef CW4
}

// ---------------- fused MFMA GRU v6: counted-vmcnt pipeline, lean I/O ----------
template<int LAST>
__global__ __launch_bounds__(512) void k_gru_mfma(
        const short* __restrict__ XB,     // ctx bf16
        const short* __restrict__ HBl,    // h bf16 (read)
        float* __restrict__ hbuf,         // h fp32 (written only when LAST)
        const short* __restrict__ Bih,    // frag-major (8,48,64,8)
        const short* __restrict__ Bhh,
        const float* __restrict__ bih, const float* __restrict__ bhh,
        float* __restrict__ act_out,
        short* __restrict__ HB_out,
        short* __restrict__ ACT_out) {
    __shared__ short ldsB[3][12288];      // 3 x 24 KB
    __shared__ short ldsA[2][16384];      // x,h slabs: 2 x 32 KB (swizzled)
    const int t = threadIdx.x;
    const int wave = t >> 6, lane = t & 63;
    const int rh = wave >> 2;
    const int wn = wave & 3;
    const int lr = lane & 15, lk = lane >> 4;
    const int bid = blockIdx.x;
    const int kofs = bid & 7;
    const int abase = bid * 64;

#define PKS(p)  ((((p) >> 2) + kofs) & 7)
#define STAGEP(p) do { \
        const short* base_ = ((((p) >> 1) & 1) ? Bhh : Bih) + (size_t)PKS(p) * 24576; \
        const int h_ = (p) & 1; \
        _Pragma("unroll") \
        for (int e = 0; e < 3; ++e) { \
            int j = wave * 3 + e; \
            int nt = 4 * (j >> 1) + 2 * h_ + (j & 1); \
            GLL(base_ + nt * 512 + lane * 8, &ldsB[(p) % 3][j * 512]); \
        } } while (0)
#define LDA_READ(s, r, c) (*(const short8*)((const char*)ldsA[s] + \
        ((((r) * 512 + (c) * 2)) ^ ((((r) & 7)) << 4))))
#define LDA_READ1(s, r, c) (*(const short*)((const char*)ldsA[s] + \
        ((((r) * 512 + (c) * 2)) ^ ((((r) & 7)) << 4))))

    {
        const char* xsrc = (const char*)(XB + (size_t)abase * FP);
        const char* hsrc = (const char*)(HBl + (size_t)abase * FP);
#pragma unroll
        for (int it = 0; it < 4; ++it) {
            int off = it * 8192 + wave * 1024 + lane * 16;
            int src = off ^ (((off >> 9) & 7) << 4);
            GLL(xsrc + src, (char*)ldsA[0] + off);
            GLL(hsrc + src, (char*)ldsA[1] + off);
        }
    }
    STAGEP(0);
    STAGEP(1);

    f32x4 acc_rz[2][8] = {};
    f32x4 acc_in[2][4] = {};
    f32x4 acc_hn[2][4] = {};

    short8 ax0{}, ah0{}, ax1{}, ah1{};
#pragma unroll
    for (int p = 0; p < 32; ++p) {
        if (p < 31) { asm volatile("s_waitcnt vmcnt(3)" ::: "memory"); }
        else        { asm volatile("s_waitcnt vmcnt(0)" ::: "memory"); }
        __builtin_amdgcn_s_barrier();
        __builtin_amdgcn_sched_barrier(0);
        if (p < 30) STAGEP(p + 2);
        const int h_ = p & 1;
        const int mat = (p >> 1) & 1;
        if ((p & 3) == 0) {
            int ks = PKS(p);
            int c = ks * 32 + lk * 8;
            ax0 = LDA_READ(0, rh * 32 + lr, c);
            ah0 = LDA_READ(1, rh * 32 + lr, c);
            ax1 = LDA_READ(0, rh * 32 + 16 + lr, c);
            ah1 = LDA_READ(1, rh * 32 + 16 + lr, c);
        }
#pragma unroll
        for (int rg = 0; rg < 2; ++rg) {
            const short8 a8 = mat ? (rg ? ah1 : ah0) : (rg ? ax1 : ax0);
#pragma unroll
            for (int g = 0; g < 3; ++g) {
#pragma unroll
                for (int s2 = 0; s2 < 2; ++s2) {
                    const int sub = 2 * h_ + s2;
                    const int j = ((4 * g + wn) << 1) | s2;
                    short8 bf = *(const short8*)(&ldsB[p % 3][j * 512 + lane * 8]);
                    if (g < 2)
                        acc_rz[rg][g * 4 + sub] = __builtin_amdgcn_mfma_f32_16x16x32_bf16(a8, bf, acc_rz[rg][g * 4 + sub], 0, 0, 0);
                    else if (mat)
                        acc_hn[rg][sub] = __builtin_amdgcn_mfma_f32_16x16x32_bf16(a8, bf, acc_hn[rg][sub], 0, 0, 0);
                    else
                        acc_in[rg][sub] = __builtin_amdgcn_mfma_f32_16x16x32_bf16(a8, bf, acc_in[rg][sub], 0, 0, 0);
                }
            }
        }
    }
#undef STAGEP
#undef PKS

#pragma unroll
    for (int sub = 0; sub < 4; ++sub) {
        int c = wn * 64 + sub * 16 + lr;
        float brz_r = bih[c] + bhh[c];
        float brz_z = bih[FP + c] + bhh[FP + c];
        float bin_ = bih[2 * FP + c];
        float bhn = bhh[2 * FP + c];
#pragma unroll
        for (int rg = 0; rg < 2; ++rg) {
#pragma unroll
            for (int q = 0; q < 4; ++q) {
                int row = rh * 32 + rg * 16 + lk * 4 + q;
                int atom = abase + row;
                size_t idx = (size_t)atom * FP + c;
                float hold = bf2f(LDA_READ1(1, row, c));
                float r = 1.f / (1.f + expf(-(acc_rz[rg][0 * 4 + sub][q] + brz_r)));
                float z = 1.f / (1.f + expf(-(acc_rz[rg][1 * 4 + sub][q] + brz_z)));
                float n = tanhf(acc_in[rg][sub][q] + bin_ + r * (acc_hn[rg][sub][q] + bhn));
                float hn = (1.f - z) * n + z * hold;
                float rl = fmaxf(hn, 0.f);
                act_out[idx] = rl;
                if constexpr (LAST) {
                    hbuf[idx] = hn;
                } else {
                    HB_out[idx] = f2bf(hn);
                    ACT_out[idx] = f2bf(rl);
                }
            }
        }
    }
#undef LDA_READ
#undef LDA_READ1
}

// ---------------- mol reductions ----------------
__global__ __launch_bounds__(256) void k_mol_reduce(const float* __restrict__ hbuf,
                                                    const float* __restrict__ act,
                                                    const float* __restrict__ mask,
                                                    float* __restrict__ o_unb0,
                                                    float* __restrict__ o_mfv0,
                                                    float* __restrict__ molF) {
    int b = blockIdx.x, t = threadIdx.x;
    float s1 = 0.f, s2 = 0.f;
    for (int l = 0; l < LL; ++l) {
        float mk = mask[b * LL + l];
        s1 += hbuf[((size_t)b * LL + l) * FP + t] * mk;
        s2 += act[((size_t)b * LL + l) * FP + t] * mk;
    }
    o_unb0[b * FP + t] = s1;
    o_mfv0[b * FP + t] = s2;
    molF[b * FP + t] = s2;
}

// ---------------- AV = act @ mol_attend_W.T + b ----------------
__global__ __launch_bounds__(256) void k_av(const float* __restrict__ act,
                                            const float* __restrict__ MWaT,
                                            const float* __restrict__ mab,
                                            float* __restrict__ AV) {
    int g0 = blockIdx.x * 8;
    int t = threadIdx.x;
    __shared__ float xs[8][FP];
    for (int a = 0; a < 8; ++a) xs[a][t] = act[(size_t)(g0 + a) * FP + t];
    __syncthreads();
    float acc[8];
    float bb2 = mab[t];
#pragma unroll
    for (int a = 0; a < 8; ++a) acc[a] = bb2;
    for (int i = 0; i < FP; ++i) {
        float w = MWaT[i * FP + t];
#pragma unroll
        for (int a = 0; a < 8; ++a) acc[a] += xs[a][i] * w;
    }
    for (int a = 0; a < 8; ++a) AV[(size_t)(g0 + a) * FP + t] = acc[a];
}

// ---------------- mol attention + mol GRU (bf16 weights) ----------------
__global__ __launch_bounds__(256) void k_mol_step(int step,
        const float* __restrict__ act,
        const float* __restrict__ AV,
        float* __restrict__ molF,
        const float* __restrict__ mask,
        const float* __restrict__ mAw, const float* __restrict__ mAb,
        const short* __restrict__ MihB, const short* __restrict__ MhhB,
        const float* __restrict__ mbih, const float* __restrict__ mbhh,
        float* __restrict__ o_mfv, float* __restrict__ o_unb,
        float* __restrict__ o_mawv, float* __restrict__ o_molfeat) {
    int b = blockIdx.x, t = threadIdx.x;
    int wave = t >> 6, lane = t & 63;
    __shared__ float am[FP], hh[FP], cx[FP];
    __shared__ float S2[LL], mw[LL];
    __shared__ float red[4];

    float hprev = molF[b * FP + t];
    hh[t] = hprev;
    am[t] = fmaxf(hprev, 0.f);
    __syncthreads();

    float v = am[t] * mAw[t];
#pragma unroll
    for (int off = 32; off >= 1; off >>= 1) v += __shfl_xor(v, off);
    if (lane == 0) red[wave] = v;
    __syncthreads();
    float s_self = red[0] + red[1] + red[2] + red[3];

    for (int l = wave; l < LL; l += 4) {
        float v2 = 0.f;
#pragma unroll
        for (int q = 0; q < 4; ++q) {
            int i = lane + 64 * q;
            v2 += act[((size_t)b * LL + l) * FP + i] * mAw[FP + i];
        }
#pragma unroll
        for (int off = 32; off >= 1; off >>= 1) v2 += __shfl_xor(v2, off);
        if (lane == 0) S2[l] = v2;
    }
    __syncthreads();

    if (t < LL) {
        float s = fmaxf(s_self + S2[t] + mAb[0], 0.f);
        if (mask[b * LL + t] == 0.f) s += -9e8f;
        S2[t] = s;
    }
    __syncthreads();

    float m = -1e30f;
    for (int l = 0; l < LL; ++l) m = fmaxf(m, S2[l]);
    float den = 0.f;
    for (int l = 0; l < LL; ++l) den += expf(S2[l] - m);
    if (t < LL) {
        float w = expf(S2[t] - m) / den * mask[b * LL + t];
        mw[t] = w;
        o_mawv[(size_t)step * (BB * LL) + b * LL + t] = w;
    }
    __syncthreads();

    float acc = 0.f;
    for (int l = 0; l < LL; ++l) acc += mw[l] * AV[((size_t)b * LL + l) * FP + t];
    cx[t] = fmaxf(acc, 0.f);
    __syncthreads();

    float air = mbih[t], aiz = mbih[FP + t], ain = mbih[2 * FP + t];
    float ahr = mbhh[t], ahz = mbhh[FP + t], ahn = mbhh[2 * FP + t];
    for (int i = 0; i < FP; ++i) {
        float c = cx[i], h = hh[i];
        air += c * bf2f(MihB[i * 768 + t]);
        aiz += c * bf2f(MihB[i * 768 + FP + t]);
        ain += c * bf2f(MihB[i * 768 + 2 * FP + t]);
        ahr += h * bf2f(MhhB[i * 768 + t]);
        ahz += h * bf2f(MhhB[i * 768 + FP + t]);
        ahn += h * bf2f(MhhB[i * 768 + 2 * FP + t]);
    }
    float r = 1.f / (1.f + expf(-(air + ahr)));
    float z = 1.f / (1.f + expf(-(aiz + ahz)));
    float n = tanhf(ain + r * ahn);
    float hn = (1.f - z) * n + z * hprev;

    molF[b * FP + t] = hn;
    o_unb[(size_t)(step + 1) * (BB * FP) + b * FP + t] = hn;
    o_mfv[(size_t)(step + 1) * (BB * FP) + b * FP + t] = fmaxf(hn, 0.f);
    if (step == TT - 1) o_molfeat[b * FP + t] = hn;
}

extern "C" void kernel_launch(void* const* d_in, const int* in_sizes, int n_in,
                              void* d_out, int out_size, void* d_ws, size_t ws_size,
                              hipStream_t stream) {
    const float* atom_list = (const float*)d_in[0];
    const float* bond_list = (const float*)d_in[1];
    const int*   adeg      = (const int*)d_in[2];
    const int*   bdeg      = (const int*)d_in[3];
    const float* amask     = (const float*)d_in[4];
    const float* atom_fc_W = (const float*)d_in[5];
    const float* atom_fc_b = (const float*)d_in[6];
    const float* nfc_W     = (const float*)d_in[7];
    const float* nfc_b     = (const float*)d_in[8];
    const float* gwih      = (const float*)d_in[9];
    const float* gwhh      = (const float*)d_in[10];
    const float* gbih      = (const float*)d_in[11];
    const float* gbhh      = (const float*)d_in[12];
    const float* alW       = (const float*)d_in[13];
    const float* alb       = (const float*)d_in[14];
    const float* atW       = (const float*)d_in[15];
    const float* atb       = (const float*)d_in[16];
    const float* mgwih     = (const float*)d_in[17];
    const float* mgwhh     = (const float*)d_in[18];
    const float* mgbih     = (const float*)d_in[19];
    const float* mgbhh     = (const float*)d_in[20];
    const float* malW      = (const float*)d_in[21];
    const float* malb      = (const float*)d_in[22];
    const float* matW      = (const float*)d_in[23];
    const float* matb      = (const float*)d_in[24];

    const size_t BLF = (size_t)BB * LL * FP;
    float* out = (float*)d_out;
    float* O0 = out;                                 // atom_feature / h (fp32)
    float* O1 = out + BLF;                           // afv (4,B,L,FP)
    float* O2 = O1 + 4 * BLF;                        // awv (3,B,L,K)
    float* O3 = O2 + (size_t)RR * BB * LL * KK;      // mfv
    float* O4 = O3 + (size_t)(TT + 1) * BB * FP;     // mol_unb
    float* O5 = O4 + (size_t)(TT + 1) * BB * FP;     // mawv
    float* O6 = O5 + (size_t)TT * BB * LL;           // mol_feature

    // ws layout
    float* ws = (float*)d_ws;
    short* XB   = (short*)ws;                        // BLF shorts: wn d0 bf16
    short* XB2  = XB + BLF;                          // BLF shorts: ctx bf16
    short* HBb  = XB + 2 * BLF;                      // BLF shorts: h bf16
    short* ACTB = XB + 3 * BLF;                      // BLF shorts: relu(h) bf16
    float* AV   = ws;                                // aliases XB/XB2 (mol phase)
    float* rest = ws + 2 * BLF;
    short* ApreB = (short*)rest;                     // BLF shorts
    float* SW    = rest + BLF / 2;                   // B*L floats
    float* MOLF  = SW + (size_t)BB * LL;
    float* WafcT = MOLF + (size_t)BB * FP;
    float* WnT   = WafcT + AA * FP;
    float* MWaT  = WnT + (AA + BDD) * FP;
    short* MihB  = (short*)(MWaT + (size_t)FP * FP);
    short* MhhB  = MihB + (size_t)FP * 768;
    short* GW    = MhhB + (size_t)FP * 768;             // RR*2*(8*48*512) shorts
    short* WaF   = GW + (size_t)RR * 2 * 8 * 48 * 512;  // RR*(8*16*512) shorts
    (void)ws_size; (void)in_sizes; (void)n_in; (void)out_size;

    auto tr = [&](const float* src, float* dst, int O, int I) {
        int n = O * I;
        k_transpose<<<(n + 255) / 256, 256, 0, stream>>>(src, dst, O, I);
    };
    tr(atom_fc_W, WafcT, FP, AA);
    tr(nfc_W, WnT, FP, AA + BDD);
    tr(matW, MWaT, FP, FP);

    {
        int n = RR * 2 * 8 * 48 * 512;
        k_prep_gruw<<<(n + 255) / 256, 256, 0, stream>>>(gwih, gwhh, GW);
        int n2 = RR * 8 * 16 * 512;
        k_prep_waf<<<(n2 + 255) / 256, 256, 0, stream>>>(atW, WaF);
        int n3 = FP * 768;
        k_prep_molw<<<(n3 + 255) / 256, 256, 0, stream>>>(mgwih, mgwhh, MihB, MhhB);
    }

    k_atom_pre<<<BB * LL / 8, 256, 0, stream>>>(atom_list, WafcT, atom_fc_b,
                                                WnT, nfc_b, O1, O0, HBb, ApreB);

    const size_t wblk = (size_t)8 * 48 * 512;
    for (int d = 0; d < RR; ++d) {
        if (d == 0) {
            k_awn_d0<<<BB * 2, 512, 0, stream>>>(HBb, ApreB, bond_list, adeg, bdeg,
                    WnT, alW, alb, XB, SW, O2);
            k_ctx_mfma<<<BB * LL / 32, 512, 0, stream>>>(XB, SW, WaF,
                    atb, XB2);
        } else {
            k_actx<<<BB, 512, 0, stream>>>(d, ACTB, adeg,
                    alW, alb, WaF, atb,
                    XB2, O2 + (size_t)d * BB * LL * KK);
        }
        if (d == RR - 1) {
            k_gru_mfma<1><<<BB * LL / 64, 512, 0, stream>>>(XB2, HBb, O0,
                    GW + (size_t)(d * 2 + 0) * wblk, GW + (size_t)(d * 2 + 1) * wblk,
                    gbih + (size_t)d * 768, gbhh + (size_t)d * 768,
                    O1 + (size_t)(d + 1) * BLF, HBb, ACTB);
        } else {
            k_gru_mfma<0><<<BB * LL / 64, 512, 0, stream>>>(XB2, HBb, O0,
                    GW + (size_t)(d * 2 + 0) * wblk, GW + (size_t)(d * 2 + 1) * wblk,
                    gbih + (size_t)d * 768, gbhh + (size_t)d * 768,
                    O1 + (size_t)(d + 1) * BLF, HBb, ACTB);
        }
    }

    const float* actFin = O1 + (size_t)RR * BLF;
    k_mol_reduce<<<BB, 256, 0, stream>>>(O0, actFin, amask, O4, O3, MOLF);
    k_av<<<BB * LL / 8, 256, 0, stream>>>(actFin, MWaT, matb, AV);
    for (int st = 0; st < TT; ++st) {
        k_mol_step<<<BB, 256, 0, stream>>>(st, actFin, AV, MOLF, amask,
                malW, malb, MihB, MhhB, mgbih, mgbhh,
                O3, O4, O5, O6);
    }
}

// Round 14
// 569.636 us; speedup vs baseline: 1.7335x; 1.1097x over previous
//
#include <hip/hip_runtime.h>
#include <hip/hip_bf16.h>

// Dims
#define BB 256
#define LL 128
#define AA 39
#define BDD 10
#define KK 6
#define MM 256
#define FP 256
#define RR 3
#define TT 2

using short8  = __attribute__((ext_vector_type(8))) short;
using short4v = __attribute__((ext_vector_type(4))) short;
using f32x4   = __attribute__((ext_vector_type(4))) float;
using f32x2   = __attribute__((ext_vector_type(2))) float;

__device__ __forceinline__ short f2bf(float f) {
    union { float f; unsigned u; } v; v.f = f;
    unsigned u = v.u;
    u += 0x7fffu + ((u >> 16) & 1u);   // round-to-nearest-even
    return (short)(u >> 16);
}
__device__ __forceinline__ float bf2f(short s) {
    union { unsigned u; float f; } v; v.u = ((unsigned)(unsigned short)s) << 16;
    return v.f;
}
__device__ __forceinline__ float wred64(float v) {
#pragma unroll
    for (int off = 32; off >= 1; off >>= 1) v += __shfl_xor(v, off);
    return v;
}

#define GLL(gp, lp) __builtin_amdgcn_global_load_lds( \
    (const __attribute__((address_space(1))) void*)(gp), \
    (__attribute__((address_space(3))) void*)(lp), 16, 0, 0)

// ---------------- transpose ----------------
__global__ __launch_bounds__(256) void k_transpose(const float* __restrict__ src,
                                                   float* __restrict__ dst, int O, int I) {
    int idx = blockIdx.x * 256 + threadIdx.x;
    if (idx >= O * I) return;
    int o = idx / I, i = idx - o * I;
    dst[i * O + o] = src[idx];
}

// ---------------- pack GRU weights: [d][mat][ks(8)][nt(48)][lane][8] ----------------
__global__ __launch_bounds__(256) void k_prep_gruw(const float* __restrict__ gwih,
                                                   const float* __restrict__ gwhh,
                                                   short* __restrict__ out) {
    int idx = blockIdx.x * 256 + threadIdx.x;
    if (idx >= RR * 2 * 8 * 48 * 512) return;
    int j = idx & 7;
    int lane = (idx >> 3) & 63;
    int blk = idx >> 9;
    int nt = blk % 48;
    int ks = (blk / 48) % 8;
    int mat = (blk / (48 * 8)) % 2;
    int d = blk / (48 * 8 * 2);
    int n = nt * 16 + (lane & 15);
    int k = ks * 32 + (lane >> 4) * 8 + j;
    const float* W = mat ? gwhh : gwih;
    out[idx] = f2bf(W[((size_t)d * 768 + n) * FP + k]);
}

// ---------------- pack mol GRU weights: [mat][ks(8)][nt(48)][lane][8] ----------------
__global__ __launch_bounds__(256) void k_prep_molfrag(const float* __restrict__ mih,
                                                      const float* __restrict__ mhh,
                                                      short* __restrict__ out) {
    int idx = blockIdx.x * 256 + threadIdx.x;
    if (idx >= 2 * 8 * 48 * 512) return;
    int j = idx & 7;
    int lane = (idx >> 3) & 63;
    int blk = idx >> 9;
    int nt = blk % 48;
    int ks = (blk / 48) % 8;
    int mat = blk / (48 * 8);
    int n = nt * 16 + (lane & 15);
    int k = ks * 32 + (lane >> 4) * 8 + j;
    const float* W = mat ? mhh : mih;
    out[idx] = f2bf(W[(size_t)n * FP + k]);
}

// ---------------- pack attend weights: [d][ks(8)][nt(16)][lane][8] ----------------
__global__ __launch_bounds__(256) void k_prep_waf(const float* __restrict__ atW,
                                                  short* __restrict__ out) {
    int idx = blockIdx.x * 256 + threadIdx.x;
    if (idx >= RR * 8 * 16 * 512) return;
    int j = idx & 7;
    int lane = (idx >> 3) & 63;
    int blk = idx >> 9;
    int nt = blk % 16;
    int ks = (blk / 16) % 8;
    int d = blk / 128;
    int n = nt * 16 + (lane & 15);
    int k = ks * 32 + (lane >> 4) * 8 + j;
    out[idx] = f2bf(atW[(size_t)d * FP * FP + (size_t)n * FP + k]);
}

// ---------------- fused atom fc + neighbor-fc atom part ----------------
__global__ __launch_bounds__(256) void k_atom_pre(const float* __restrict__ atom_list,
                                                  const float* __restrict__ WafcT,
                                                  const float* __restrict__ afc_b,
                                                  const float* __restrict__ WnT,
                                                  const float* __restrict__ bn,
                                                  float* __restrict__ out_pre,
                                                  float* __restrict__ hbuf,
                                                  short* __restrict__ hb16,
                                                  short* __restrict__ ApreB) {
    int g0 = blockIdx.x * 8;
    int t = threadIdx.x;
    __shared__ float x[8][AA];
    for (int i = t; i < 8 * AA; i += 256) x[i / AA][i % AA] = atom_list[(size_t)g0 * AA + i];
    __syncthreads();
    float a1[8], a2[8];
    float b1 = afc_b[t], b2 = bn[t];
#pragma unroll
    for (int a = 0; a < 8; ++a) { a1[a] = b1; a2[a] = b2; }
    for (int i = 0; i < AA; ++i) {
        float w1 = WafcT[i * FP + t];
        float w2 = WnT[i * FP + t];
#pragma unroll
        for (int a = 0; a < 8; ++a) { a1[a] += x[a][i] * w1; a2[a] += x[a][i] * w2; }
    }
#pragma unroll
    for (int a = 0; a < 8; ++a) {
        size_t idx = (size_t)(g0 + a) * FP + t;
        out_pre[idx] = a1[a];
        float rl = fmaxf(a1[a], 0.f);
        hbuf[idx] = rl;
        hb16[idx] = f2bf(rl);   // h0 = relu(pre)
        ApreB[idx] = f2bf(a2[a]);
    }
}

// ---------------- d0 attention (bond terms) -> wn(XB), sumaw(SW), awv(O2 d0) ----
__global__ __launch_bounds__(512) void k_awn_d0(
        const short* __restrict__ ACTB,
        const short* __restrict__ SRC,
        const float* __restrict__ bond_list,
        const int* __restrict__ adeg, const int* __restrict__ bdeg,
        const float* __restrict__ WnT,
        const float* __restrict__ alignW, const float* __restrict__ alignBp,
        short* __restrict__ wn_out, float* __restrict__ sw_out,
        float* __restrict__ awv_out) {
    __shared__ short snb[LL * FP];          // 64 KB
    const int b = blockIdx.x >> 1;
    const int half = blockIdx.x & 1;
    const int t = threadIdx.x;
    const int wave = t >> 6, lane = t & 63;

    {
        const char* src = (const char*)(SRC + (size_t)b * LL * FP);
#pragma unroll
        for (int it = 0; it < 8; ++it) {
            int off = it * 8192 + wave * 1024 + lane * 16;
            GLL(src + off, (char*)snb + it * 8192 + wave * 1024);
        }
    }

    f32x4 w0 = *(const f32x4*)(alignW + lane * 4);
    f32x4 w1 = *(const f32x4*)(alignW + FP + lane * 4);
    float bias = alignBp[0];

    float wnt[BDD][4];
#pragma unroll
    for (int i = 0; i < BDD; ++i) {
        f32x4 v = *(const f32x4*)(WnT + (AA + i) * FP + lane * 4);
#pragma unroll
        for (int q = 0; q < 4; ++q) wnt[i][q] = v[q];
    }

    __syncthreads();

#pragma unroll
    for (int ai = 0; ai < 8; ++ai) {
        const int al = half * 64 + wave * 8 + ai;
        const int ga = b * LL + al;

        short4v sv = *(const short4v*)(ACTB + (size_t)ga * FP + lane * 4);
        float ss = wred64(bf2f(sv[0]) * w0[0] + bf2f(sv[1]) * w0[1] +
                          bf2f(sv[2]) * w0[2] + bf2f(sv[3]) * w0[3]);

        int jx[KK];
#pragma unroll
        for (int k = 0; k < KK; ++k) jx[k] = adeg[ga * KK + k];

        float nf[KK][4];
        float sc[KK];
#pragma unroll
        for (int k = 0; k < KK; ++k) {
            short4v nv = *(const short4v*)(snb + jx[k] * FP + lane * 4);
            float f0 = bf2f(nv[0]), f1 = bf2f(nv[1]), f2 = bf2f(nv[2]), f3 = bf2f(nv[3]);
            int bi = bdeg[ga * KK + k];
            const float* bp = bond_list + ((size_t)b * MM + bi) * BDD;
            float bb[BDD];
#pragma unroll
            for (int i = 0; i < 5; ++i) {
                f32x2 v2 = *(const f32x2*)(bp + 2 * i);
                bb[2 * i] = v2[0]; bb[2 * i + 1] = v2[1];
            }
            float b0 = 0.f, b1 = 0.f, b2 = 0.f, b3 = 0.f;
#pragma unroll
            for (int i = 0; i < BDD; ++i) {
                b0 += bb[i] * wnt[i][0]; b1 += bb[i] * wnt[i][1];
                b2 += bb[i] * wnt[i][2]; b3 += bb[i] * wnt[i][3];
            }
            f0 = fmaxf(f0 + b0, 0.f); f1 = fmaxf(f1 + b1, 0.f);
            f2 = fmaxf(f2 + b2, 0.f); f3 = fmaxf(f3 + b3, 0.f);
            nf[k][0] = f0; nf[k][1] = f1; nf[k][2] = f2; nf[k][3] = f3;
            float s2 = wred64(f0 * w1[0] + f1 * w1[1] + f2 * w1[2] + f3 * w1[3]);
            float s = fmaxf(ss + s2 + bias, 0.f);
            if (jx[k] == LL - 1) s -= 9.0f;
            sc[k] = s;
        }

        float m = sc[0];
#pragma unroll
        for (int k = 1; k < KK; ++k) m = fmaxf(m, sc[k]);
        float e[KK], den = 0.f;
#pragma unroll
        for (int k = 0; k < KK; ++k) { e[k] = expf(sc[k] - m); den += e[k]; }
        float aw[KK], sumaw = 0.f;
#pragma unroll
        for (int k = 0; k < KK; ++k) {
            aw[k] = (jx[k] == LL - 1) ? 0.f : e[k] / den;
            sumaw += aw[k];
        }
        if (lane < KK) {
            float av = aw[0];
#pragma unroll
            for (int k = 1; k < KK; ++k) if (lane == k) av = aw[k];
            awv_out[(size_t)ga * KK + lane] = av;
        }
        if (lane == 0) sw_out[ga] = sumaw;

        short4v wo;
#pragma unroll
        for (int q = 0; q < 4; ++q) {
            float w = 0.f;
#pragma unroll
            for (int k = 0; k < KK; ++k) w += aw[k] * nf[k][q];
            wo[q] = f2bf(w);
        }
        *(short4v*)(wn_out + (size_t)ga * FP + lane * 4) = wo;
    }
}

// ---------------- ctx = relu(WN @ Wa^T + sumaw*ab), LDS-staged B (d0 path) ----
__global__ __launch_bounds__(512) void k_ctx_mfma(
        const short* __restrict__ XB,      // wn bf16
        const float* __restrict__ SW,
        const short* __restrict__ WaF,     // frag-major (8,16,64,8)
        const float* __restrict__ ab,
        short* __restrict__ ctx_out) {
    __shared__ short lds[2][8192];         // 2 x 16KB
    const int t = threadIdx.x;
    const int wave = t >> 6, lane = t & 63;
    const int abase = blockIdx.x * 32 + (wave >> 2) * 16;
    const int wn4 = wave & 3;
    const int lr = lane & 15, lk = lane >> 4;
    const int kofs = blockIdx.x & 7;

#define CSTAGE(i) do { \
        int ke_ = ((i) + kofs) & 7; \
        _Pragma("unroll") \
        for (int e = 0; e < 2; ++e) { \
            int f = wave * 2 + e; \
            GLL(WaF + (size_t)(ke_ * 16 + f) * 512 + lane * 8, &lds[(i) & 1][f * 512]); \
        } } while (0)

    f32x4 acc[4] = {};
    const short8* xrow = (const short8*)(XB + (size_t)(abase + lr) * FP);

    CSTAGE(0);
#pragma unroll
    for (int i = 0; i < 8; ++i) {
        int ke = (i + kofs) & 7;
        short8 ax = xrow[ke * 4 + lk];
        __syncthreads();
        if (i < 7) CSTAGE(i + 1);
#pragma unroll
        for (int sub = 0; sub < 4; ++sub) {
            int nt = wn4 * 4 + sub;
            short8 bf = *(const short8*)(&lds[i & 1][nt * 512 + lane * 8]);
            acc[sub] = __builtin_amdgcn_mfma_f32_16x16x32_bf16(ax, bf, acc[sub], 0, 0, 0);
        }
    }
#undef CSTAGE

#pragma unroll
    for (int sub = 0; sub < 4; ++sub) {
        int c = wn4 * 64 + sub * 16 + lr;
        float abc = ab[c];
#pragma unroll
        for (int q = 0; q < 4; ++q) {
            int atom = abase + lk * 4 + q;
            float v = acc[sub][q] + SW[atom] * abc;
            ctx_out[(size_t)atom * FP + c] = f2bf(fmaxf(v, 0.f));
        }
    }
}

// ---------- fused attention+ctx for d>0: 1 block/molecule ----------
__global__ __launch_bounds__(512) void k_actx(int d,
        const short* __restrict__ ACTB,
        const int* __restrict__ adeg,
        const float* __restrict__ alW, const float* __restrict__ alb,
        const short* __restrict__ WaF, const float* __restrict__ atb,
        short* __restrict__ ctx_out, float* __restrict__ awv_out) {
    __shared__ __align__(16) short aS[32768];     // 64 KB act slab (swizzled)
    __shared__ __align__(16) short cS[32768];     // 64 KB wn slab (swizzled)
    __shared__ int   jxS[LL * KK];
    __shared__ float awS[LL * KK];
    __shared__ float swS[LL];

    const int b = blockIdx.x;
    const int t = threadIdx.x;
    const int wave = t >> 6, lane = t & 63;
    const int lr = lane & 15, lk = lane >> 4;

#define SLAB_OFF(r, cb) ((((r) * 512 + (cb))) ^ ((((r) & 7)) << 4))
#define A4R(r, c)  (*(const short4v*)((const char*)aS + SLAB_OFF(r, (c) * 2)))
#define C8R(r, c)  (*(const short8*)((const char*)cS + SLAB_OFF(r, (c) * 2)))
#define CW4(r, c, v) (*(short4v*)((char*)cS + SLAB_OFF(r, (c) * 2)) = (v))

    {
        const char* src = (const char*)(ACTB + (size_t)b * LL * FP);
#pragma unroll
        for (int it = 0; it < 8; ++it) {
            int off = it * 8192 + wave * 1024 + lane * 16;
            int so = off ^ (((off >> 9) & 7) << 4);
            GLL(src + so, (char*)aS + off);
        }
        for (int i = t; i < LL * KK; i += 512) jxS[i] = adeg[b * LL * KK + i];
    }
    __syncthreads();

    {
        f32x4 w0 = *(const f32x4*)(alW + (size_t)d * 2 * FP + lane * 4);
        f32x4 w1 = *(const f32x4*)(alW + (size_t)d * 2 * FP + FP + lane * 4);
        float bias = alb[d];
        for (int ai = 0; ai < 16; ++ai) {
            int a = wave * 16 + ai;
            short4v sv = A4R(a, lane * 4);
            float ss = wred64(bf2f(sv[0]) * w0[0] + bf2f(sv[1]) * w0[1] +
                              bf2f(sv[2]) * w0[2] + bf2f(sv[3]) * w0[3]);
            float sc[KK]; int jx[KK];
#pragma unroll
            for (int k = 0; k < KK; ++k) {
                int j = jxS[a * KK + k]; jx[k] = j;
                short4v nv = A4R(j, lane * 4);
                float s2 = wred64(bf2f(nv[0]) * w1[0] + bf2f(nv[1]) * w1[1] +
                                  bf2f(nv[2]) * w1[2] + bf2f(nv[3]) * w1[3]);
                float s = fmaxf(ss + s2 + bias, 0.f);
                if (j == LL - 1) s -= 9.0f;
                sc[k] = s;
            }
            float m = sc[0];
#pragma unroll
            for (int k = 1; k < KK; ++k) m = fmaxf(m, sc[k]);
            float e[KK], den = 0.f;
#pragma unroll
            for (int k = 0; k < KK; ++k) { e[k] = expf(sc[k] - m); den += e[k]; }
            float aw[KK], sumaw = 0.f;
#pragma unroll
            for (int k = 0; k < KK; ++k) {
                aw[k] = (jx[k] == LL - 1) ? 0.f : e[k] / den;
                sumaw += aw[k];
            }
            if (lane < KK) {
                float av = aw[0];
#pragma unroll
                for (int k = 1; k < KK; ++k) if (lane == k) av = aw[k];
                awS[a * KK + lane] = av;
                awv_out[((size_t)b * LL + a) * KK + lane] = av;
            }
            if (lane == 0) swS[a] = sumaw;
        }
    }
    __syncthreads();

    for (int ai = 0; ai < 16; ++ai) {
        int a = wave * 16 + ai;
        float a0 = 0.f, a1 = 0.f, a2 = 0.f, a3 = 0.f;
#pragma unroll
        for (int k = 0; k < KK; ++k) {
            float awv = awS[a * KK + k];
            short4v nv = A4R(jxS[a * KK + k], lane * 4);
            a0 += awv * bf2f(nv[0]);
            a1 += awv * bf2f(nv[1]);
            a2 += awv * bf2f(nv[2]);
            a3 += awv * bf2f(nv[3]);
        }
        short4v wo; wo[0] = f2bf(a0); wo[1] = f2bf(a1); wo[2] = f2bf(a2); wo[3] = f2bf(a3);
        CW4(a, lane * 4, wo);
    }
    __syncthreads();

    {
        const int rg = wave >> 1, csl = wave & 1;
        f32x4 acc[2][8] = {};
        const short8* wb = (const short8*)(WaF + (size_t)d * 8 * 16 * 512);
        for (int ks = 0; ks < 8; ++ks) {
            short8 a0 = C8R(rg * 32 + lr, ks * 32 + lk * 8);
            short8 a1 = C8R(rg * 32 + 16 + lr, ks * 32 + lk * 8);
#pragma unroll
            for (int nt2 = 0; nt2 < 8; ++nt2) {
                short8 bf = wb[(size_t)(ks * 16 + csl * 8 + nt2) * 64 + lane];
                acc[0][nt2] = __builtin_amdgcn_mfma_f32_16x16x32_bf16(a0, bf, acc[0][nt2], 0, 0, 0);
                acc[1][nt2] = __builtin_amdgcn_mfma_f32_16x16x32_bf16(a1, bf, acc[1][nt2], 0, 0, 0);
            }
        }
#pragma unroll
        for (int rt = 0; rt < 2; ++rt)
#pragma unroll
        for (int nt2 = 0; nt2 < 8; ++nt2) {
            int col = csl * 128 + nt2 * 16 + lr;
            float abv = atb[d * FP + col];
#pragma unroll
            for (int q = 0; q < 4; ++q) {
                int row = rg * 32 + rt * 16 + lk * 4 + q;
                float v = acc[rt][nt2][q] + swS[row] * abv;
                ctx_out[((size_t)b * LL + row) * FP + col] = f2bf(fmaxf(v, 0.f));
            }
        }
    }
#undef SLAB_OFF
#undef A4R
#undef C8R
#undef CW4
}

// ---------------- fused MFMA GRU v6: counted-vmcnt pipeline, lean I/O ----------
template<int LAST>
__global__ __launch_bounds__(512) void k_gru_mfma(
        const short* __restrict__ XB,     // ctx bf16
        const short* __restrict__ HBl,    // h bf16 (read)
        float* __restrict__ hbuf,         // h fp32 (written only when LAST)
        const short* __restrict__ Bih,    // frag-major (8,48,64,8)
        const short* __restrict__ Bhh,
        const float* __restrict__ bih, const float* __restrict__ bhh,
        float* __restrict__ act_out,
        short* __restrict__ HB_out,
        short* __restrict__ ACT_out) {
    __shared__ short ldsB[3][12288];      // 3 x 24 KB
    __shared__ short ldsA[2][16384];      // x,h slabs: 2 x 32 KB (swizzled)
    const int t = threadIdx.x;
    const int wave = t >> 6, lane = t & 63;
    const int rh = wave >> 2;
    const int wn = wave & 3;
    const int lr = lane & 15, lk = lane >> 4;
    const int bid = blockIdx.x;
    const int kofs = bid & 7;
    const int abase = bid * 64;

#define PKS(p)  ((((p) >> 2) + kofs) & 7)
#define STAGEP(p) do { \
        const short* base_ = ((((p) >> 1) & 1) ? Bhh : Bih) + (size_t)PKS(p) * 24576; \
        const int h_ = (p) & 1; \
        _Pragma("unroll") \
        for (int e = 0; e < 3; ++e) { \
            int j = wave * 3 + e; \
            int nt = 4 * (j >> 1) + 2 * h_ + (j & 1); \
            GLL(base_ + nt * 512 + lane * 8, &ldsB[(p) % 3][j * 512]); \
        } } while (0)
#define LDA_READ(s, r, c) (*(const short8*)((const char*)ldsA[s] + \
        ((((r) * 512 + (c) * 2)) ^ ((((r) & 7)) << 4))))
#define LDA_READ1(s, r, c) (*(const short*)((const char*)ldsA[s] + \
        ((((r) * 512 + (c) * 2)) ^ ((((r) & 7)) << 4))))

    {
        const char* xsrc = (const char*)(XB + (size_t)abase * FP);
        const char* hsrc = (const char*)(HBl + (size_t)abase * FP);
#pragma unroll
        for (int it = 0; it < 4; ++it) {
            int off = it * 8192 + wave * 1024 + lane * 16;
            int src = off ^ (((off >> 9) & 7) << 4);
            GLL(xsrc + src, (char*)ldsA[0] + off);
            GLL(hsrc + src, (char*)ldsA[1] + off);
        }
    }
    STAGEP(0);
    STAGEP(1);

    f32x4 acc_rz[2][8] = {};
    f32x4 acc_in[2][4] = {};
    f32x4 acc_hn[2][4] = {};

    short8 ax0{}, ah0{}, ax1{}, ah1{};
#pragma unroll
    for (int p = 0; p < 32; ++p) {
        if (p < 31) { asm volatile("s_waitcnt vmcnt(3)" ::: "memory"); }
        else        { asm volatile("s_waitcnt vmcnt(0)" ::: "memory"); }
        __builtin_amdgcn_s_barrier();
        __builtin_amdgcn_sched_barrier(0);
        if (p < 30) STAGEP(p + 2);
        const int h_ = p & 1;
        const int mat = (p >> 1) & 1;
        if ((p & 3) == 0) {
            int ks = PKS(p);
            int c = ks * 32 + lk * 8;
            ax0 = LDA_READ(0, rh * 32 + lr, c);
            ah0 = LDA_READ(1, rh * 32 + lr, c);
            ax1 = LDA_READ(0, rh * 32 + 16 + lr, c);
            ah1 = LDA_READ(1, rh * 32 + 16 + lr, c);
        }
#pragma unroll
        for (int rg = 0; rg < 2; ++rg) {
            const short8 a8 = mat ? (rg ? ah1 : ah0) : (rg ? ax1 : ax0);
#pragma unroll
            for (int g = 0; g < 3; ++g) {
#pragma unroll
                for (int s2 = 0; s2 < 2; ++s2) {
                    const int sub = 2 * h_ + s2;
                    const int j = ((4 * g + wn) << 1) | s2;
                    short8 bf = *(const short8*)(&ldsB[p % 3][j * 512 + lane * 8]);
                    if (g < 2)
                        acc_rz[rg][g * 4 + sub] = __builtin_amdgcn_mfma_f32_16x16x32_bf16(a8, bf, acc_rz[rg][g * 4 + sub], 0, 0, 0);
                    else if (mat)
                        acc_hn[rg][sub] = __builtin_amdgcn_mfma_f32_16x16x32_bf16(a8, bf, acc_hn[rg][sub], 0, 0, 0);
                    else
                        acc_in[rg][sub] = __builtin_amdgcn_mfma_f32_16x16x32_bf16(a8, bf, acc_in[rg][sub], 0, 0, 0);
                }
            }
        }
    }
#undef STAGEP
#undef PKS

#pragma unroll
    for (int sub = 0; sub < 4; ++sub) {
        int c = wn * 64 + sub * 16 + lr;
        float brz_r = bih[c] + bhh[c];
        float brz_z = bih[FP + c] + bhh[FP + c];
        float bin_ = bih[2 * FP + c];
        float bhn = bhh[2 * FP + c];
#pragma unroll
        for (int rg = 0; rg < 2; ++rg) {
#pragma unroll
            for (int q = 0; q < 4; ++q) {
                int row = rh * 32 + rg * 16 + lk * 4 + q;
                int atom = abase + row;
                size_t idx = (size_t)atom * FP + c;
                float hold = bf2f(LDA_READ1(1, row, c));
                float r = 1.f / (1.f + expf(-(acc_rz[rg][0 * 4 + sub][q] + brz_r)));
                float z = 1.f / (1.f + expf(-(acc_rz[rg][1 * 4 + sub][q] + brz_z)));
                float n = tanhf(acc_in[rg][sub][q] + bin_ + r * (acc_hn[rg][sub][q] + bhn));
                float hn = (1.f - z) * n + z * hold;
                float rl = fmaxf(hn, 0.f);
                act_out[idx] = rl;
                if constexpr (LAST) {
                    hbuf[idx] = hn;
                } else {
                    HB_out[idx] = f2bf(hn);
                    ACT_out[idx] = f2bf(rl);
                }
            }
        }
    }
#undef LDA_READ
#undef LDA_READ1
}

// ---------------- mol reduce + S2 precompute ----------------
// s1 = sum h*mask -> O4[0]; s2 = sum act*mask -> O3[0], molF, MOLFb;
// S2g[l] = dot(act_l, malW[FP:]) (step-independent score part)
__global__ __launch_bounds__(256) void k_mol_reduce(const float* __restrict__ hbuf,
                                                    const float* __restrict__ act,
                                                    const float* __restrict__ mask,
                                                    const float* __restrict__ malW,
                                                    float* __restrict__ o_unb0,
                                                    float* __restrict__ o_mfv0,
                                                    float* __restrict__ molF,
                                                    short* __restrict__ MOLFb,
                                                    float* __restrict__ S2g) {
    int b = blockIdx.x, t = threadIdx.x;
    int wave = t >> 6, lane = t & 63;
    float s1 = 0.f, s2 = 0.f;
    for (int l = 0; l < LL; ++l) {
        float mk = mask[b * LL + l];
        s1 += hbuf[((size_t)b * LL + l) * FP + t] * mk;
        s2 += act[((size_t)b * LL + l) * FP + t] * mk;
    }
    o_unb0[b * FP + t] = s1;
    o_mfv0[b * FP + t] = s2;
    molF[b * FP + t] = s2;
    MOLFb[b * FP + t] = f2bf(s2);

    // S2 row dots: wave w handles rows l = w, w+4, ...
    for (int l = wave; l < LL; l += 4) {
        float v2 = 0.f;
#pragma unroll
        for (int q = 0; q < 4; ++q) {
            int i = lane + 64 * q;
            v2 += act[((size_t)b * LL + l) * FP + i] * malW[FP + i];
        }
        v2 = wred64(v2);
        if (lane == 0) S2g[b * LL + l] = v2;
    }
}

// ---------------- mol step: scores + softmax + rank-1 attend -> mctx bf16 ------
__global__ __launch_bounds__(256) void k_mstep(int step,
        const float* __restrict__ act,       // actFin fp32
        const float* __restrict__ molF,
        const float* __restrict__ mask,
        const float* __restrict__ S2g,
        const float* __restrict__ malW, const float* __restrict__ malb,
        const float* __restrict__ MWaT, const float* __restrict__ matb,
        short* __restrict__ MCTXb,
        float* __restrict__ o_mawv) {
    int b = blockIdx.x, t = threadIdx.x;
    int wave = t >> 6, lane = t & 63;
    __shared__ float sS[LL], mwS[LL], waS[FP];
    __shared__ float red[4];

    float hprev = molF[b * FP + t];
    float am = fmaxf(hprev, 0.f);

    float v = am * malW[t];
    v = wred64(v);
    if (lane == 0) red[wave] = v;
    __syncthreads();
    float s_self = red[0] + red[1] + red[2] + red[3];

    if (t < LL) {
        float s = fmaxf(s_self + S2g[b * LL + t] + malb[0], 0.f);
        if (mask[b * LL + t] == 0.f) s += -9e8f;
        sS[t] = s;
    }
    __syncthreads();

    float m = -1e30f;
    for (int l = 0; l < LL; ++l) m = fmaxf(m, sS[l]);
    float den = 0.f;
    for (int l = 0; l < LL; ++l) den += expf(sS[l] - m);
    if (t < LL) {
        float w = expf(sS[t] - m) / den * mask[b * LL + t];
        mwS[t] = w;
        o_mawv[(size_t)step * (BB * LL) + b * LL + t] = w;
    }
    __syncthreads();

    float sumaw = 0.f;
    for (int l = 0; l < LL; ++l) sumaw += mwS[l];

    // wa = mw @ act (column t)
    float wa = 0.f;
    for (int l = 0; l < LL; ++l) wa += mwS[l] * act[((size_t)b * LL + l) * FP + t];
    waS[t] = wa;
    __syncthreads();

    // mctx[t] = relu(wa @ MWa^T |_t + sumaw*matb[t])
    float acc = sumaw * matb[t];
    for (int i = 0; i < FP; ++i) acc += waS[i] * MWaT[i * FP + t];
    MCTXb[b * FP + t] = f2bf(fmaxf(acc, 0.f));
}

// ---------------- mol GRU as 256-row MFMA GEMM (4 blocks x 64 rows) ----------
__global__ __launch_bounds__(512) void k_mol_gru(int step,
        const short* __restrict__ XB,     // mctx bf16 (256,FP)
        const short* __restrict__ HBl,    // molF bf16
        const short* __restrict__ Bih,    // frag-major (8,48,64,8)
        const short* __restrict__ Bhh,
        const float* __restrict__ bih, const float* __restrict__ bhh,
        float* __restrict__ o_unb, float* __restrict__ o_mfv,
        float* __restrict__ molF, short* __restrict__ MOLFb,
        float* __restrict__ o_molfeat) {
    __shared__ short ldsB[3][12288];
    __shared__ short ldsA[2][16384];
    const int t = threadIdx.x;
    const int wave = t >> 6, lane = t & 63;
    const int rh = wave >> 2;
    const int wn = wave & 3;
    const int lr = lane & 15, lk = lane >> 4;
    const int bid = blockIdx.x;
    const int kofs = bid & 7;
    const int abase = bid * 64;

#define PKS(p)  ((((p) >> 2) + kofs) & 7)
#define STAGEP(p) do { \
        const short* base_ = ((((p) >> 1) & 1) ? Bhh : Bih) + (size_t)PKS(p) * 24576; \
        const int h_ = (p) & 1; \
        _Pragma("unroll") \
        for (int e = 0; e < 3; ++e) { \
            int j = wave * 3 + e; \
            int nt = 4 * (j >> 1) + 2 * h_ + (j & 1); \
            GLL(base_ + nt * 512 + lane * 8, &ldsB[(p) % 3][j * 512]); \
        } } while (0)
#define LDA_READ(s, r, c) (*(const short8*)((const char*)ldsA[s] + \
        ((((r) * 512 + (c) * 2)) ^ ((((r) & 7)) << 4))))
#define LDA_READ1(s, r, c) (*(const short*)((const char*)ldsA[s] + \
        ((((r) * 512 + (c) * 2)) ^ ((((r) & 7)) << 4))))

    {
        const char* xsrc = (const char*)(XB + (size_t)abase * FP);
        const char* hsrc = (const char*)(HBl + (size_t)abase * FP);
#pragma unroll
        for (int it = 0; it < 4; ++it) {
            int off = it * 8192 + wave * 1024 + lane * 16;
            int src = off ^ (((off >> 9) & 7) << 4);
            GLL(xsrc + src, (char*)ldsA[0] + off);
            GLL(hsrc + src, (char*)ldsA[1] + off);
        }
    }
    STAGEP(0);
    STAGEP(1);

    f32x4 acc_rz[2][8] = {};
    f32x4 acc_in[2][4] = {};
    f32x4 acc_hn[2][4] = {};

    short8 ax0{}, ah0{}, ax1{}, ah1{};
#pragma unroll
    for (int p = 0; p < 32; ++p) {
        if (p < 31) { asm volatile("s_waitcnt vmcnt(3)" ::: "memory"); }
        else        { asm volatile("s_waitcnt vmcnt(0)" ::: "memory"); }
        __builtin_amdgcn_s_barrier();
        __builtin_amdgcn_sched_barrier(0);
        if (p < 30) STAGEP(p + 2);
        const int h_ = p & 1;
        const int mat = (p >> 1) & 1;
        if ((p & 3) == 0) {
            int ks = PKS(p);
            int c = ks * 32 + lk * 8;
            ax0 = LDA_READ(0, rh * 32 + lr, c);
            ah0 = LDA_READ(1, rh * 32 + lr, c);
            ax1 = LDA_READ(0, rh * 32 + 16 + lr, c);
            ah1 = LDA_READ(1, rh * 32 + 16 + lr, c);
        }
#pragma unroll
        for (int rg = 0; rg < 2; ++rg) {
            const short8 a8 = mat ? (rg ? ah1 : ah0) : (rg ? ax1 : ax0);
#pragma unroll
            for (int g = 0; g < 3; ++g) {
#pragma unroll
                for (int s2 = 0; s2 < 2; ++s2) {
                    const int sub = 2 * h_ + s2;
                    const int j = ((4 * g + wn) << 1) | s2;
                    short8 bf = *(const short8*)(&ldsB[p % 3][j * 512 + lane * 8]);
                    if (g < 2)
                        acc_rz[rg][g * 4 + sub] = __builtin_amdgcn_mfma_f32_16x16x32_bf16(a8, bf, acc_rz[rg][g * 4 + sub], 0, 0, 0);
                    else if (mat)
                        acc_hn[rg][sub] = __builtin_amdgcn_mfma_f32_16x16x32_bf16(a8, bf, acc_hn[rg][sub], 0, 0, 0);
                    else
                        acc_in[rg][sub] = __builtin_amdgcn_mfma_f32_16x16x32_bf16(a8, bf, acc_in[rg][sub], 0, 0, 0);
                }
            }
        }
    }
#undef STAGEP
#undef PKS

#pragma unroll
    for (int sub = 0; sub < 4; ++sub) {
        int c = wn * 64 + sub * 16 + lr;
        float brz_r = bih[c] + bhh[c];
        float brz_z = bih[FP + c] + bhh[FP + c];
        float bin_ = bih[2 * FP + c];
        float bhn = bhh[2 * FP + c];
#pragma unroll
        for (int rg = 0; rg < 2; ++rg) {
#pragma unroll
            for (int q = 0; q < 4; ++q) {
                int row = rh * 32 + rg * 16 + lk * 4 + q;
                int m = abase + row;                     // molecule index
                size_t idx = (size_t)m * FP + c;
                float hold = bf2f(LDA_READ1(1, row, c));
                float r = 1.f / (1.f + expf(-(acc_rz[rg][0 * 4 + sub][q] + brz_r)));
                float z = 1.f / (1.f + expf(-(acc_rz[rg][1 * 4 + sub][q] + brz_z)));
                float n = tanhf(acc_in[rg][sub][q] + bin_ + r * (acc_hn[rg][sub][q] + bhn));
                float hn = (1.f - z) * n + z * hold;
                o_unb[(size_t)(step + 1) * (BB * FP) + idx] = hn;
                o_mfv[(size_t)(step + 1) * (BB * FP) + idx] = fmaxf(hn, 0.f);
                molF[idx] = hn;
                MOLFb[idx] = f2bf(hn);
                if (step == TT - 1) o_molfeat[idx] = hn;
            }
        }
    }
#undef LDA_READ
#undef LDA_READ1
}

extern "C" void kernel_launch(void* const* d_in, const int* in_sizes, int n_in,
                              void* d_out, int out_size, void* d_ws, size_t ws_size,
                              hipStream_t stream) {
    const float* atom_list = (const float*)d_in[0];
    const float* bond_list = (const float*)d_in[1];
    const int*   adeg      = (const int*)d_in[2];
    const int*   bdeg      = (const int*)d_in[3];
    const float* amask     = (const float*)d_in[4];
    const float* atom_fc_W = (const float*)d_in[5];
    const float* atom_fc_b = (const float*)d_in[6];
    const float* nfc_W     = (const float*)d_in[7];
    const float* nfc_b     = (const float*)d_in[8];
    const float* gwih      = (const float*)d_in[9];
    const float* gwhh      = (const float*)d_in[10];
    const float* gbih      = (const float*)d_in[11];
    const float* gbhh      = (const float*)d_in[12];
    const float* alW       = (const float*)d_in[13];
    const float* alb       = (const float*)d_in[14];
    const float* atW       = (const float*)d_in[15];
    const float* atb       = (const float*)d_in[16];
    const float* mgwih     = (const float*)d_in[17];
    const float* mgwhh     = (const float*)d_in[18];
    const float* mgbih     = (const float*)d_in[19];
    const float* mgbhh     = (const float*)d_in[20];
    const float* malW      = (const float*)d_in[21];
    const float* malb      = (const float*)d_in[22];
    const float* matW      = (const float*)d_in[23];
    const float* matb      = (const float*)d_in[24];

    const size_t BLF = (size_t)BB * LL * FP;
    float* out = (float*)d_out;
    float* O0 = out;                                 // atom_feature / h (fp32)
    float* O1 = out + BLF;                           // afv (4,B,L,FP)
    float* O2 = O1 + 4 * BLF;                        // awv (3,B,L,K)
    float* O3 = O2 + (size_t)RR * BB * LL * KK;      // mfv
    float* O4 = O3 + (size_t)(TT + 1) * BB * FP;     // mol_unb
    float* O5 = O4 + (size_t)(TT + 1) * BB * FP;     // mawv
    float* O6 = O5 + (size_t)TT * BB * LL;           // mol_feature

    // ws layout
    float* ws = (float*)d_ws;
    short* XB   = (short*)ws;                        // BLF shorts: wn d0 bf16
    short* XB2  = XB + BLF;                          // BLF shorts: ctx bf16
    short* HBb  = XB + 2 * BLF;                      // BLF shorts: h bf16
    short* ACTB = XB + 3 * BLF;                      // BLF shorts: relu(h) bf16
    float* rest = ws + 2 * BLF;
    short* ApreB = (short*)rest;                     // BLF shorts
    float* SW    = rest + BLF / 2;                   // B*L floats
    float* MOLF  = SW + (size_t)BB * LL;
    float* WafcT = MOLF + (size_t)BB * FP;
    float* WnT   = WafcT + AA * FP;
    float* MWaT  = WnT + (AA + BDD) * FP;
    short* MolGW = (short*)(MWaT + (size_t)FP * FP);    // 2*(8*48*512) shorts
    short* GW    = MolGW + (size_t)2 * 8 * 48 * 512;    // RR*2*(8*48*512) shorts
    short* WaF   = GW + (size_t)RR * 2 * 8 * 48 * 512;  // RR*(8*16*512) shorts
    short* MCTXb = WaF + (size_t)RR * 8 * 16 * 512;     // BB*FP shorts
    short* MOLFb = MCTXb + (size_t)BB * FP;             // BB*FP shorts
    float* S2g   = (float*)(MOLFb + (size_t)BB * FP);   // BB*LL floats
    (void)ws_size; (void)in_sizes; (void)n_in; (void)out_size;

    auto tr = [&](const float* src, float* dst, int O, int I) {
        int n = O * I;
        k_transpose<<<(n + 255) / 256, 256, 0, stream>>>(src, dst, O, I);
    };
    tr(atom_fc_W, WafcT, FP, AA);
    tr(nfc_W, WnT, FP, AA + BDD);
    tr(matW, MWaT, FP, FP);

    {
        int n = RR * 2 * 8 * 48 * 512;
        k_prep_gruw<<<(n + 255) / 256, 256, 0, stream>>>(gwih, gwhh, GW);
        int n2 = RR * 8 * 16 * 512;
        k_prep_waf<<<(n2 + 255) / 256, 256, 0, stream>>>(atW, WaF);
        int n3 = 2 * 8 * 48 * 512;
        k_prep_molfrag<<<(n3 + 255) / 256, 256, 0, stream>>>(mgwih, mgwhh, MolGW);
    }

    k_atom_pre<<<BB * LL / 8, 256, 0, stream>>>(atom_list, WafcT, atom_fc_b,
                                                WnT, nfc_b, O1, O0, HBb, ApreB);

    const size_t wblk = (size_t)8 * 48 * 512;
    for (int d = 0; d < RR; ++d) {
        if (d == 0) {
            k_awn_d0<<<BB * 2, 512, 0, stream>>>(HBb, ApreB, bond_list, adeg, bdeg,
                    WnT, alW, alb, XB, SW, O2);
            k_ctx_mfma<<<BB * LL / 32, 512, 0, stream>>>(XB, SW, WaF,
                    atb, XB2);
        } else {
            k_actx<<<BB, 512, 0, stream>>>(d, ACTB, adeg,
                    alW, alb, WaF, atb,
                    XB2, O2 + (size_t)d * BB * LL * KK);
        }
        if (d == RR - 1) {
            k_gru_mfma<1><<<BB * LL / 64, 512, 0, stream>>>(XB2, HBb, O0,
                    GW + (size_t)(d * 2 + 0) * wblk, GW + (size_t)(d * 2 + 1) * wblk,
                    gbih + (size_t)d * 768, gbhh + (size_t)d * 768,
                    O1 + (size_t)(d + 1) * BLF, HBb, ACTB);
        } else {
            k_gru_mfma<0><<<BB * LL / 64, 512, 0, stream>>>(XB2, HBb, O0,
                    GW + (size_t)(d * 2 + 0) * wblk, GW + (size_t)(d * 2 + 1) * wblk,
                    gbih + (size_t)d * 768, gbhh + (size_t)d * 768,
                    O1 + (size_t)(d + 1) * BLF, HBb, ACTB);
        }
    }

    const float* actFin = O1 + (size_t)RR * BLF;
    k_mol_reduce<<<BB, 256, 0, stream>>>(O0, actFin, amask, malW,
                                         O4, O3, MOLF, MOLFb, S2g);
    for (int st = 0; st < TT; ++st) {
        k_mstep<<<BB, 256, 0, stream>>>(st, actFin, MOLF, amask, S2g,
                malW, malb, MWaT, matb, MCTXb, O5);
        k_mol_gru<<<4, 512, 0, stream>>>(st, MCTXb, MOLFb,
                MolGW, MolGW + wblk, mgbih, mgbhh,
                O4, O3, MOLF, MOLFb, O6);
    }
}

// Round 15
// 541.163 us; speedup vs baseline: 1.8247x; 1.0526x over previous
//
#include <hip/hip_runtime.h>
#include <hip/hip_bf16.h>

// Dims
#define BB 256
#define LL 128
#define AA 39
#define BDD 10
#define KK 6
#define MM 256
#define FP 256
#define RR 3
#define TT 2

using short8  = __attribute__((ext_vector_type(8))) short;
using short4v = __attribute__((ext_vector_type(4))) short;
using f32x4   = __attribute__((ext_vector_type(4))) float;
using f32x2   = __attribute__((ext_vector_type(2))) float;

__device__ __forceinline__ short f2bf(float f) {
    union { float f; unsigned u; } v; v.f = f;
    unsigned u = v.u;
    u += 0x7fffu + ((u >> 16) & 1u);   // round-to-nearest-even
    return (short)(u >> 16);
}
__device__ __forceinline__ float bf2f(short s) {
    union { unsigned u; float f; } v; v.u = ((unsigned)(unsigned short)s) << 16;
    return v.f;
}
__device__ __forceinline__ float wred64(float v) {
#pragma unroll
    for (int off = 32; off >= 1; off >>= 1) v += __shfl_xor(v, off);
    return v;
}

#define GLL(gp, lp) __builtin_amdgcn_global_load_lds( \
    (const __attribute__((address_space(1))) void*)(gp), \
    (__attribute__((address_space(3))) void*)(lp), 16, 0, 0)

// ---------------- transpose ----------------
__global__ __launch_bounds__(256) void k_transpose(const float* __restrict__ src,
                                                   float* __restrict__ dst, int O, int I) {
    int idx = blockIdx.x * 256 + threadIdx.x;
    if (idx >= O * I) return;
    int o = idx / I, i = idx - o * I;
    dst[i * O + o] = src[idx];
}

// ---------------- pack GRU weights: [d][mat][ks(8)][nt(48)][lane][8] ----------------
__global__ __launch_bounds__(256) void k_prep_gruw(const float* __restrict__ gwih,
                                                   const float* __restrict__ gwhh,
                                                   short* __restrict__ out) {
    int idx = blockIdx.x * 256 + threadIdx.x;
    if (idx >= RR * 2 * 8 * 48 * 512) return;
    int j = idx & 7;
    int lane = (idx >> 3) & 63;
    int blk = idx >> 9;
    int nt = blk % 48;
    int ks = (blk / 48) % 8;
    int mat = (blk / (48 * 8)) % 2;
    int d = blk / (48 * 8 * 2);
    int n = nt * 16 + (lane & 15);
    int k = ks * 32 + (lane >> 4) * 8 + j;
    const float* W = mat ? gwhh : gwih;
    out[idx] = f2bf(W[((size_t)d * 768 + n) * FP + k]);
}

// ---------------- pack mol GRU weights: [mat][ks(8)][nt(48)][lane][8] ----------------
__global__ __launch_bounds__(256) void k_prep_molfrag(const float* __restrict__ mih,
                                                      const float* __restrict__ mhh,
                                                      short* __restrict__ out) {
    int idx = blockIdx.x * 256 + threadIdx.x;
    if (idx >= 2 * 8 * 48 * 512) return;
    int j = idx & 7;
    int lane = (idx >> 3) & 63;
    int blk = idx >> 9;
    int nt = blk % 48;
    int ks = (blk / 48) % 8;
    int mat = blk / (48 * 8);
    int n = nt * 16 + (lane & 15);
    int k = ks * 32 + (lane >> 4) * 8 + j;
    const float* W = mat ? mhh : mih;
    out[idx] = f2bf(W[(size_t)n * FP + k]);
}

// ---------------- pack attend weights: [d][ks(8)][nt(16)][lane][8] ----------------
__global__ __launch_bounds__(256) void k_prep_waf(const float* __restrict__ atW,
                                                  short* __restrict__ out) {
    int idx = blockIdx.x * 256 + threadIdx.x;
    if (idx >= RR * 8 * 16 * 512) return;
    int j = idx & 7;
    int lane = (idx >> 3) & 63;
    int blk = idx >> 9;
    int nt = blk % 16;
    int ks = (blk / 16) % 8;
    int d = blk / 128;
    int n = nt * 16 + (lane & 15);
    int k = ks * 32 + (lane >> 4) * 8 + j;
    out[idx] = f2bf(atW[(size_t)d * FP * FP + (size_t)n * FP + k]);
}

// ---------------- fused atom fc + neighbor-fc atom part ----------------
__global__ __launch_bounds__(256) void k_atom_pre(const float* __restrict__ atom_list,
                                                  const float* __restrict__ WafcT,
                                                  const float* __restrict__ afc_b,
                                                  const float* __restrict__ WnT,
                                                  const float* __restrict__ bn,
                                                  float* __restrict__ out_pre,
                                                  short* __restrict__ hb16,
                                                  short* __restrict__ ApreB) {
    int g0 = blockIdx.x * 8;
    int t = threadIdx.x;
    __shared__ float x[8][AA];
    for (int i = t; i < 8 * AA; i += 256) x[i / AA][i % AA] = atom_list[(size_t)g0 * AA + i];
    __syncthreads();
    float a1[8], a2[8];
    float b1 = afc_b[t], b2 = bn[t];
#pragma unroll
    for (int a = 0; a < 8; ++a) { a1[a] = b1; a2[a] = b2; }
    for (int i = 0; i < AA; ++i) {
        float w1 = WafcT[i * FP + t];
        float w2 = WnT[i * FP + t];
#pragma unroll
        for (int a = 0; a < 8; ++a) { a1[a] += x[a][i] * w1; a2[a] += x[a][i] * w2; }
    }
#pragma unroll
    for (int a = 0; a < 8; ++a) {
        size_t idx = (size_t)(g0 + a) * FP + t;
        out_pre[idx] = a1[a];
        hb16[idx] = f2bf(fmaxf(a1[a], 0.f));   // h0 = relu(pre); O0 write is dead (gru<1> overwrites)
        ApreB[idx] = f2bf(a2[a]);
    }
}

// ---------- fused d0 attention+ctx: 1 block/molecule, bond terms, 1-pass nf ----------
__global__ __launch_bounds__(512) void k_actx_d0(
        const short* __restrict__ ACTB,      // relu(h0) bf16 (self dots, global)
        const short* __restrict__ ApreB,     // neighbor-fc atom preact bf16
        const float* __restrict__ bond_list,
        const int* __restrict__ adeg, const int* __restrict__ bdeg,
        const float* __restrict__ WnT,       // bond rows AA..AA+BDD-1
        const float* __restrict__ alW, const float* __restrict__ alb,
        const short* __restrict__ WaF, const float* __restrict__ atb,
        short* __restrict__ ctx_out, float* __restrict__ awv_out) {
    __shared__ __align__(16) short aS[32768];     // 64 KB ApreB slab (swizzled)
    __shared__ __align__(16) short cS[32768];     // 64 KB wn slab (swizzled)
    __shared__ int jxS[LL * KK];
    __shared__ int bxS[LL * KK];
    __shared__ float swS[LL];

    const int b = blockIdx.x;
    const int t = threadIdx.x;
    const int wave = t >> 6, lane = t & 63;
    const int lr = lane & 15, lk = lane >> 4;

#define SLAB_OFF(r, cb) ((((r) * 512 + (cb))) ^ ((((r) & 7)) << 4))
#define A4R(r, c)  (*(const short4v*)((const char*)aS + SLAB_OFF(r, (c) * 2)))
#define C8R(r, c)  (*(const short8*)((const char*)cS + SLAB_OFF(r, (c) * 2)))
#define CW4(r, c, v) (*(short4v*)((char*)cS + SLAB_OFF(r, (c) * 2)) = (v))

    {
        const char* src = (const char*)(ApreB + (size_t)b * LL * FP);
#pragma unroll
        for (int it = 0; it < 8; ++it) {
            int off = it * 8192 + wave * 1024 + lane * 16;
            int so = off ^ (((off >> 9) & 7) << 4);
            GLL(src + so, (char*)aS + off);
        }
        for (int i = t; i < LL * KK; i += 512) {
            jxS[i] = adeg[b * LL * KK + i];
            bxS[i] = bdeg[b * LL * KK + i];
        }
    }

    f32x4 w0 = *(const f32x4*)(alW + lane * 4);
    f32x4 w1 = *(const f32x4*)(alW + FP + lane * 4);
    float bias = alb[0];

    float wnt[BDD][4];
#pragma unroll
    for (int i = 0; i < BDD; ++i) {
        f32x4 v = *(const f32x4*)(WnT + (AA + i) * FP + lane * 4);
#pragma unroll
        for (int q = 0; q < 4; ++q) wnt[i][q] = v[q];
    }
    __syncthreads();   // staging complete

    // one pass: nf (regs) -> scores -> softmax -> wn -> cS
    for (int ai = 0; ai < 16; ++ai) {
        const int a = wave * 16 + ai;
        const int ga = b * LL + a;

        short4v sv = *(const short4v*)(ACTB + (size_t)ga * FP + lane * 4);
        float ss = wred64(bf2f(sv[0]) * w0[0] + bf2f(sv[1]) * w0[1] +
                          bf2f(sv[2]) * w0[2] + bf2f(sv[3]) * w0[3]);

        int jx[KK];
#pragma unroll
        for (int k = 0; k < KK; ++k) jx[k] = jxS[a * KK + k];

        float nf[KK][4];
        float sc[KK];
#pragma unroll
        for (int k = 0; k < KK; ++k) {
            short4v nv = A4R(jx[k], lane * 4);
            float f0 = bf2f(nv[0]), f1 = bf2f(nv[1]), f2 = bf2f(nv[2]), f3 = bf2f(nv[3]);
            int bi = bxS[a * KK + k];
            const float* bp = bond_list + ((size_t)b * MM + bi) * BDD;
            float bb[BDD];
#pragma unroll
            for (int i = 0; i < 5; ++i) {
                f32x2 v2 = *(const f32x2*)(bp + 2 * i);
                bb[2 * i] = v2[0]; bb[2 * i + 1] = v2[1];
            }
            float b0 = 0.f, b1 = 0.f, b2 = 0.f, b3 = 0.f;
#pragma unroll
            for (int i = 0; i < BDD; ++i) {
                b0 += bb[i] * wnt[i][0]; b1 += bb[i] * wnt[i][1];
                b2 += bb[i] * wnt[i][2]; b3 += bb[i] * wnt[i][3];
            }
            f0 = fmaxf(f0 + b0, 0.f); f1 = fmaxf(f1 + b1, 0.f);
            f2 = fmaxf(f2 + b2, 0.f); f3 = fmaxf(f3 + b3, 0.f);
            nf[k][0] = f0; nf[k][1] = f1; nf[k][2] = f2; nf[k][3] = f3;
            float s2 = wred64(f0 * w1[0] + f1 * w1[1] + f2 * w1[2] + f3 * w1[3]);
            float s = fmaxf(ss + s2 + bias, 0.f);
            if (jx[k] == LL - 1) s -= 9.0f;
            sc[k] = s;
        }

        float m = sc[0];
#pragma unroll
        for (int k = 1; k < KK; ++k) m = fmaxf(m, sc[k]);
        float e[KK], den = 0.f;
#pragma unroll
        for (int k = 0; k < KK; ++k) { e[k] = expf(sc[k] - m); den += e[k]; }
        float aw[KK], sumaw = 0.f;
#pragma unroll
        for (int k = 0; k < KK; ++k) {
            aw[k] = (jx[k] == LL - 1) ? 0.f : e[k] / den;
            sumaw += aw[k];
        }
        if (lane < KK) {
            float av = aw[0];
#pragma unroll
            for (int k = 1; k < KK; ++k) if (lane == k) av = aw[k];
            awv_out[(size_t)ga * KK + lane] = av;
        }
        if (lane == 0) swS[a] = sumaw;

        short4v wo;
#pragma unroll
        for (int q = 0; q < 4; ++q) {
            float w = 0.f;
#pragma unroll
            for (int k = 0; k < KK; ++k) w += aw[k] * nf[k][q];
            wo[q] = f2bf(w);
        }
        CW4(a, lane * 4, wo);
    }
    __syncthreads();

    // ctx GEMM: cS(wn) @ Wa^T + sumaw*ab -> relu -> ctx_out (d=0 weights)
    {
        const int rg = wave >> 1, csl = wave & 1;
        f32x4 acc[2][8] = {};
        const short8* wb = (const short8*)WaF;
        for (int ks = 0; ks < 8; ++ks) {
            short8 a0 = C8R(rg * 32 + lr, ks * 32 + lk * 8);
            short8 a1 = C8R(rg * 32 + 16 + lr, ks * 32 + lk * 8);
#pragma unroll
            for (int nt2 = 0; nt2 < 8; ++nt2) {
                short8 bf = wb[(size_t)(ks * 16 + csl * 8 + nt2) * 64 + lane];
                acc[0][nt2] = __builtin_amdgcn_mfma_f32_16x16x32_bf16(a0, bf, acc[0][nt2], 0, 0, 0);
                acc[1][nt2] = __builtin_amdgcn_mfma_f32_16x16x32_bf16(a1, bf, acc[1][nt2], 0, 0, 0);
            }
        }
#pragma unroll
        for (int rt = 0; rt < 2; ++rt)
#pragma unroll
        for (int nt2 = 0; nt2 < 8; ++nt2) {
            int col = csl * 128 + nt2 * 16 + lr;
            float abv = atb[col];
#pragma unroll
            for (int q = 0; q < 4; ++q) {
                int row = rg * 32 + rt * 16 + lk * 4 + q;
                float v = acc[rt][nt2][q] + swS[row] * abv;
                ctx_out[((size_t)b * LL + row) * FP + col] = f2bf(fmaxf(v, 0.f));
            }
        }
    }
#undef SLAB_OFF
#undef A4R
#undef C8R
#undef CW4
}

// ---------- fused attention+ctx for d>0: 1 block/molecule (round-13, verified) ----------
__global__ __launch_bounds__(512) void k_actx(int d,
        const short* __restrict__ ACTB,
        const int* __restrict__ adeg,
        const float* __restrict__ alW, const float* __restrict__ alb,
        const short* __restrict__ WaF, const float* __restrict__ atb,
        short* __restrict__ ctx_out, float* __restrict__ awv_out) {
    __shared__ __align__(16) short aS[32768];     // 64 KB act slab (swizzled)
    __shared__ __align__(16) short cS[32768];     // 64 KB wn slab (swizzled)
    __shared__ int   jxS[LL * KK];
    __shared__ float awS[LL * KK];
    __shared__ float swS[LL];

    const int b = blockIdx.x;
    const int t = threadIdx.x;
    const int wave = t >> 6, lane = t & 63;
    const int lr = lane & 15, lk = lane >> 4;

#define SLAB_OFF(r, cb) ((((r) * 512 + (cb))) ^ ((((r) & 7)) << 4))
#define A4R(r, c)  (*(const short4v*)((const char*)aS + SLAB_OFF(r, (c) * 2)))
#define C8R(r, c)  (*(const short8*)((const char*)cS + SLAB_OFF(r, (c) * 2)))
#define CW4(r, c, v) (*(short4v*)((char*)cS + SLAB_OFF(r, (c) * 2)) = (v))

    {
        const char* src = (const char*)(ACTB + (size_t)b * LL * FP);
#pragma unroll
        for (int it = 0; it < 8; ++it) {
            int off = it * 8192 + wave * 1024 + lane * 16;
            int so = off ^ (((off >> 9) & 7) << 4);
            GLL(src + so, (char*)aS + off);
        }
        for (int i = t; i < LL * KK; i += 512) jxS[i] = adeg[b * LL * KK + i];
    }
    __syncthreads();

    {
        f32x4 w0 = *(const f32x4*)(alW + (size_t)d * 2 * FP + lane * 4);
        f32x4 w1 = *(const f32x4*)(alW + (size_t)d * 2 * FP + FP + lane * 4);
        float bias = alb[d];
        for (int ai = 0; ai < 16; ++ai) {
            int a = wave * 16 + ai;
            short4v sv = A4R(a, lane * 4);
            float ss = wred64(bf2f(sv[0]) * w0[0] + bf2f(sv[1]) * w0[1] +
                              bf2f(sv[2]) * w0[2] + bf2f(sv[3]) * w0[3]);
            float sc[KK]; int jx[KK];
#pragma unroll
            for (int k = 0; k < KK; ++k) {
                int j = jxS[a * KK + k]; jx[k] = j;
                short4v nv = A4R(j, lane * 4);
                float s2 = wred64(bf2f(nv[0]) * w1[0] + bf2f(nv[1]) * w1[1] +
                                  bf2f(nv[2]) * w1[2] + bf2f(nv[3]) * w1[3]);
                float s = fmaxf(ss + s2 + bias, 0.f);
                if (j == LL - 1) s -= 9.0f;
                sc[k] = s;
            }
            float m = sc[0];
#pragma unroll
            for (int k = 1; k < KK; ++k) m = fmaxf(m, sc[k]);
            float e[KK], den = 0.f;
#pragma unroll
            for (int k = 0; k < KK; ++k) { e[k] = expf(sc[k] - m); den += e[k]; }
            float aw[KK], sumaw = 0.f;
#pragma unroll
            for (int k = 0; k < KK; ++k) {
                aw[k] = (jx[k] == LL - 1) ? 0.f : e[k] / den;
                sumaw += aw[k];
            }
            if (lane < KK) {
                float av = aw[0];
#pragma unroll
                for (int k = 1; k < KK; ++k) if (lane == k) av = aw[k];
                awS[a * KK + lane] = av;
                awv_out[((size_t)b * LL + a) * KK + lane] = av;
            }
            if (lane == 0) swS[a] = sumaw;
        }
    }
    __syncthreads();

    for (int ai = 0; ai < 16; ++ai) {
        int a = wave * 16 + ai;
        float a0 = 0.f, a1 = 0.f, a2 = 0.f, a3 = 0.f;
#pragma unroll
        for (int k = 0; k < KK; ++k) {
            float awv = awS[a * KK + k];
            short4v nv = A4R(jxS[a * KK + k], lane * 4);
            a0 += awv * bf2f(nv[0]);
            a1 += awv * bf2f(nv[1]);
            a2 += awv * bf2f(nv[2]);
            a3 += awv * bf2f(nv[3]);
        }
        short4v wo; wo[0] = f2bf(a0); wo[1] = f2bf(a1); wo[2] = f2bf(a2); wo[3] = f2bf(a3);
        CW4(a, lane * 4, wo);
    }
    __syncthreads();

    {
        const int rg = wave >> 1, csl = wave & 1;
        f32x4 acc[2][8] = {};
        const short8* wb = (const short8*)(WaF + (size_t)d * 8 * 16 * 512);
        for (int ks = 0; ks < 8; ++ks) {
            short8 a0 = C8R(rg * 32 + lr, ks * 32 + lk * 8);
            short8 a1 = C8R(rg * 32 + 16 + lr, ks * 32 + lk * 8);
#pragma unroll
            for (int nt2 = 0; nt2 < 8; ++nt2) {
                short8 bf = wb[(size_t)(ks * 16 + csl * 8 + nt2) * 64 + lane];
                acc[0][nt2] = __builtin_amdgcn_mfma_f32_16x16x32_bf16(a0, bf, acc[0][nt2], 0, 0, 0);
                acc[1][nt2] = __builtin_amdgcn_mfma_f32_16x16x32_bf16(a1, bf, acc[1][nt2], 0, 0, 0);
            }
        }
#pragma unroll
        for (int rt = 0; rt < 2; ++rt)
#pragma unroll
        for (int nt2 = 0; nt2 < 8; ++nt2) {
            int col = csl * 128 + nt2 * 16 + lr;
            float abv = atb[d * FP + col];
#pragma unroll
            for (int q = 0; q < 4; ++q) {
                int row = rg * 32 + rt * 16 + lk * 4 + q;
                float v = acc[rt][nt2][q] + swS[row] * abv;
                ctx_out[((size_t)b * LL + row) * FP + col] = f2bf(fmaxf(v, 0.f));
            }
        }
    }
#undef SLAB_OFF
#undef A4R
#undef C8R
#undef CW4
}

// ---------------- fused MFMA GRU v6: counted-vmcnt pipeline, lean I/O ----------
template<int LAST>
__global__ __launch_bounds__(512) void k_gru_mfma(
        const short* __restrict__ XB,     // ctx bf16
        const short* __restrict__ HBl,    // h bf16 (read)
        float* __restrict__ hbuf,         // h fp32 (written only when LAST)
        const short* __restrict__ Bih,    // frag-major (8,48,64,8)
        const short* __restrict__ Bhh,
        const float* __restrict__ bih, const float* __restrict__ bhh,
        float* __restrict__ act_out,
        short* __restrict__ HB_out,
        short* __restrict__ ACT_out) {
    __shared__ short ldsB[3][12288];      // 3 x 24 KB
    __shared__ short ldsA[2][16384];      // x,h slabs: 2 x 32 KB (swizzled)
    const int t = threadIdx.x;
    const int wave = t >> 6, lane = t & 63;
    const int rh = wave >> 2;
    const int wn = wave & 3;
    const int lr = lane & 15, lk = lane >> 4;
    const int bid = blockIdx.x;
    const int kofs = bid & 7;
    const int abase = bid * 64;

#define PKS(p)  ((((p) >> 2) + kofs) & 7)
#define STAGEP(p) do { \
        const short* base_ = ((((p) >> 1) & 1) ? Bhh : Bih) + (size_t)PKS(p) * 24576; \
        const int h_ = (p) & 1; \
        _Pragma("unroll") \
        for (int e = 0; e < 3; ++e) { \
            int j = wave * 3 + e; \
            int nt = 4 * (j >> 1) + 2 * h_ + (j & 1); \
            GLL(base_ + nt * 512 + lane * 8, &ldsB[(p) % 3][j * 512]); \
        } } while (0)
#define LDA_READ(s, r, c) (*(const short8*)((const char*)ldsA[s] + \
        ((((r) * 512 + (c) * 2)) ^ ((((r) & 7)) << 4))))
#define LDA_READ1(s, r, c) (*(const short*)((const char*)ldsA[s] + \
        ((((r) * 512 + (c) * 2)) ^ ((((r) & 7)) << 4))))

    {
        const char* xsrc = (const char*)(XB + (size_t)abase * FP);
        const char* hsrc = (const char*)(HBl + (size_t)abase * FP);
#pragma unroll
        for (int it = 0; it < 4; ++it) {
            int off = it * 8192 + wave * 1024 + lane * 16;
            int src = off ^ (((off >> 9) & 7) << 4);
            GLL(xsrc + src, (char*)ldsA[0] + off);
            GLL(hsrc + src, (char*)ldsA[1] + off);
        }
    }
    STAGEP(0);
    STAGEP(1);

    f32x4 acc_rz[2][8] = {};
    f32x4 acc_in[2][4] = {};
    f32x4 acc_hn[2][4] = {};

    short8 ax0{}, ah0{}, ax1{}, ah1{};
#pragma unroll
    for (int p = 0; p < 32; ++p) {
        if (p < 31) { asm volatile("s_waitcnt vmcnt(3)" ::: "memory"); }
        else        { asm volatile("s_waitcnt vmcnt(0)" ::: "memory"); }
        __builtin_amdgcn_s_barrier();
        __builtin_amdgcn_sched_barrier(0);
        if (p < 30) STAGEP(p + 2);
        const int h_ = p & 1;
        const int mat = (p >> 1) & 1;
        if ((p & 3) == 0) {
            int ks = PKS(p);
            int c = ks * 32 + lk * 8;
            ax0 = LDA_READ(0, rh * 32 + lr, c);
            ah0 = LDA_READ(1, rh * 32 + lr, c);
            ax1 = LDA_READ(0, rh * 32 + 16 + lr, c);
            ah1 = LDA_READ(1, rh * 32 + 16 + lr, c);
        }
#pragma unroll
        for (int rg = 0; rg < 2; ++rg) {
            const short8 a8 = mat ? (rg ? ah1 : ah0) : (rg ? ax1 : ax0);
#pragma unroll
            for (int g = 0; g < 3; ++g) {
#pragma unroll
                for (int s2 = 0; s2 < 2; ++s2) {
                    const int sub = 2 * h_ + s2;
                    const int j = ((4 * g + wn) << 1) | s2;
                    short8 bf = *(const short8*)(&ldsB[p % 3][j * 512 + lane * 8]);
                    if (g < 2)
                        acc_rz[rg][g * 4 + sub] = __builtin_amdgcn_mfma_f32_16x16x32_bf16(a8, bf, acc_rz[rg][g * 4 + sub], 0, 0, 0);
                    else if (mat)
                        acc_hn[rg][sub] = __builtin_amdgcn_mfma_f32_16x16x32_bf16(a8, bf, acc_hn[rg][sub], 0, 0, 0);
                    else
                        acc_in[rg][sub] = __builtin_amdgcn_mfma_f32_16x16x32_bf16(a8, bf, acc_in[rg][sub], 0, 0, 0);
                }
            }
        }
    }
#undef STAGEP
#undef PKS

#pragma unroll
    for (int sub = 0; sub < 4; ++sub) {
        int c = wn * 64 + sub * 16 + lr;
        float brz_r = bih[c] + bhh[c];
        float brz_z = bih[FP + c] + bhh[FP + c];
        float bin_ = bih[2 * FP + c];
        float bhn = bhh[2 * FP + c];
#pragma unroll
        for (int rg = 0; rg < 2; ++rg) {
#pragma unroll
            for (int q = 0; q < 4; ++q) {
                int row = rh * 32 + rg * 16 + lk * 4 + q;
                int atom = abase + row;
                size_t idx = (size_t)atom * FP + c;
                float hold = bf2f(LDA_READ1(1, row, c));
                float r = 1.f / (1.f + expf(-(acc_rz[rg][0 * 4 + sub][q] + brz_r)));
                float z = 1.f / (1.f + expf(-(acc_rz[rg][1 * 4 + sub][q] + brz_z)));
                float n = tanhf(acc_in[rg][sub][q] + bin_ + r * (acc_hn[rg][sub][q] + bhn));
                float hn = (1.f - z) * n + z * hold;
                float rl = fmaxf(hn, 0.f);
                act_out[idx] = rl;
                if constexpr (LAST) {
                    hbuf[idx] = hn;
                } else {
                    HB_out[idx] = f2bf(hn);
                    ACT_out[idx] = f2bf(rl);
                }
            }
        }
    }
#undef LDA_READ
#undef LDA_READ1
}

// ---------------- mol reduce + S2 precompute ----------------
__global__ __launch_bounds__(256) void k_mol_reduce(const float* __restrict__ hbuf,
                                                    const float* __restrict__ act,
                                                    const float* __restrict__ mask,
                                                    const float* __restrict__ malW,
                                                    float* __restrict__ o_unb0,
                                                    float* __restrict__ o_mfv0,
                                                    float* __restrict__ molF,
                                                    short* __restrict__ MOLFb,
                                                    float* __restrict__ S2g) {
    int b = blockIdx.x, t = threadIdx.x;
    int wave = t >> 6, lane = t & 63;
    float s1 = 0.f, s2 = 0.f;
    for (int l = 0; l < LL; ++l) {
        float mk = mask[b * LL + l];
        s1 += hbuf[((size_t)b * LL + l) * FP + t] * mk;
        s2 += act[((size_t)b * LL + l) * FP + t] * mk;
    }
    o_unb0[b * FP + t] = s1;
    o_mfv0[b * FP + t] = s2;
    molF[b * FP + t] = s2;
    MOLFb[b * FP + t] = f2bf(s2);

    for (int l = wave; l < LL; l += 4) {
        float v2 = 0.f;
#pragma unroll
        for (int q = 0; q < 4; ++q) {
            int i = lane + 64 * q;
            v2 += act[((size_t)b * LL + l) * FP + i] * malW[FP + i];
        }
        v2 = wred64(v2);
        if (lane == 0) S2g[b * LL + l] = v2;
    }
}

// ---------------- mol step: scores + softmax + rank-1 attend -> mctx bf16 ------
__global__ __launch_bounds__(256) void k_mstep(int step,
        const float* __restrict__ act,
        const float* __restrict__ molF,
        const float* __restrict__ mask,
        const float* __restrict__ S2g,
        const float* __restrict__ malW, const float* __restrict__ malb,
        const float* __restrict__ MWaT, const float* __restrict__ matb,
        short* __restrict__ MCTXb,
        float* __restrict__ o_mawv) {
    int b = blockIdx.x, t = threadIdx.x;
    int wave = t >> 6, lane = t & 63;
    __shared__ float sS[LL], mwS[LL], waS[FP];
    __shared__ float red[4];

    float hprev = molF[b * FP + t];
    float am = fmaxf(hprev, 0.f);

    float v = am * malW[t];
    v = wred64(v);
    if (lane == 0) red[wave] = v;
    __syncthreads();
    float s_self = red[0] + red[1] + red[2] + red[3];

    if (t < LL) {
        float s = fmaxf(s_self + S2g[b * LL + t] + malb[0], 0.f);
        if (mask[b * LL + t] == 0.f) s += -9e8f;
        sS[t] = s;
    }
    __syncthreads();

    float m = -1e30f;
    for (int l = 0; l < LL; ++l) m = fmaxf(m, sS[l]);
    float den = 0.f;
    for (int l = 0; l < LL; ++l) den += expf(sS[l] - m);
    if (t < LL) {
        float w = expf(sS[t] - m) / den * mask[b * LL + t];
        mwS[t] = w;
        o_mawv[(size_t)step * (BB * LL) + b * LL + t] = w;
    }
    __syncthreads();

    float sumaw = 0.f;
    for (int l = 0; l < LL; ++l) sumaw += mwS[l];

    float wa = 0.f;
    for (int l = 0; l < LL; ++l) wa += mwS[l] * act[((size_t)b * LL + l) * FP + t];
    waS[t] = wa;
    __syncthreads();

    float acc = sumaw * matb[t];
    for (int i = 0; i < FP; ++i) acc += waS[i] * MWaT[i * FP + t];
    MCTXb[b * FP + t] = f2bf(fmaxf(acc, 0.f));
}

// ---------------- mol GRU as 256-row MFMA GEMM (4 blocks x 64 rows) ----------
__global__ __launch_bounds__(512) void k_mol_gru(int step,
        const short* __restrict__ XB,     // mctx bf16 (256,FP)
        const short* __restrict__ HBl,    // molF bf16
        const short* __restrict__ Bih,    // frag-major (8,48,64,8)
        const short* __restrict__ Bhh,
        const float* __restrict__ bih, const float* __restrict__ bhh,
        float* __restrict__ o_unb, float* __restrict__ o_mfv,
        float* __restrict__ molF, short* __restrict__ MOLFb,
        float* __restrict__ o_molfeat) {
    __shared__ short ldsB[3][12288];
    __shared__ short ldsA[2][16384];
    const int t = threadIdx.x;
    const int wave = t >> 6, lane = t & 63;
    const int rh = wave >> 2;
    const int wn = wave & 3;
    const int lr = lane & 15, lk = lane >> 4;
    const int bid = blockIdx.x;
    const int kofs = bid & 7;
    const int abase = bid * 64;

#define PKS(p)  ((((p) >> 2) + kofs) & 7)
#define STAGEP(p) do { \
        const short* base_ = ((((p) >> 1) & 1) ? Bhh : Bih) + (size_t)PKS(p) * 24576; \
        const int h_ = (p) & 1; \
        _Pragma("unroll") \
        for (int e = 0; e < 3; ++e) { \
            int j = wave * 3 + e; \
            int nt = 4 * (j >> 1) + 2 * h_ + (j & 1); \
            GLL(base_ + nt * 512 + lane * 8, &ldsB[(p) % 3][j * 512]); \
        } } while (0)
#define LDA_READ(s, r, c) (*(const short8*)((const char*)ldsA[s] + \
        ((((r) * 512 + (c) * 2)) ^ ((((r) & 7)) << 4))))
#define LDA_READ1(s, r, c) (*(const short*)((const char*)ldsA[s] + \
        ((((r) * 512 + (c) * 2)) ^ ((((r) & 7)) << 4))))

    {
        const char* xsrc = (const char*)(XB + (size_t)abase * FP);
        const char* hsrc = (const char*)(HBl + (size_t)abase * FP);
#pragma unroll
        for (int it = 0; it < 4; ++it) {
            int off = it * 8192 + wave * 1024 + lane * 16;
            int src = off ^ (((off >> 9) & 7) << 4);
            GLL(xsrc + src, (char*)ldsA[0] + off);
            GLL(hsrc + src, (char*)ldsA[1] + off);
        }
    }
    STAGEP(0);
    STAGEP(1);

    f32x4 acc_rz[2][8] = {};
    f32x4 acc_in[2][4] = {};
    f32x4 acc_hn[2][4] = {};

    short8 ax0{}, ah0{}, ax1{}, ah1{};
#pragma unroll
    for (int p = 0; p < 32; ++p) {
        if (p < 31) { asm volatile("s_waitcnt vmcnt(3)" ::: "memory"); }
        else        { asm volatile("s_waitcnt vmcnt(0)" ::: "memory"); }
        __builtin_amdgcn_s_barrier();
        __builtin_amdgcn_sched_barrier(0);
        if (p < 30) STAGEP(p + 2);
        const int h_ = p & 1;
        const int mat = (p >> 1) & 1;
        if ((p & 3) == 0) {
            int ks = PKS(p);
            int c = ks * 32 + lk * 8;
            ax0 = LDA_READ(0, rh * 32 + lr, c);
            ah0 = LDA_READ(1, rh * 32 + lr, c);
            ax1 = LDA_READ(0, rh * 32 + 16 + lr, c);
            ah1 = LDA_READ(1, rh * 32 + 16 + lr, c);
        }
#pragma unroll
        for (int rg = 0; rg < 2; ++rg) {
            const short8 a8 = mat ? (rg ? ah1 : ah0) : (rg ? ax1 : ax0);
#pragma unroll
            for (int g = 0; g < 3; ++g) {
#pragma unroll
                for (int s2 = 0; s2 < 2; ++s2) {
                    const int sub = 2 * h_ + s2;
                    const int j = ((4 * g + wn) << 1) | s2;
                    short8 bf = *(const short8*)(&ldsB[p % 3][j * 512 + lane * 8]);
                    if (g < 2)
                        acc_rz[rg][g * 4 + sub] = __builtin_amdgcn_mfma_f32_16x16x32_bf16(a8, bf, acc_rz[rg][g * 4 + sub], 0, 0, 0);
                    else if (mat)
                        acc_hn[rg][sub] = __builtin_amdgcn_mfma_f32_16x16x32_bf16(a8, bf, acc_hn[rg][sub], 0, 0, 0);
                    else
                        acc_in[rg][sub] = __builtin_amdgcn_mfma_f32_16x16x32_bf16(a8, bf, acc_in[rg][sub], 0, 0, 0);
                }
            }
        }
    }
#undef STAGEP
#undef PKS

#pragma unroll
    for (int sub = 0; sub < 4; ++sub) {
        int c = wn * 64 + sub * 16 + lr;
        float brz_r = bih[c] + bhh[c];
        float brz_z = bih[FP + c] + bhh[FP + c];
        float bin_ = bih[2 * FP + c];
        float bhn = bhh[2 * FP + c];
#pragma unroll
        for (int rg = 0; rg < 2; ++rg) {
#pragma unroll
            for (int q = 0; q < 4; ++q) {
                int row = rh * 32 + rg * 16 + lk * 4 + q;
                int m = abase + row;                     // molecule index
                size_t idx = (size_t)m * FP + c;
                float hold = bf2f(LDA_READ1(1, row, c));
                float r = 1.f / (1.f + expf(-(acc_rz[rg][0 * 4 + sub][q] + brz_r)));
                float z = 1.f / (1.f + expf(-(acc_rz[rg][1 * 4 + sub][q] + brz_z)));
                float n = tanhf(acc_in[rg][sub][q] + bin_ + r * (acc_hn[rg][sub][q] + bhn));
                float hn = (1.f - z) * n + z * hold;
                o_unb[(size_t)(step + 1) * (BB * FP) + idx] = hn;
                o_mfv[(size_t)(step + 1) * (BB * FP) + idx] = fmaxf(hn, 0.f);
                molF[idx] = hn;
                MOLFb[idx] = f2bf(hn);
                if (step == TT - 1) o_molfeat[idx] = hn;
            }
        }
    }
#undef LDA_READ
#undef LDA_READ1
}

extern "C" void kernel_launch(void* const* d_in, const int* in_sizes, int n_in,
                              void* d_out, int out_size, void* d_ws, size_t ws_size,
                              hipStream_t stream) {
    const float* atom_list = (const float*)d_in[0];
    const float* bond_list = (const float*)d_in[1];
    const int*   adeg      = (const int*)d_in[2];
    const int*   bdeg      = (const int*)d_in[3];
    const float* amask     = (const float*)d_in[4];
    const float* atom_fc_W = (const float*)d_in[5];
    const float* atom_fc_b = (const float*)d_in[6];
    const float* nfc_W     = (const float*)d_in[7];
    const float* nfc_b     = (const float*)d_in[8];
    const float* gwih      = (const float*)d_in[9];
    const float* gwhh      = (const float*)d_in[10];
    const float* gbih      = (const float*)d_in[11];
    const float* gbhh      = (const float*)d_in[12];
    const float* alW       = (const float*)d_in[13];
    const float* alb       = (const float*)d_in[14];
    const float* atW       = (const float*)d_in[15];
    const float* atb       = (const float*)d_in[16];
    const float* mgwih     = (const float*)d_in[17];
    const float* mgwhh     = (const float*)d_in[18];
    const float* mgbih     = (const float*)d_in[19];
    const float* mgbhh     = (const float*)d_in[20];
    const float* malW      = (const float*)d_in[21];
    const float* malb      = (const float*)d_in[22];
    const float* matW      = (const float*)d_in[23];
    const float* matb      = (const float*)d_in[24];

    const size_t BLF = (size_t)BB * LL * FP;
    float* out = (float*)d_out;
    float* O0 = out;                                 // atom_feature / h (fp32)
    float* O1 = out + BLF;                           // afv (4,B,L,FP)
    float* O2 = O1 + 4 * BLF;                        // awv (3,B,L,K)
    float* O3 = O2 + (size_t)RR * BB * LL * KK;      // mfv
    float* O4 = O3 + (size_t)(TT + 1) * BB * FP;     // mol_unb
    float* O5 = O4 + (size_t)(TT + 1) * BB * FP;     // mawv
    float* O6 = O5 + (size_t)TT * BB * LL;           // mol_feature

    // ws layout
    float* ws = (float*)d_ws;
    short* XB   = (short*)ws;                        // (spare)
    short* XB2  = XB + BLF;                          // BLF shorts: ctx bf16
    short* HBb  = XB + 2 * BLF;                      // BLF shorts: h bf16
    short* ACTB = XB + 3 * BLF;                      // BLF shorts: relu(h) bf16
    float* rest = ws + 2 * BLF;
    short* ApreB = (short*)rest;                     // BLF shorts
    float* SW    = rest + BLF / 2;                   // B*L floats (unused, kept)
    float* MOLF  = SW + (size_t)BB * LL;
    float* WafcT = MOLF + (size_t)BB * FP;
    float* WnT   = WafcT + AA * FP;
    float* MWaT  = WnT + (AA + BDD) * FP;
    short* MolGW = (short*)(MWaT + (size_t)FP * FP);    // 2*(8*48*512) shorts
    short* GW    = MolGW + (size_t)2 * 8 * 48 * 512;    // RR*2*(8*48*512) shorts
    short* WaF   = GW + (size_t)RR * 2 * 8 * 48 * 512;  // RR*(8*16*512) shorts
    short* MCTXb = WaF + (size_t)RR * 8 * 16 * 512;     // BB*FP shorts
    short* MOLFb = MCTXb + (size_t)BB * FP;             // BB*FP shorts
    float* S2g   = (float*)(MOLFb + (size_t)BB * FP);   // BB*LL floats
    (void)ws_size; (void)in_sizes; (void)n_in; (void)out_size;

    auto tr = [&](const float* src, float* dst, int O, int I) {
        int n = O * I;
        k_transpose<<<(n + 255) / 256, 256, 0, stream>>>(src, dst, O, I);
    };
    tr(atom_fc_W, WafcT, FP, AA);
    tr(nfc_W, WnT, FP, AA + BDD);
    tr(matW, MWaT, FP, FP);

    {
        int n = RR * 2 * 8 * 48 * 512;
        k_prep_gruw<<<(n + 255) / 256, 256, 0, stream>>>(gwih, gwhh, GW);
        int n2 = RR * 8 * 16 * 512;
        k_prep_waf<<<(n2 + 255) / 256, 256, 0, stream>>>(atW, WaF);
        int n3 = 2 * 8 * 48 * 512;
        k_prep_molfrag<<<(n3 + 255) / 256, 256, 0, stream>>>(mgwih, mgwhh, MolGW);
    }

    k_atom_pre<<<BB * LL / 8, 256, 0, stream>>>(atom_list, WafcT, atom_fc_b,
                                                WnT, nfc_b, O1, HBb, ApreB);

    const size_t wblk = (size_t)8 * 48 * 512;
    for (int d = 0; d < RR; ++d) {
        if (d == 0) {
            k_actx_d0<<<BB, 512, 0, stream>>>(HBb, ApreB, bond_list, adeg, bdeg,
                    WnT, alW, alb, WaF, atb, XB2, O2);
        } else {
            k_actx<<<BB, 512, 0, stream>>>(d, ACTB, adeg,
                    alW, alb, WaF, atb,
                    XB2, O2 + (size_t)d * BB * LL * KK);
        }
        if (d == RR - 1) {
            k_gru_mfma<1><<<BB * LL / 64, 512, 0, stream>>>(XB2, HBb, O0,
                    GW + (size_t)(d * 2 + 0) * wblk, GW + (size_t)(d * 2 + 1) * wblk,
                    gbih + (size_t)d * 768, gbhh + (size_t)d * 768,
                    O1 + (size_t)(d + 1) * BLF, HBb, ACTB);
        } else {
            k_gru_mfma<0><<<BB * LL / 64, 512, 0, stream>>>(XB2, HBb, O0,
                    GW + (size_t)(d * 2 + 0) * wblk, GW + (size_t)(d * 2 + 1) * wblk,
                    gbih + (size_t)d * 768, gbhh + (size_t)d * 768,
                    O1 + (size_t)(d + 1) * BLF, HBb, ACTB);
        }
    }

    const float* actFin = O1 + (size_t)RR * BLF;
    k_mol_reduce<<<BB, 256, 0, stream>>>(O0, actFin, amask, malW,
                                         O4, O3, MOLF, MOLFb, S2g);
    for (int st = 0; st < TT; ++st) {
        k_mstep<<<BB, 256, 0, stream>>>(st, actFin, MOLF, amask, S2g,
                malW, malb, MWaT, matb, MCTXb, O5);
        k_mol_gru<<<4, 512, 0, stream>>>(st, MCTXb, MOLFb,
                MolGW, MolGW + wblk, mgbih, mgbhh,
                O4, O3, MOLF, MOLFb, O6);
    }
}

// Round 16
// 538.428 us; speedup vs baseline: 1.8340x; 1.0051x over previous
//
#include <hip/hip_runtime.h>
#include <hip/hip_bf16.h>

// Dims
#define BB 256
#define LL 128
#define AA 39
#define BDD 10
#define KK 6
#define MM 256
#define FP 256
#define RR 3
#define TT 2

using short8  = __attribute__((ext_vector_type(8))) short;
using short4v = __attribute__((ext_vector_type(4))) short;
using f32x4   = __attribute__((ext_vector_type(4))) float;
using f32x2   = __attribute__((ext_vector_type(2))) float;

__device__ __forceinline__ short f2bf(float f) {
    union { float f; unsigned u; } v; v.f = f;
    unsigned u = v.u;
    u += 0x7fffu + ((u >> 16) & 1u);   // round-to-nearest-even
    return (short)(u >> 16);
}
__device__ __forceinline__ float bf2f(short s) {
    union { unsigned u; float f; } v; v.u = ((unsigned)(unsigned short)s) << 16;
    return v.f;
}
__device__ __forceinline__ float wred64(float v) {
#pragma unroll
    for (int off = 32; off >= 1; off >>= 1) v += __shfl_xor(v, off);
    return v;
}

#define GLL(gp, lp) __builtin_amdgcn_global_load_lds( \
    (const __attribute__((address_space(1))) void*)(gp), \
    (__attribute__((address_space(3))) void*)(lp), 16, 0, 0)

// ---------------- merged transposes: WafcT, WnT, MWaT ----------------
__global__ __launch_bounds__(256) void k_prep_trans(
        const float* __restrict__ atom_fc_W, const float* __restrict__ nfc_W,
        const float* __restrict__ matW,
        float* __restrict__ WafcT, float* __restrict__ WnT, float* __restrict__ MWaT) {
    const int N1 = FP * AA, N2 = FP * (AA + BDD), N3 = FP * FP;
    int idx = blockIdx.x * 256 + threadIdx.x;
    if (idx < N1) {
        int o = idx / AA, i = idx - o * AA;
        WafcT[i * FP + o] = atom_fc_W[idx];
    } else if (idx < N1 + N2) {
        int r = idx - N1;
        int o = r / (AA + BDD), i = r - o * (AA + BDD);
        WnT[i * FP + o] = nfc_W[r];
    } else if (idx < N1 + N2 + N3) {
        int r = idx - N1 - N2;
        int o = r >> 8, i = r & 255;
        MWaT[i * FP + o] = matW[r];
    }
}

// ---------------- merged packs: GRU frag, attend frag, mol-GRU frag ----------------
__global__ __launch_bounds__(256) void k_prep_pack(
        const float* __restrict__ gwih, const float* __restrict__ gwhh,
        const float* __restrict__ atW,
        const float* __restrict__ mih, const float* __restrict__ mhh,
        short* __restrict__ GW, short* __restrict__ WaF, short* __restrict__ MolGW) {
    const int N1 = RR * 2 * 8 * 48 * 512;   // gru
    const int N2 = RR * 8 * 16 * 512;       // attend
    const int N3 = 2 * 8 * 48 * 512;        // mol gru
    int idx = blockIdx.x * 256 + threadIdx.x;
    if (idx < N1) {
        int j = idx & 7, lane = (idx >> 3) & 63, blk = idx >> 9;
        int nt = blk % 48, ks = (blk / 48) % 8, mat = (blk / 384) % 2, d = blk / 768;
        int n = nt * 16 + (lane & 15);
        int k = ks * 32 + (lane >> 4) * 8 + j;
        const float* W = mat ? gwhh : gwih;
        GW[idx] = f2bf(W[((size_t)d * 768 + n) * FP + k]);
    } else if (idx < N1 + N2) {
        int r = idx - N1;
        int j = r & 7, lane = (r >> 3) & 63, blk = r >> 9;
        int nt = blk % 16, ks = (blk / 16) % 8, d = blk / 128;
        int n = nt * 16 + (lane & 15);
        int k = ks * 32 + (lane >> 4) * 8 + j;
        WaF[r] = f2bf(atW[(size_t)d * FP * FP + (size_t)n * FP + k]);
    } else if (idx < N1 + N2 + N3) {
        int r = idx - N1 - N2;
        int j = r & 7, lane = (r >> 3) & 63, blk = r >> 9;
        int nt = blk % 48, ks = (blk / 48) % 8, mat = blk / 384;
        int n = nt * 16 + (lane & 15);
        int k = ks * 32 + (lane >> 4) * 8 + j;
        const float* W = mat ? mhh : mih;
        MolGW[r] = f2bf(W[(size_t)n * FP + k]);
    }
}

// ---------------- fused atom fc + neighbor-fc atom part ----------------
__global__ __launch_bounds__(256) void k_atom_pre(const float* __restrict__ atom_list,
                                                  const float* __restrict__ WafcT,
                                                  const float* __restrict__ afc_b,
                                                  const float* __restrict__ WnT,
                                                  const float* __restrict__ bn,
                                                  float* __restrict__ out_pre,
                                                  short* __restrict__ hb16,
                                                  short* __restrict__ ApreB) {
    int g0 = blockIdx.x * 8;
    int t = threadIdx.x;
    __shared__ float x[8][AA];
    for (int i = t; i < 8 * AA; i += 256) x[i / AA][i % AA] = atom_list[(size_t)g0 * AA + i];
    __syncthreads();
    float a1[8], a2[8];
    float b1 = afc_b[t], b2 = bn[t];
#pragma unroll
    for (int a = 0; a < 8; ++a) { a1[a] = b1; a2[a] = b2; }
    for (int i = 0; i < AA; ++i) {
        float w1 = WafcT[i * FP + t];
        float w2 = WnT[i * FP + t];
#pragma unroll
        for (int a = 0; a < 8; ++a) { a1[a] += x[a][i] * w1; a2[a] += x[a][i] * w2; }
    }
#pragma unroll
    for (int a = 0; a < 8; ++a) {
        size_t idx = (size_t)(g0 + a) * FP + t;
        out_pre[idx] = a1[a];
        hb16[idx] = f2bf(fmaxf(a1[a], 0.f));   // h0 = relu(pre)
        ApreB[idx] = f2bf(a2[a]);
    }
}

// ---------- fused d0 attention+ctx: 1 block/molecule, bond terms, 1-pass nf ----------
__global__ __launch_bounds__(512) void k_actx_d0(
        const short* __restrict__ ACTB,      // relu(h0) bf16 (self dots, global)
        const short* __restrict__ ApreB,     // neighbor-fc atom preact bf16
        const float* __restrict__ bond_list,
        const int* __restrict__ adeg, const int* __restrict__ bdeg,
        const float* __restrict__ WnT,       // bond rows AA..AA+BDD-1
        const float* __restrict__ alW, const float* __restrict__ alb,
        const short* __restrict__ WaF, const float* __restrict__ atb,
        short* __restrict__ ctx_out, float* __restrict__ awv_out) {
    __shared__ __align__(16) short aS[32768];     // 64 KB ApreB slab (swizzled)
    __shared__ __align__(16) short cS[32768];     // 64 KB wn slab (swizzled)
    __shared__ int jxS[LL * KK];
    __shared__ int bxS[LL * KK];
    __shared__ float swS[LL];

    const int b = blockIdx.x;
    const int t = threadIdx.x;
    const int wave = t >> 6, lane = t & 63;
    const int lr = lane & 15, lk = lane >> 4;

#define SLAB_OFF(r, cb) ((((r) * 512 + (cb))) ^ ((((r) & 7)) << 4))
#define A4R(r, c)  (*(const short4v*)((const char*)aS + SLAB_OFF(r, (c) * 2)))
#define C8R(r, c)  (*(const short8*)((const char*)cS + SLAB_OFF(r, (c) * 2)))
#define CW4(r, c, v) (*(short4v*)((char*)cS + SLAB_OFF(r, (c) * 2)) = (v))

    {
        const char* src = (const char*)(ApreB + (size_t)b * LL * FP);
#pragma unroll
        for (int it = 0; it < 8; ++it) {
            int off = it * 8192 + wave * 1024 + lane * 16;
            int so = off ^ (((off >> 9) & 7) << 4);
            GLL(src + so, (char*)aS + off);
        }
        for (int i = t; i < LL * KK; i += 512) {
            jxS[i] = adeg[b * LL * KK + i];
            bxS[i] = bdeg[b * LL * KK + i];
        }
    }

    f32x4 w0 = *(const f32x4*)(alW + lane * 4);
    f32x4 w1 = *(const f32x4*)(alW + FP + lane * 4);
    float bias = alb[0];

    float wnt[BDD][4];
#pragma unroll
    for (int i = 0; i < BDD; ++i) {
        f32x4 v = *(const f32x4*)(WnT + (AA + i) * FP + lane * 4);
#pragma unroll
        for (int q = 0; q < 4; ++q) wnt[i][q] = v[q];
    }
    __syncthreads();   // staging complete

    for (int ai = 0; ai < 16; ++ai) {
        const int a = wave * 16 + ai;
        const int ga = b * LL + a;

        short4v sv = *(const short4v*)(ACTB + (size_t)ga * FP + lane * 4);
        float ss = wred64(bf2f(sv[0]) * w0[0] + bf2f(sv[1]) * w0[1] +
                          bf2f(sv[2]) * w0[2] + bf2f(sv[3]) * w0[3]);

        int jx[KK];
#pragma unroll
        for (int k = 0; k < KK; ++k) jx[k] = jxS[a * KK + k];

        float nf[KK][4];
        float sc[KK];
#pragma unroll
        for (int k = 0; k < KK; ++k) {
            short4v nv = A4R(jx[k], lane * 4);
            float f0 = bf2f(nv[0]), f1 = bf2f(nv[1]), f2 = bf2f(nv[2]), f3 = bf2f(nv[3]);
            int bi = bxS[a * KK + k];
            const float* bp = bond_list + ((size_t)b * MM + bi) * BDD;
            float bb[BDD];
#pragma unroll
            for (int i = 0; i < 5; ++i) {
                f32x2 v2 = *(const f32x2*)(bp + 2 * i);
                bb[2 * i] = v2[0]; bb[2 * i + 1] = v2[1];
            }
            float b0 = 0.f, b1 = 0.f, b2 = 0.f, b3 = 0.f;
#pragma unroll
            for (int i = 0; i < BDD; ++i) {
                b0 += bb[i] * wnt[i][0]; b1 += bb[i] * wnt[i][1];
                b2 += bb[i] * wnt[i][2]; b3 += bb[i] * wnt[i][3];
            }
            f0 = fmaxf(f0 + b0, 0.f); f1 = fmaxf(f1 + b1, 0.f);
            f2 = fmaxf(f2 + b2, 0.f); f3 = fmaxf(f3 + b3, 0.f);
            nf[k][0] = f0; nf[k][1] = f1; nf[k][2] = f2; nf[k][3] = f3;
            float s2 = wred64(f0 * w1[0] + f1 * w1[1] + f2 * w1[2] + f3 * w1[3]);
            float s = fmaxf(ss + s2 + bias, 0.f);
            if (jx[k] == LL - 1) s -= 9.0f;
            sc[k] = s;
        }

        float m = sc[0];
#pragma unroll
        for (int k = 1; k < KK; ++k) m = fmaxf(m, sc[k]);
        float e[KK], den = 0.f;
#pragma unroll
        for (int k = 0; k < KK; ++k) { e[k] = expf(sc[k] - m); den += e[k]; }
        float aw[KK], sumaw = 0.f;
#pragma unroll
        for (int k = 0; k < KK; ++k) {
            aw[k] = (jx[k] == LL - 1) ? 0.f : e[k] / den;
            sumaw += aw[k];
        }
        if (lane < KK) {
            float av = aw[0];
#pragma unroll
            for (int k = 1; k < KK; ++k) if (lane == k) av = aw[k];
            awv_out[(size_t)ga * KK + lane] = av;
        }
        if (lane == 0) swS[a] = sumaw;

        short4v wo;
#pragma unroll
        for (int q = 0; q < 4; ++q) {
            float w = 0.f;
#pragma unroll
            for (int k = 0; k < KK; ++k) w += aw[k] * nf[k][q];
            wo[q] = f2bf(w);
        }
        CW4(a, lane * 4, wo);
    }
    __syncthreads();

    {
        const int rg = wave >> 1, csl = wave & 1;
        f32x4 acc[2][8] = {};
        const short8* wb = (const short8*)WaF;
        for (int ks = 0; ks < 8; ++ks) {
            short8 a0 = C8R(rg * 32 + lr, ks * 32 + lk * 8);
            short8 a1 = C8R(rg * 32 + 16 + lr, ks * 32 + lk * 8);
#pragma unroll
            for (int nt2 = 0; nt2 < 8; ++nt2) {
                short8 bf = wb[(size_t)(ks * 16 + csl * 8 + nt2) * 64 + lane];
                acc[0][nt2] = __builtin_amdgcn_mfma_f32_16x16x32_bf16(a0, bf, acc[0][nt2], 0, 0, 0);
                acc[1][nt2] = __builtin_amdgcn_mfma_f32_16x16x32_bf16(a1, bf, acc[1][nt2], 0, 0, 0);
            }
        }
#pragma unroll
        for (int rt = 0; rt < 2; ++rt)
#pragma unroll
        for (int nt2 = 0; nt2 < 8; ++nt2) {
            int col = csl * 128 + nt2 * 16 + lr;
            float abv = atb[col];
#pragma unroll
            for (int q = 0; q < 4; ++q) {
                int row = rg * 32 + rt * 16 + lk * 4 + q;
                float v = acc[rt][nt2][q] + swS[row] * abv;
                ctx_out[((size_t)b * LL + row) * FP + col] = f2bf(fmaxf(v, 0.f));
            }
        }
    }
#undef SLAB_OFF
#undef A4R
#undef C8R
#undef CW4
}

// ---------- fused attention+ctx for d>0: single-pass (nf in regs) ----------
__global__ __launch_bounds__(512) void k_actx(int d,
        const short* __restrict__ ACTB,
        const int* __restrict__ adeg,
        const float* __restrict__ alW, const float* __restrict__ alb,
        const short* __restrict__ WaF, const float* __restrict__ atb,
        short* __restrict__ ctx_out, float* __restrict__ awv_out) {
    __shared__ __align__(16) short aS[32768];     // 64 KB act slab (swizzled)
    __shared__ __align__(16) short cS[32768];     // 64 KB wn slab (swizzled)
    __shared__ int   jxS[LL * KK];
    __shared__ float swS[LL];

    const int b = blockIdx.x;
    const int t = threadIdx.x;
    const int wave = t >> 6, lane = t & 63;
    const int lr = lane & 15, lk = lane >> 4;

#define SLAB_OFF(r, cb) ((((r) * 512 + (cb))) ^ ((((r) & 7)) << 4))
#define A4R(r, c)  (*(const short4v*)((const char*)aS + SLAB_OFF(r, (c) * 2)))
#define C8R(r, c)  (*(const short8*)((const char*)cS + SLAB_OFF(r, (c) * 2)))
#define CW4(r, c, v) (*(short4v*)((char*)cS + SLAB_OFF(r, (c) * 2)) = (v))

    {
        const char* src = (const char*)(ACTB + (size_t)b * LL * FP);
#pragma unroll
        for (int it = 0; it < 8; ++it) {
            int off = it * 8192 + wave * 1024 + lane * 16;
            int so = off ^ (((off >> 9) & 7) << 4);
            GLL(src + so, (char*)aS + off);
        }
        for (int i = t; i < LL * KK; i += 512) jxS[i] = adeg[b * LL * KK + i];
    }

    f32x4 w0 = *(const f32x4*)(alW + (size_t)d * 2 * FP + lane * 4);
    f32x4 w1 = *(const f32x4*)(alW + (size_t)d * 2 * FP + FP + lane * 4);
    float bias = alb[d];
    __syncthreads();

    for (int ai = 0; ai < 16; ++ai) {
        const int a = wave * 16 + ai;
        const int ga = b * LL + a;

        short4v sv = A4R(a, lane * 4);
        float ss = wred64(bf2f(sv[0]) * w0[0] + bf2f(sv[1]) * w0[1] +
                          bf2f(sv[2]) * w0[2] + bf2f(sv[3]) * w0[3]);

        int jx[KK];
#pragma unroll
        for (int k = 0; k < KK; ++k) jx[k] = jxS[a * KK + k];

        float nf[KK][4];
        float sc[KK];
#pragma unroll
        for (int k = 0; k < KK; ++k) {
            short4v nv = A4R(jx[k], lane * 4);
            nf[k][0] = bf2f(nv[0]); nf[k][1] = bf2f(nv[1]);
            nf[k][2] = bf2f(nv[2]); nf[k][3] = bf2f(nv[3]);
            float s2 = wred64(nf[k][0] * w1[0] + nf[k][1] * w1[1] +
                              nf[k][2] * w1[2] + nf[k][3] * w1[3]);
            float s = fmaxf(ss + s2 + bias, 0.f);
            if (jx[k] == LL - 1) s -= 9.0f;
            sc[k] = s;
        }

        float m = sc[0];
#pragma unroll
        for (int k = 1; k < KK; ++k) m = fmaxf(m, sc[k]);
        float e[KK], den = 0.f;
#pragma unroll
        for (int k = 0; k < KK; ++k) { e[k] = expf(sc[k] - m); den += e[k]; }
        float aw[KK], sumaw = 0.f;
#pragma unroll
        for (int k = 0; k < KK; ++k) {
            aw[k] = (jx[k] == LL - 1) ? 0.f : e[k] / den;
            sumaw += aw[k];
        }
        if (lane < KK) {
            float av = aw[0];
#pragma unroll
            for (int k = 1; k < KK; ++k) if (lane == k) av = aw[k];
            awv_out[(size_t)ga * KK + lane] = av;
        }
        if (lane == 0) swS[a] = sumaw;

        short4v wo;
#pragma unroll
        for (int q = 0; q < 4; ++q) {
            float w = 0.f;
#pragma unroll
            for (int k = 0; k < KK; ++k) w += aw[k] * nf[k][q];
            wo[q] = f2bf(w);
        }
        CW4(a, lane * 4, wo);
    }
    __syncthreads();

    {
        const int rg = wave >> 1, csl = wave & 1;
        f32x4 acc[2][8] = {};
        const short8* wb = (const short8*)(WaF + (size_t)d * 8 * 16 * 512);
        for (int ks = 0; ks < 8; ++ks) {
            short8 a0 = C8R(rg * 32 + lr, ks * 32 + lk * 8);
            short8 a1 = C8R(rg * 32 + 16 + lr, ks * 32 + lk * 8);
#pragma unroll
            for (int nt2 = 0; nt2 < 8; ++nt2) {
                short8 bf = wb[(size_t)(ks * 16 + csl * 8 + nt2) * 64 + lane];
                acc[0][nt2] = __builtin_amdgcn_mfma_f32_16x16x32_bf16(a0, bf, acc[0][nt2], 0, 0, 0);
                acc[1][nt2] = __builtin_amdgcn_mfma_f32_16x16x32_bf16(a1, bf, acc[1][nt2], 0, 0, 0);
            }
        }
#pragma unroll
        for (int rt = 0; rt < 2; ++rt)
#pragma unroll
        for (int nt2 = 0; nt2 < 8; ++nt2) {
            int col = csl * 128 + nt2 * 16 + lr;
            float abv = atb[d * FP + col];
#pragma unroll
            for (int q = 0; q < 4; ++q) {
                int row = rg * 32 + rt * 16 + lk * 4 + q;
                float v = acc[rt][nt2][q] + swS[row] * abv;
                ctx_out[((size_t)b * LL + row) * FP + col] = f2bf(fmaxf(v, 0.f));
            }
        }
    }
#undef SLAB_OFF
#undef A4R
#undef C8R
#undef CW4
}

// ---------------- fused MFMA GRU v6: counted-vmcnt pipeline, lean I/O ----------
template<int LAST>
__global__ __launch_bounds__(512) void k_gru_mfma(
        const short* __restrict__ XB,     // ctx bf16
        const short* __restrict__ HBl,    // h bf16 (read)
        float* __restrict__ hbuf,         // h fp32 (written only when LAST)
        const short* __restrict__ Bih,    // frag-major (8,48,64,8)
        const short* __restrict__ Bhh,
        const float* __restrict__ bih, const float* __restrict__ bhh,
        float* __restrict__ act_out,
        short* __restrict__ HB_out,
        short* __restrict__ ACT_out) {
    __shared__ short ldsB[3][12288];      // 3 x 24 KB
    __shared__ short ldsA[2][16384];      // x,h slabs: 2 x 32 KB (swizzled)
    const int t = threadIdx.x;
    const int wave = t >> 6, lane = t & 63;
    const int rh = wave >> 2;
    const int wn = wave & 3;
    const int lr = lane & 15, lk = lane >> 4;
    const int bid = blockIdx.x;
    const int kofs = bid & 7;
    const int abase = bid * 64;

#define PKS(p)  ((((p) >> 2) + kofs) & 7)
#define STAGEP(p) do { \
        const short* base_ = ((((p) >> 1) & 1) ? Bhh : Bih) + (size_t)PKS(p) * 24576; \
        const int h_ = (p) & 1; \
        _Pragma("unroll") \
        for (int e = 0; e < 3; ++e) { \
            int j = wave * 3 + e; \
            int nt = 4 * (j >> 1) + 2 * h_ + (j & 1); \
            GLL(base_ + nt * 512 + lane * 8, &ldsB[(p) % 3][j * 512]); \
        } } while (0)
#define LDA_READ(s, r, c) (*(const short8*)((const char*)ldsA[s] + \
        ((((r) * 512 + (c) * 2)) ^ ((((r) & 7)) << 4))))
#define LDA_READ1(s, r, c) (*(const short*)((const char*)ldsA[s] + \
        ((((r) * 512 + (c) * 2)) ^ ((((r) & 7)) << 4))))

    {
        const char* xsrc = (const char*)(XB + (size_t)abase * FP);
        const char* hsrc = (const char*)(HBl + (size_t)abase * FP);
#pragma unroll
        for (int it = 0; it < 4; ++it) {
            int off = it * 8192 + wave * 1024 + lane * 16;
            int src = off ^ (((off >> 9) & 7) << 4);
            GLL(xsrc + src, (char*)ldsA[0] + off);
            GLL(hsrc + src, (char*)ldsA[1] + off);
        }
    }
    STAGEP(0);
    STAGEP(1);

    f32x4 acc_rz[2][8] = {};
    f32x4 acc_in[2][4] = {};
    f32x4 acc_hn[2][4] = {};

    short8 ax0{}, ah0{}, ax1{}, ah1{};
#pragma unroll
    for (int p = 0; p < 32; ++p) {
        if (p < 31) { asm volatile("s_waitcnt vmcnt(3)" ::: "memory"); }
        else        { asm volatile("s_waitcnt vmcnt(0)" ::: "memory"); }
        __builtin_amdgcn_s_barrier();
        __builtin_amdgcn_sched_barrier(0);
        if (p < 30) STAGEP(p + 2);
        const int h_ = p & 1;
        const int mat = (p >> 1) & 1;
        if ((p & 3) == 0) {
            int ks = PKS(p);
            int c = ks * 32 + lk * 8;
            ax0 = LDA_READ(0, rh * 32 + lr, c);
            ah0 = LDA_READ(1, rh * 32 + lr, c);
            ax1 = LDA_READ(0, rh * 32 + 16 + lr, c);
            ah1 = LDA_READ(1, rh * 32 + 16 + lr, c);
        }
#pragma unroll
        for (int rg = 0; rg < 2; ++rg) {
            const short8 a8 = mat ? (rg ? ah1 : ah0) : (rg ? ax1 : ax0);
#pragma unroll
            for (int g = 0; g < 3; ++g) {
#pragma unroll
                for (int s2 = 0; s2 < 2; ++s2) {
                    const int sub = 2 * h_ + s2;
                    const int j = ((4 * g + wn) << 1) | s2;
                    short8 bf = *(const short8*)(&ldsB[p % 3][j * 512 + lane * 8]);
                    if (g < 2)
                        acc_rz[rg][g * 4 + sub] = __builtin_amdgcn_mfma_f32_16x16x32_bf16(a8, bf, acc_rz[rg][g * 4 + sub], 0, 0, 0);
                    else if (mat)
                        acc_hn[rg][sub] = __builtin_amdgcn_mfma_f32_16x16x32_bf16(a8, bf, acc_hn[rg][sub], 0, 0, 0);
                    else
                        acc_in[rg][sub] = __builtin_amdgcn_mfma_f32_16x16x32_bf16(a8, bf, acc_in[rg][sub], 0, 0, 0);
                }
            }
        }
    }
#undef STAGEP
#undef PKS

#pragma unroll
    for (int sub = 0; sub < 4; ++sub) {
        int c = wn * 64 + sub * 16 + lr;
        float brz_r = bih[c] + bhh[c];
        float brz_z = bih[FP + c] + bhh[FP + c];
        float bin_ = bih[2 * FP + c];
        float bhn = bhh[2 * FP + c];
#pragma unroll
        for (int rg = 0; rg < 2; ++rg) {
#pragma unroll
            for (int q = 0; q < 4; ++q) {
                int row = rh * 32 + rg * 16 + lk * 4 + q;
                int atom = abase + row;
                size_t idx = (size_t)atom * FP + c;
                float hold = bf2f(LDA_READ1(1, row, c));
                float r = 1.f / (1.f + expf(-(acc_rz[rg][0 * 4 + sub][q] + brz_r)));
                float z = 1.f / (1.f + expf(-(acc_rz[rg][1 * 4 + sub][q] + brz_z)));
                float n = tanhf(acc_in[rg][sub][q] + bin_ + r * (acc_hn[rg][sub][q] + bhn));
                float hn = (1.f - z) * n + z * hold;
                float rl = fmaxf(hn, 0.f);
                act_out[idx] = rl;
                if constexpr (LAST) {
                    hbuf[idx] = hn;
                } else {
                    HB_out[idx] = f2bf(hn);
                    ACT_out[idx] = f2bf(rl);
                }
            }
        }
    }
#undef LDA_READ
#undef LDA_READ1
}

// ---------------- fused mol reduce + step-0 mstep ----------------
__global__ __launch_bounds__(256) void k_mol_head(
        const float* __restrict__ hbuf, const float* __restrict__ act,
        const float* __restrict__ mask,
        const float* __restrict__ malW, const float* __restrict__ malb,
        const float* __restrict__ MWaT, const float* __restrict__ matb,
        float* __restrict__ o_unb0, float* __restrict__ o_mfv0,
        float* __restrict__ molF, short* __restrict__ MOLFb,
        float* __restrict__ S2g,
        short* __restrict__ MCTXb, float* __restrict__ o_mawv) {
    int b = blockIdx.x, t = threadIdx.x;
    int wave = t >> 6, lane = t & 63;
    __shared__ float sS2[LL], sS[LL], mwS[LL], waS[FP];
    __shared__ float red[4];

    float s1 = 0.f, s2 = 0.f;
    for (int l = 0; l < LL; ++l) {
        float mk = mask[b * LL + l];
        s1 += hbuf[((size_t)b * LL + l) * FP + t] * mk;
        s2 += act[((size_t)b * LL + l) * FP + t] * mk;
    }
    o_unb0[b * FP + t] = s1;
    o_mfv0[b * FP + t] = s2;
    molF[b * FP + t] = s2;
    MOLFb[b * FP + t] = f2bf(s2);

    for (int l = wave; l < LL; l += 4) {
        float v2 = 0.f;
#pragma unroll
        for (int q = 0; q < 4; ++q) {
            int i = lane + 64 * q;
            v2 += act[((size_t)b * LL + l) * FP + i] * malW[FP + i];
        }
        v2 = wred64(v2);
        if (lane == 0) { sS2[l] = v2; S2g[b * LL + l] = v2; }
    }

    // step-0 mstep body (hprev = s2, in register)
    float am = fmaxf(s2, 0.f);
    float v = am * malW[t];
    v = wred64(v);
    if (lane == 0) red[wave] = v;
    __syncthreads();
    float s_self = red[0] + red[1] + red[2] + red[3];

    if (t < LL) {
        float s = fmaxf(s_self + sS2[t] + malb[0], 0.f);
        if (mask[b * LL + t] == 0.f) s += -9e8f;
        sS[t] = s;
    }
    __syncthreads();

    float m = -1e30f;
    for (int l = 0; l < LL; ++l) m = fmaxf(m, sS[l]);
    float den = 0.f;
    for (int l = 0; l < LL; ++l) den += expf(sS[l] - m);
    if (t < LL) {
        float w = expf(sS[t] - m) / den * mask[b * LL + t];
        mwS[t] = w;
        o_mawv[b * LL + t] = w;   // step 0
    }
    __syncthreads();

    float sumaw = 0.f;
    for (int l = 0; l < LL; ++l) sumaw += mwS[l];

    float wa = 0.f;
    for (int l = 0; l < LL; ++l) wa += mwS[l] * act[((size_t)b * LL + l) * FP + t];
    waS[t] = wa;
    __syncthreads();

    float acc = sumaw * matb[t];
    for (int i = 0; i < FP; ++i) acc += waS[i] * MWaT[i * FP + t];
    MCTXb[b * FP + t] = f2bf(fmaxf(acc, 0.f));
}

// ---------------- mol step (step>=1): scores + softmax + rank-1 attend ------
__global__ __launch_bounds__(256) void k_mstep(int step,
        const float* __restrict__ act,
        const float* __restrict__ molF,
        const float* __restrict__ mask,
        const float* __restrict__ S2g,
        const float* __restrict__ malW, const float* __restrict__ malb,
        const float* __restrict__ MWaT, const float* __restrict__ matb,
        short* __restrict__ MCTXb,
        float* __restrict__ o_mawv) {
    int b = blockIdx.x, t = threadIdx.x;
    int wave = t >> 6, lane = t & 63;
    __shared__ float sS[LL], mwS[LL], waS[FP];
    __shared__ float red[4];

    float hprev = molF[b * FP + t];
    float am = fmaxf(hprev, 0.f);

    float v = am * malW[t];
    v = wred64(v);
    if (lane == 0) red[wave] = v;
    __syncthreads();
    float s_self = red[0] + red[1] + red[2] + red[3];

    if (t < LL) {
        float s = fmaxf(s_self + S2g[b * LL + t] + malb[0], 0.f);
        if (mask[b * LL + t] == 0.f) s += -9e8f;
        sS[t] = s;
    }
    __syncthreads();

    float m = -1e30f;
    for (int l = 0; l < LL; ++l) m = fmaxf(m, sS[l]);
    float den = 0.f;
    for (int l = 0; l < LL; ++l) den += expf(sS[l] - m);
    if (t < LL) {
        float w = expf(sS[t] - m) / den * mask[b * LL + t];
        mwS[t] = w;
        o_mawv[(size_t)step * (BB * LL) + b * LL + t] = w;
    }
    __syncthreads();

    float sumaw = 0.f;
    for (int l = 0; l < LL; ++l) sumaw += mwS[l];

    float wa = 0.f;
    for (int l = 0; l < LL; ++l) wa += mwS[l] * act[((size_t)b * LL + l) * FP + t];
    waS[t] = wa;
    __syncthreads();

    float acc = sumaw * matb[t];
    for (int i = 0; i < FP; ++i) acc += waS[i] * MWaT[i * FP + t];
    MCTXb[b * FP + t] = f2bf(fmaxf(acc, 0.f));
}

// ---------------- mol GRU as 256-row MFMA GEMM (4 blocks x 64 rows) ----------
__global__ __launch_bounds__(512) void k_mol_gru(int step,
        const short* __restrict__ XB,     // mctx bf16 (256,FP)
        const short* __restrict__ HBl,    // molF bf16
        const short* __restrict__ Bih,    // frag-major (8,48,64,8)
        const short* __restrict__ Bhh,
        const float* __restrict__ bih, const float* __restrict__ bhh,
        float* __restrict__ o_unb, float* __restrict__ o_mfv,
        float* __restrict__ molF, short* __restrict__ MOLFb,
        float* __restrict__ o_molfeat) {
    __shared__ short ldsB[3][12288];
    __shared__ short ldsA[2][16384];
    const int t = threadIdx.x;
    const int wave = t >> 6, lane = t & 63;
    const int rh = wave >> 2;
    const int wn = wave & 3;
    const int lr = lane & 15, lk = lane >> 4;
    const int bid = blockIdx.x;
    const int kofs = bid & 7;
    const int abase = bid * 64;

#define PKS(p)  ((((p) >> 2) + kofs) & 7)
#define STAGEP(p) do { \
        const short* base_ = ((((p) >> 1) & 1) ? Bhh : Bih) + (size_t)PKS(p) * 24576; \
        const int h_ = (p) & 1; \
        _Pragma("unroll") \
        for (int e = 0; e < 3; ++e) { \
            int j = wave * 3 + e; \
            int nt = 4 * (j >> 1) + 2 * h_ + (j & 1); \
            GLL(base_ + nt * 512 + lane * 8, &ldsB[(p) % 3][j * 512]); \
        } } while (0)
#define LDA_READ(s, r, c) (*(const short8*)((const char*)ldsA[s] + \
        ((((r) * 512 + (c) * 2)) ^ ((((r) & 7)) << 4))))
#define LDA_READ1(s, r, c) (*(const short*)((const char*)ldsA[s] + \
        ((((r) * 512 + (c) * 2)) ^ ((((r) & 7)) << 4))))

    {
        const char* xsrc = (const char*)(XB + (size_t)abase * FP);
        const char* hsrc = (const char*)(HBl + (size_t)abase * FP);
#pragma unroll
        for (int it = 0; it < 4; ++it) {
            int off = it * 8192 + wave * 1024 + lane * 16;
            int src = off ^ (((off >> 9) & 7) << 4);
            GLL(xsrc + src, (char*)ldsA[0] + off);
            GLL(hsrc + src, (char*)ldsA[1] + off);
        }
    }
    STAGEP(0);
    STAGEP(1);

    f32x4 acc_rz[2][8] = {};
    f32x4 acc_in[2][4] = {};
    f32x4 acc_hn[2][4] = {};

    short8 ax0{}, ah0{}, ax1{}, ah1{};
#pragma unroll
    for (int p = 0; p < 32; ++p) {
        if (p < 31) { asm volatile("s_waitcnt vmcnt(3)" ::: "memory"); }
        else        { asm volatile("s_waitcnt vmcnt(0)" ::: "memory"); }
        __builtin_amdgcn_s_barrier();
        __builtin_amdgcn_sched_barrier(0);
        if (p < 30) STAGEP(p + 2);
        const int h_ = p & 1;
        const int mat = (p >> 1) & 1;
        if ((p & 3) == 0) {
            int ks = PKS(p);
            int c = ks * 32 + lk * 8;
            ax0 = LDA_READ(0, rh * 32 + lr, c);
            ah0 = LDA_READ(1, rh * 32 + lr, c);
            ax1 = LDA_READ(0, rh * 32 + 16 + lr, c);
            ah1 = LDA_READ(1, rh * 32 + 16 + lr, c);
        }
#pragma unroll
        for (int rg = 0; rg < 2; ++rg) {
            const short8 a8 = mat ? (rg ? ah1 : ah0) : (rg ? ax1 : ax0);
#pragma unroll
            for (int g = 0; g < 3; ++g) {
#pragma unroll
                for (int s2 = 0; s2 < 2; ++s2) {
                    const int sub = 2 * h_ + s2;
                    const int j = ((4 * g + wn) << 1) | s2;
                    short8 bf = *(const short8*)(&ldsB[p % 3][j * 512 + lane * 8]);
                    if (g < 2)
                        acc_rz[rg][g * 4 + sub] = __builtin_amdgcn_mfma_f32_16x16x32_bf16(a8, bf, acc_rz[rg][g * 4 + sub], 0, 0, 0);
                    else if (mat)
                        acc_hn[rg][sub] = __builtin_amdgcn_mfma_f32_16x16x32_bf16(a8, bf, acc_hn[rg][sub], 0, 0, 0);
                    else
                        acc_in[rg][sub] = __builtin_amdgcn_mfma_f32_16x16x32_bf16(a8, bf, acc_in[rg][sub], 0, 0, 0);
                }
            }
        }
    }
#undef STAGEP
#undef PKS

#pragma unroll
    for (int sub = 0; sub < 4; ++sub) {
        int c = wn * 64 + sub * 16 + lr;
        float brz_r = bih[c] + bhh[c];
        float brz_z = bih[FP + c] + bhh[FP + c];
        float bin_ = bih[2 * FP + c];
        float bhn = bhh[2 * FP + c];
#pragma unroll
        for (int rg = 0; rg < 2; ++rg) {
#pragma unroll
            for (int q = 0; q < 4; ++q) {
                int row = rh * 32 + rg * 16 + lk * 4 + q;
                int m = abase + row;                     // molecule index
                size_t idx = (size_t)m * FP + c;
                float hold = bf2f(LDA_READ1(1, row, c));
                float r = 1.f / (1.f + expf(-(acc_rz[rg][0 * 4 + sub][q] + brz_r)));
                float z = 1.f / (1.f + expf(-(acc_rz[rg][1 * 4 + sub][q] + brz_z)));
                float n = tanhf(acc_in[rg][sub][q] + bin_ + r * (acc_hn[rg][sub][q] + bhn));
                float hn = (1.f - z) * n + z * hold;
                o_unb[(size_t)(step + 1) * (BB * FP) + idx] = hn;
                o_mfv[(size_t)(step + 1) * (BB * FP) + idx] = fmaxf(hn, 0.f);
                molF[idx] = hn;
                MOLFb[idx] = f2bf(hn);
                if (step == TT - 1) o_molfeat[idx] = hn;
            }
        }
    }
#undef LDA_READ
#undef LDA_READ1
}

extern "C" void kernel_launch(void* const* d_in, const int* in_sizes, int n_in,
                              void* d_out, int out_size, void* d_ws, size_t ws_size,
                              hipStream_t stream) {
    const float* atom_list = (const float*)d_in[0];
    const float* bond_list = (const float*)d_in[1];
    const int*   adeg      = (const int*)d_in[2];
    const int*   bdeg      = (const int*)d_in[3];
    const float* amask     = (const float*)d_in[4];
    const float* atom_fc_W = (const float*)d_in[5];
    const float* atom_fc_b = (const float*)d_in[6];
    const float* nfc_W     = (const float*)d_in[7];
    const float* nfc_b     = (const float*)d_in[8];
    const float* gwih      = (const float*)d_in[9];
    const float* gwhh      = (const float*)d_in[10];
    const float* gbih      = (const float*)d_in[11];
    const float* gbhh      = (const float*)d_in[12];
    const float* alW       = (const float*)d_in[13];
    const float* alb       = (const float*)d_in[14];
    const float* atW       = (const float*)d_in[15];
    const float* atb       = (const float*)d_in[16];
    const float* mgwih     = (const float*)d_in[17];
    const float* mgwhh     = (const float*)d_in[18];
    const float* mgbih     = (const float*)d_in[19];
    const float* mgbhh     = (const float*)d_in[20];
    const float* malW      = (const float*)d_in[21];
    const float* malb      = (const float*)d_in[22];
    const float* matW      = (const float*)d_in[23];
    const float* matb      = (const float*)d_in[24];

    const size_t BLF = (size_t)BB * LL * FP;
    float* out = (float*)d_out;
    float* O0 = out;                                 // atom_feature / h (fp32)
    float* O1 = out + BLF;                           // afv (4,B,L,FP)
    float* O2 = O1 + 4 * BLF;                        // awv (3,B,L,K)
    float* O3 = O2 + (size_t)RR * BB * LL * KK;      // mfv
    float* O4 = O3 + (size_t)(TT + 1) * BB * FP;     // mol_unb
    float* O5 = O4 + (size_t)(TT + 1) * BB * FP;     // mawv
    float* O6 = O5 + (size_t)TT * BB * LL;           // mol_feature

    // ws layout
    float* ws = (float*)d_ws;
    short* XB   = (short*)ws;                        // (spare)
    short* XB2  = XB + BLF;                          // BLF shorts: ctx bf16
    short* HBb  = XB + 2 * BLF;                      // BLF shorts: h bf16
    short* ACTB = XB + 3 * BLF;                      // BLF shorts: relu(h) bf16
    float* rest = ws + 2 * BLF;
    short* ApreB = (short*)rest;                     // BLF shorts
    float* SW    = rest + BLF / 2;                   // (unused, kept for layout)
    float* MOLF  = SW + (size_t)BB * LL;
    float* WafcT = MOLF + (size_t)BB * FP;
    float* WnT   = WafcT + AA * FP;
    float* MWaT  = WnT + (AA + BDD) * FP;
    short* MolGW = (short*)(MWaT + (size_t)FP * FP);    // 2*(8*48*512) shorts
    short* GW    = MolGW + (size_t)2 * 8 * 48 * 512;    // RR*2*(8*48*512) shorts
    short* WaF   = GW + (size_t)RR * 2 * 8 * 48 * 512;  // RR*(8*16*512) shorts
    short* MCTXb = WaF + (size_t)RR * 8 * 16 * 512;     // BB*FP shorts
    short* MOLFb = MCTXb + (size_t)BB * FP;             // BB*FP shorts
    float* S2g   = (float*)(MOLFb + (size_t)BB * FP);   // BB*LL floats
    (void)ws_size; (void)in_sizes; (void)n_in; (void)out_size;

    {
        int nT = FP * AA + FP * (AA + BDD) + FP * FP;
        k_prep_trans<<<(nT + 255) / 256, 256, 0, stream>>>(atom_fc_W, nfc_W, matW,
                                                           WafcT, WnT, MWaT);
        int nP = RR * 2 * 8 * 48 * 512 + RR * 8 * 16 * 512 + 2 * 8 * 48 * 512;
        k_prep_pack<<<(nP + 255) / 256, 256, 0, stream>>>(gwih, gwhh, atW,
                                                          mgwih, mgwhh, GW, WaF, MolGW);
    }

    k_atom_pre<<<BB * LL / 8, 256, 0, stream>>>(atom_list, WafcT, atom_fc_b,
                                                WnT, nfc_b, O1, HBb, ApreB);

    const size_t wblk = (size_t)8 * 48 * 512;
    for (int d = 0; d < RR; ++d) {
        if (d == 0) {
            k_actx_d0<<<BB, 512, 0, stream>>>(HBb, ApreB, bond_list, adeg, bdeg,
                    WnT, alW, alb, WaF, atb, XB2, O2);
        } else {
            k_actx<<<BB, 512, 0, stream>>>(d, ACTB, adeg,
                    alW, alb, WaF, atb,
                    XB2, O2 + (size_t)d * BB * LL * KK);
        }
        if (d == RR - 1) {
            k_gru_mfma<1><<<BB * LL / 64, 512, 0, stream>>>(XB2, HBb, O0,
                    GW + (size_t)(d * 2 + 0) * wblk, GW + (size_t)(d * 2 + 1) * wblk,
                    gbih + (size_t)d * 768, gbhh + (size_t)d * 768,
                    O1 + (size_t)(d + 1) * BLF, HBb, ACTB);
        } else {
            k_gru_mfma<0><<<BB * LL / 64, 512, 0, stream>>>(XB2, HBb, O0,
                    GW + (size_t)(d * 2 + 0) * wblk, GW + (size_t)(d * 2 + 1) * wblk,
                    gbih + (size_t)d * 768, gbhh + (size_t)d * 768,
                    O1 + (size_t)(d + 1) * BLF, HBb, ACTB);
        }
    }

    const float* actFin = O1 + (size_t)RR * BLF;
    k_mol_head<<<BB, 256, 0, stream>>>(O0, actFin, amask, malW, malb, MWaT, matb,
                                       O4, O3, MOLF, MOLFb, S2g, MCTXb, O5);
    k_mol_gru<<<4, 512, 0, stream>>>(0, MCTXb, MOLFb,
            MolGW, MolGW + wblk, mgbih, mgbhh,
            O4, O3, MOLF, MOLFb, O6);
    k_mstep<<<BB, 256, 0, stream>>>(1, actFin, MOLF, amask, S2g,
            malW, malb, MWaT, matb, MCTXb, O5);
    k_mol_gru<<<4, 512, 0, stream>>>(1, MCTXb, MOLFb,
            MolGW, MolGW + wblk, mgbih, mgbhh,
            O4, O3, MOLF, MOLFb, O6);
}

// Round 17
// 502.940 us; speedup vs baseline: 1.9634x; 1.0706x over previous
//
#include <hip/hip_runtime.h>
#include <hip/hip_bf16.h>

// Dims
#define BB 256
#define LL 128
#define AA 39
#define BDD 10
#define KK 6
#define MM 256
#define FP 256
#define RR 3
#define TT 2

using short8  = __attribute__((ext_vector_type(8))) short;
using short4v = __attribute__((ext_vector_type(4))) short;
using f32x4   = __attribute__((ext_vector_type(4))) float;
using f32x2   = __attribute__((ext_vector_type(2))) float;

__device__ __forceinline__ short f2bf(float f) {
    union { float f; unsigned u; } v; v.f = f;
    unsigned u = v.u;
    u += 0x7fffu + ((u >> 16) & 1u);   // round-to-nearest-even
    return (short)(u >> 16);
}
__device__ __forceinline__ float bf2f(short s) {
    union { unsigned u; float f; } v; v.u = ((unsigned)(unsigned short)s) << 16;
    return v.f;
}
__device__ __forceinline__ float wred64(float v) {
#pragma unroll
    for (int off = 32; off >= 1; off >>= 1) v += __shfl_xor(v, off);
    return v;
}

#define GLL(gp, lp) __builtin_amdgcn_global_load_lds( \
    (const __attribute__((address_space(1))) void*)(gp), \
    (__attribute__((address_space(3))) void*)(lp), 16, 0, 0)

// ---------------- merged transposes: WafcT, WnT, MWaT ----------------
__global__ __launch_bounds__(256) void k_prep_trans(
        const float* __restrict__ atom_fc_W, const float* __restrict__ nfc_W,
        const float* __restrict__ matW,
        float* __restrict__ WafcT, float* __restrict__ WnT, float* __restrict__ MWaT) {
    const int N1 = FP * AA, N2 = FP * (AA + BDD), N3 = FP * FP;
    int idx = blockIdx.x * 256 + threadIdx.x;
    if (idx < N1) {
        int o = idx / AA, i = idx - o * AA;
        WafcT[i * FP + o] = atom_fc_W[idx];
    } else if (idx < N1 + N2) {
        int r = idx - N1;
        int o = r / (AA + BDD), i = r - o * (AA + BDD);
        WnT[i * FP + o] = nfc_W[r];
    } else if (idx < N1 + N2 + N3) {
        int r = idx - N1 - N2;
        int o = r >> 8, i = r & 255;
        MWaT[i * FP + o] = matW[r];
    }
}

// ---------------- merged packs: GRU frag, attend frag, mol-GRU frag ----------------
__global__ __launch_bounds__(256) void k_prep_pack(
        const float* __restrict__ gwih, const float* __restrict__ gwhh,
        const float* __restrict__ atW,
        const float* __restrict__ mih, const float* __restrict__ mhh,
        short* __restrict__ GW, short* __restrict__ WaF, short* __restrict__ MolGW) {
    const int N1 = RR * 2 * 8 * 48 * 512;   // gru
    const int N2 = RR * 8 * 16 * 512;       // attend
    const int N3 = 2 * 8 * 48 * 512;        // mol gru
    int idx = blockIdx.x * 256 + threadIdx.x;
    if (idx < N1) {
        int j = idx & 7, lane = (idx >> 3) & 63, blk = idx >> 9;
        int nt = blk % 48, ks = (blk / 48) % 8, mat = (blk / 384) % 2, d = blk / 768;
        int n = nt * 16 + (lane & 15);
        int k = ks * 32 + (lane >> 4) * 8 + j;
        const float* W = mat ? gwhh : gwih;
        GW[idx] = f2bf(W[((size_t)d * 768 + n) * FP + k]);
    } else if (idx < N1 + N2) {
        int r = idx - N1;
        int j = r & 7, lane = (r >> 3) & 63, blk = r >> 9;
        int nt = blk % 16, ks = (blk / 16) % 8, d = blk / 128;
        int n = nt * 16 + (lane & 15);
        int k = ks * 32 + (lane >> 4) * 8 + j;
        WaF[r] = f2bf(atW[(size_t)d * FP * FP + (size_t)n * FP + k]);
    } else if (idx < N1 + N2 + N3) {
        int r = idx - N1 - N2;
        int j = r & 7, lane = (r >> 3) & 63, blk = r >> 9;
        int nt = blk % 48, ks = (blk / 48) % 8, mat = blk / 384;
        int n = nt * 16 + (lane & 15);
        int k = ks * 32 + (lane >> 4) * 8 + j;
        const float* W = mat ? mhh : mih;
        MolGW[r] = f2bf(W[(size_t)n * FP + k]);
    }
}

// ---------------- fused atom fc + neighbor-fc atom part ----------------
__global__ __launch_bounds__(256) void k_atom_pre(const float* __restrict__ atom_list,
                                                  const float* __restrict__ WafcT,
                                                  const float* __restrict__ afc_b,
                                                  const float* __restrict__ WnT,
                                                  const float* __restrict__ bn,
                                                  float* __restrict__ out_pre,
                                                  short* __restrict__ hb16,
                                                  short* __restrict__ ApreB) {
    int g0 = blockIdx.x * 8;
    int t = threadIdx.x;
    __shared__ float x[8][AA];
    for (int i = t; i < 8 * AA; i += 256) x[i / AA][i % AA] = atom_list[(size_t)g0 * AA + i];
    __syncthreads();
    float a1[8], a2[8];
    float b1 = afc_b[t], b2 = bn[t];
#pragma unroll
    for (int a = 0; a < 8; ++a) { a1[a] = b1; a2[a] = b2; }
    for (int i = 0; i < AA; ++i) {
        float w1 = WafcT[i * FP + t];
        float w2 = WnT[i * FP + t];
#pragma unroll
        for (int a = 0; a < 8; ++a) { a1[a] += x[a][i] * w1; a2[a] += x[a][i] * w2; }
    }
#pragma unroll
    for (int a = 0; a < 8; ++a) {
        size_t idx = (size_t)(g0 + a) * FP + t;
        out_pre[idx] = a1[a];
        hb16[idx] = f2bf(fmaxf(a1[a], 0.f));   // h0 = relu(pre)
        ApreB[idx] = f2bf(a2[a]);
    }
}

// ---------- fused d0 attention+ctx: 1 block/molecule, bond terms, 1-pass nf ----------
__global__ __launch_bounds__(512) void k_actx_d0(
        const short* __restrict__ ACTB,      // relu(h0) bf16 (self dots, global)
        const short* __restrict__ ApreB,     // neighbor-fc atom preact bf16
        const float* __restrict__ bond_list,
        const int* __restrict__ adeg, const int* __restrict__ bdeg,
        const float* __restrict__ WnT,       // bond rows AA..AA+BDD-1
        const float* __restrict__ alW, const float* __restrict__ alb,
        const short* __restrict__ WaF, const float* __restrict__ atb,
        short* __restrict__ ctx_out, float* __restrict__ awv_out) {
    __shared__ __align__(16) short aS[32768];     // 64 KB ApreB slab (swizzled)
    __shared__ __align__(16) short cS[32768];     // 64 KB wn slab (swizzled)
    __shared__ int jxS[LL * KK];
    __shared__ int bxS[LL * KK];
    __shared__ float swS[LL];

    const int b = blockIdx.x;
    const int t = threadIdx.x;
    const int wave = t >> 6, lane = t & 63;
    const int lr = lane & 15, lk = lane >> 4;

#define SLAB_OFF(r, cb) ((((r) * 512 + (cb))) ^ ((((r) & 7)) << 4))
#define A4R(r, c)  (*(const short4v*)((const char*)aS + SLAB_OFF(r, (c) * 2)))
#define C8R(r, c)  (*(const short8*)((const char*)cS + SLAB_OFF(r, (c) * 2)))
#define CW4(r, c, v) (*(short4v*)((char*)cS + SLAB_OFF(r, (c) * 2)) = (v))

    {
        const char* src = (const char*)(ApreB + (size_t)b * LL * FP);
#pragma unroll
        for (int it = 0; it < 8; ++it) {
            int off = it * 8192 + wave * 1024 + lane * 16;
            int so = off ^ (((off >> 9) & 7) << 4);
            GLL(src + so, (char*)aS + off);
        }
        for (int i = t; i < LL * KK; i += 512) {
            jxS[i] = adeg[b * LL * KK + i];
            bxS[i] = bdeg[b * LL * KK + i];
        }
    }

    f32x4 w0 = *(const f32x4*)(alW + lane * 4);
    f32x4 w1 = *(const f32x4*)(alW + FP + lane * 4);
    float bias = alb[0];

    float wnt[BDD][4];
#pragma unroll
    for (int i = 0; i < BDD; ++i) {
        f32x4 v = *(const f32x4*)(WnT + (AA + i) * FP + lane * 4);
#pragma unroll
        for (int q = 0; q < 4; ++q) wnt[i][q] = v[q];
    }
    __syncthreads();   // staging complete

    for (int ai = 0; ai < 16; ++ai) {
        const int a = wave * 16 + ai;
        const int ga = b * LL + a;

        short4v sv = *(const short4v*)(ACTB + (size_t)ga * FP + lane * 4);
        float ss = wred64(bf2f(sv[0]) * w0[0] + bf2f(sv[1]) * w0[1] +
                          bf2f(sv[2]) * w0[2] + bf2f(sv[3]) * w0[3]);

        int jx[KK];
#pragma unroll
        for (int k = 0; k < KK; ++k) jx[k] = jxS[a * KK + k];

        float nf[KK][4];
        float sc[KK];
#pragma unroll
        for (int k = 0; k < KK; ++k) {
            short4v nv = A4R(jx[k], lane * 4);
            float f0 = bf2f(nv[0]), f1 = bf2f(nv[1]), f2 = bf2f(nv[2]), f3 = bf2f(nv[3]);
            int bi = bxS[a * KK + k];
            const float* bp = bond_list + ((size_t)b * MM + bi) * BDD;
            float bb[BDD];
#pragma unroll
            for (int i = 0; i < 5; ++i) {
                f32x2 v2 = *(const f32x2*)(bp + 2 * i);
                bb[2 * i] = v2[0]; bb[2 * i + 1] = v2[1];
            }
            float b0 = 0.f, b1 = 0.f, b2 = 0.f, b3 = 0.f;
#pragma unroll
            for (int i = 0; i < BDD; ++i) {
                b0 += bb[i] * wnt[i][0]; b1 += bb[i] * wnt[i][1];
                b2 += bb[i] * wnt[i][2]; b3 += bb[i] * wnt[i][3];
            }
            f0 = fmaxf(f0 + b0, 0.f); f1 = fmaxf(f1 + b1, 0.f);
            f2 = fmaxf(f2 + b2, 0.f); f3 = fmaxf(f3 + b3, 0.f);
            nf[k][0] = f0; nf[k][1] = f1; nf[k][2] = f2; nf[k][3] = f3;
            float s2 = wred64(f0 * w1[0] + f1 * w1[1] + f2 * w1[2] + f3 * w1[3]);
            float s = fmaxf(ss + s2 + bias, 0.f);
            if (jx[k] == LL - 1) s -= 9.0f;
            sc[k] = s;
        }

        float m = sc[0];
#pragma unroll
        for (int k = 1; k < KK; ++k) m = fmaxf(m, sc[k]);
        float e[KK], den = 0.f;
#pragma unroll
        for (int k = 0; k < KK; ++k) { e[k] = expf(sc[k] - m); den += e[k]; }
        float aw[KK], sumaw = 0.f;
#pragma unroll
        for (int k = 0; k < KK; ++k) {
            aw[k] = (jx[k] == LL - 1) ? 0.f : e[k] / den;
            sumaw += aw[k];
        }
        if (lane < KK) {
            float av = aw[0];
#pragma unroll
            for (int k = 1; k < KK; ++k) if (lane == k) av = aw[k];
            awv_out[(size_t)ga * KK + lane] = av;
        }
        if (lane == 0) swS[a] = sumaw;

        short4v wo;
#pragma unroll
        for (int q = 0; q < 4; ++q) {
            float w = 0.f;
#pragma unroll
            for (int k = 0; k < KK; ++k) w += aw[k] * nf[k][q];
            wo[q] = f2bf(w);
        }
        CW4(a, lane * 4, wo);
    }
    __syncthreads();

    {
        const int rg = wave >> 1, csl = wave & 1;
        f32x4 acc[2][8] = {};
        const short8* wb = (const short8*)WaF;
        for (int ks = 0; ks < 8; ++ks) {
            short8 a0 = C8R(rg * 32 + lr, ks * 32 + lk * 8);
            short8 a1 = C8R(rg * 32 + 16 + lr, ks * 32 + lk * 8);
#pragma unroll
            for (int nt2 = 0; nt2 < 8; ++nt2) {
                short8 bf = wb[(size_t)(ks * 16 + csl * 8 + nt2) * 64 + lane];
                acc[0][nt2] = __builtin_amdgcn_mfma_f32_16x16x32_bf16(a0, bf, acc[0][nt2], 0, 0, 0);
                acc[1][nt2] = __builtin_amdgcn_mfma_f32_16x16x32_bf16(a1, bf, acc[1][nt2], 0, 0, 0);
            }
        }
#pragma unroll
        for (int rt = 0; rt < 2; ++rt)
#pragma unroll
        for (int nt2 = 0; nt2 < 8; ++nt2) {
            int col = csl * 128 + nt2 * 16 + lr;
            float abv = atb[col];
#pragma unroll
            for (int q = 0; q < 4; ++q) {
                int row = rg * 32 + rt * 16 + lk * 4 + q;
                float v = acc[rt][nt2][q] + swS[row] * abv;
                ctx_out[((size_t)b * LL + row) * FP + col] = f2bf(fmaxf(v, 0.f));
            }
        }
    }
#undef SLAB_OFF
#undef A4R
#undef C8R
#undef CW4
}

// ---------- fused attention+ctx for d>0: single-pass (nf in regs) ----------
__global__ __launch_bounds__(512) void k_actx(int d,
        const short* __restrict__ ACTB,
        const int* __restrict__ adeg,
        const float* __restrict__ alW, const float* __restrict__ alb,
        const short* __restrict__ WaF, const float* __restrict__ atb,
        short* __restrict__ ctx_out, float* __restrict__ awv_out) {
    __shared__ __align__(16) short aS[32768];     // 64 KB act slab (swizzled)
    __shared__ __align__(16) short cS[32768];     // 64 KB wn slab (swizzled)
    __shared__ int   jxS[LL * KK];
    __shared__ float swS[LL];

    const int b = blockIdx.x;
    const int t = threadIdx.x;
    const int wave = t >> 6, lane = t & 63;
    const int lr = lane & 15, lk = lane >> 4;

#define SLAB_OFF(r, cb) ((((r) * 512 + (cb))) ^ ((((r) & 7)) << 4))
#define A4R(r, c)  (*(const short4v*)((const char*)aS + SLAB_OFF(r, (c) * 2)))
#define C8R(r, c)  (*(const short8*)((const char*)cS + SLAB_OFF(r, (c) * 2)))
#define CW4(r, c, v) (*(short4v*)((char*)cS + SLAB_OFF(r, (c) * 2)) = (v))

    {
        const char* src = (const char*)(ACTB + (size_t)b * LL * FP);
#pragma unroll
        for (int it = 0; it < 8; ++it) {
            int off = it * 8192 + wave * 1024 + lane * 16;
            int so = off ^ (((off >> 9) & 7) << 4);
            GLL(src + so, (char*)aS + off);
        }
        for (int i = t; i < LL * KK; i += 512) jxS[i] = adeg[b * LL * KK + i];
    }

    f32x4 w0 = *(const f32x4*)(alW + (size_t)d * 2 * FP + lane * 4);
    f32x4 w1 = *(const f32x4*)(alW + (size_t)d * 2 * FP + FP + lane * 4);
    float bias = alb[d];
    __syncthreads();

    for (int ai = 0; ai < 16; ++ai) {
        const int a = wave * 16 + ai;
        const int ga = b * LL + a;

        short4v sv = A4R(a, lane * 4);
        float ss = wred64(bf2f(sv[0]) * w0[0] + bf2f(sv[1]) * w0[1] +
                          bf2f(sv[2]) * w0[2] + bf2f(sv[3]) * w0[3]);

        int jx[KK];
#pragma unroll
        for (int k = 0; k < KK; ++k) jx[k] = jxS[a * KK + k];

        float nf[KK][4];
        float sc[KK];
#pragma unroll
        for (int k = 0; k < KK; ++k) {
            short4v nv = A4R(jx[k], lane * 4);
            nf[k][0] = bf2f(nv[0]); nf[k][1] = bf2f(nv[1]);
            nf[k][2] = bf2f(nv[2]); nf[k][3] = bf2f(nv[3]);
            float s2 = wred64(nf[k][0] * w1[0] + nf[k][1] * w1[1] +
                              nf[k][2] * w1[2] + nf[k][3] * w1[3]);
            float s = fmaxf(ss + s2 + bias, 0.f);
            if (jx[k] == LL - 1) s -= 9.0f;
            sc[k] = s;
        }

        float m = sc[0];
#pragma unroll
        for (int k = 1; k < KK; ++k) m = fmaxf(m, sc[k]);
        float e[KK], den = 0.f;
#pragma unroll
        for (int k = 0; k < KK; ++k) { e[k] = expf(sc[k] - m); den += e[k]; }
        float aw[KK], sumaw = 0.f;
#pragma unroll
        for (int k = 0; k < KK; ++k) {
            aw[k] = (jx[k] == LL - 1) ? 0.f : e[k] / den;
            sumaw += aw[k];
        }
        if (lane < KK) {
            float av = aw[0];
#pragma unroll
            for (int k = 1; k < KK; ++k) if (lane == k) av = aw[k];
            awv_out[(size_t)ga * KK + lane] = av;
        }
        if (lane == 0) swS[a] = sumaw;

        short4v wo;
#pragma unroll
        for (int q = 0; q < 4; ++q) {
            float w = 0.f;
#pragma unroll
            for (int k = 0; k < KK; ++k) w += aw[k] * nf[k][q];
            wo[q] = f2bf(w);
        }
        CW4(a, lane * 4, wo);
    }
    __syncthreads();

    {
        const int rg = wave >> 1, csl = wave & 1;
        f32x4 acc[2][8] = {};
        const short8* wb = (const short8*)(WaF + (size_t)d * 8 * 16 * 512);
        for (int ks = 0; ks < 8; ++ks) {
            short8 a0 = C8R(rg * 32 + lr, ks * 32 + lk * 8);
            short8 a1 = C8R(rg * 32 + 16 + lr, ks * 32 + lk * 8);
#pragma unroll
            for (int nt2 = 0; nt2 < 8; ++nt2) {
                short8 bf = wb[(size_t)(ks * 16 + csl * 8 + nt2) * 64 + lane];
                acc[0][nt2] = __builtin_amdgcn_mfma_f32_16x16x32_bf16(a0, bf, acc[0][nt2], 0, 0, 0);
                acc[1][nt2] = __builtin_amdgcn_mfma_f32_16x16x32_bf16(a1, bf, acc[1][nt2], 0, 0, 0);
            }
        }
#pragma unroll
        for (int rt = 0; rt < 2; ++rt)
#pragma unroll
        for (int nt2 = 0; nt2 < 8; ++nt2) {
            int col = csl * 128 + nt2 * 16 + lr;
            float abv = atb[d * FP + col];
#pragma unroll
            for (int q = 0; q < 4; ++q) {
                int row = rg * 32 + rt * 16 + lk * 4 + q;
                float v = acc[rt][nt2][q] + swS[row] * abv;
                ctx_out[((size_t)b * LL + row) * FP + col] = f2bf(fmaxf(v, 0.f));
            }
        }
    }
#undef SLAB_OFF
#undef A4R
#undef C8R
#undef CW4
}

// ---------------- fused MFMA GRU v7: counted-vmcnt + 2 blocks/CU ----------------
// ldsA removed (72 KB LDS): A-fragments read from global (L2-hot, rounds 8-9
// validated); h_old from global HBl bf16. Co-resident block hides barrier waits.
template<int LAST>
__global__ __launch_bounds__(512) void k_gru_mfma(
        const short* __restrict__ XB,     // ctx bf16
        const short* __restrict__ HBl,    // h bf16 (read)
        float* __restrict__ hbuf,         // h fp32 (written only when LAST)
        const short* __restrict__ Bih,    // frag-major (8,48,64,8)
        const short* __restrict__ Bhh,
        const float* __restrict__ bih, const float* __restrict__ bhh,
        float* __restrict__ act_out,
        short* __restrict__ HB_out,
        short* __restrict__ ACT_out) {
    __shared__ short ldsB[3][12288];      // 3 x 24 KB = 72 KB -> 2 blocks/CU
    const int t = threadIdx.x;
    const int wave = t >> 6, lane = t & 63;
    const int rh = wave >> 2;
    const int wn = wave & 3;
    const int lr = lane & 15, lk = lane >> 4;
    const int bid = blockIdx.x;
    const int kofs = bid & 7;
    const int abase = bid * 64;

#define PKS(p)  ((((p) >> 2) + kofs) & 7)
#define STAGEP(p) do { \
        const short* base_ = ((((p) >> 1) & 1) ? Bhh : Bih) + (size_t)PKS(p) * 24576; \
        const int h_ = (p) & 1; \
        _Pragma("unroll") \
        for (int e = 0; e < 3; ++e) { \
            int j = wave * 3 + e; \
            int nt = 4 * (j >> 1) + 2 * h_ + (j & 1); \
            GLL(base_ + nt * 512 + lane * 8, &ldsB[(p) % 3][j * 512]); \
        } } while (0)

    const short8* xrow0 = (const short8*)(XB + (size_t)(abase + rh * 32 + lr) * FP);
    const short8* hrow0 = (const short8*)(HBl + (size_t)(abase + rh * 32 + lr) * FP);
    const short8* xrow1 = (const short8*)(XB + (size_t)(abase + rh * 32 + 16 + lr) * FP);
    const short8* hrow1 = (const short8*)(HBl + (size_t)(abase + rh * 32 + 16 + lr) * FP);

    STAGEP(0);
    STAGEP(1);

    f32x4 acc_rz[2][8] = {};
    f32x4 acc_in[2][4] = {};
    f32x4 acc_hn[2][4] = {};

    short8 ax0{}, ah0{}, ax1{}, ah1{};
#pragma unroll
    for (int p = 0; p < 32; ++p) {
        if (p < 31) { asm volatile("s_waitcnt vmcnt(3)" ::: "memory"); }
        else        { asm volatile("s_waitcnt vmcnt(0)" ::: "memory"); }
        __builtin_amdgcn_s_barrier();
        __builtin_amdgcn_sched_barrier(0);
        const int h_ = p & 1;
        const int mat = (p >> 1) & 1;
        if ((p & 3) == 0) {
            // A-loads BEFORE next STAGEP so the compiler's wait for them
            // (vmcnt ~= #STAGEP loads behind) never drains the B pipeline.
            int ks = PKS(p);
            ax0 = xrow0[ks * 4 + lk];
            ah0 = hrow0[ks * 4 + lk];
            ax1 = xrow1[ks * 4 + lk];
            ah1 = hrow1[ks * 4 + lk];
            __builtin_amdgcn_sched_barrier(0);
        }
        if (p < 30) STAGEP(p + 2);
#pragma unroll
        for (int rg = 0; rg < 2; ++rg) {
            const short8 a8 = mat ? (rg ? ah1 : ah0) : (rg ? ax1 : ax0);
#pragma unroll
            for (int g = 0; g < 3; ++g) {
#pragma unroll
                for (int s2 = 0; s2 < 2; ++s2) {
                    const int sub = 2 * h_ + s2;
                    const int j = ((4 * g + wn) << 1) | s2;
                    short8 bf = *(const short8*)(&ldsB[p % 3][j * 512 + lane * 8]);
                    if (g < 2)
                        acc_rz[rg][g * 4 + sub] = __builtin_amdgcn_mfma_f32_16x16x32_bf16(a8, bf, acc_rz[rg][g * 4 + sub], 0, 0, 0);
                    else if (mat)
                        acc_hn[rg][sub] = __builtin_amdgcn_mfma_f32_16x16x32_bf16(a8, bf, acc_hn[rg][sub], 0, 0, 0);
                    else
                        acc_in[rg][sub] = __builtin_amdgcn_mfma_f32_16x16x32_bf16(a8, bf, acc_in[rg][sub], 0, 0, 0);
                }
            }
        }
    }
#undef STAGEP
#undef PKS
    __syncthreads();   // all global XB/HBl loop reads done before HB_out writes

#pragma unroll
    for (int sub = 0; sub < 4; ++sub) {
        int c = wn * 64 + sub * 16 + lr;
        float brz_r = bih[c] + bhh[c];
        float brz_z = bih[FP + c] + bhh[FP + c];
        float bin_ = bih[2 * FP + c];
        float bhn = bhh[2 * FP + c];
#pragma unroll
        for (int rg = 0; rg < 2; ++rg) {
#pragma unroll
            for (int q = 0; q < 4; ++q) {
                int row = rh * 32 + rg * 16 + lk * 4 + q;
                int atom = abase + row;
                size_t idx = (size_t)atom * FP + c;
                float hold = bf2f(HBl[idx]);
                float r = 1.f / (1.f + expf(-(acc_rz[rg][0 * 4 + sub][q] + brz_r)));
                float z = 1.f / (1.f + expf(-(acc_rz[rg][1 * 4 + sub][q] + brz_z)));
                float n = tanhf(acc_in[rg][sub][q] + bin_ + r * (acc_hn[rg][sub][q] + bhn));
                float hn = (1.f - z) * n + z * hold;
                float rl = fmaxf(hn, 0.f);
                act_out[idx] = rl;
                if constexpr (LAST) {
                    hbuf[idx] = hn;
                } else {
                    HB_out[idx] = f2bf(hn);
                    ACT_out[idx] = f2bf(rl);
                }
            }
        }
    }
}

// ---------------- fused mol reduce + step-0 mstep ----------------
__global__ __launch_bounds__(256) void k_mol_head(
        const float* __restrict__ hbuf, const float* __restrict__ act,
        const float* __restrict__ mask,
        const float* __restrict__ malW, const float* __restrict__ malb,
        const float* __restrict__ MWaT, const float* __restrict__ matb,
        float* __restrict__ o_unb0, float* __restrict__ o_mfv0,
        float* __restrict__ molF, short* __restrict__ MOLFb,
        float* __restrict__ S2g,
        short* __restrict__ MCTXb, float* __restrict__ o_mawv) {
    int b = blockIdx.x, t = threadIdx.x;
    int wave = t >> 6, lane = t & 63;
    __shared__ float sS2[LL], sS[LL], mwS[LL], waS[FP];
    __shared__ float red[4];

    float s1 = 0.f, s2 = 0.f;
    for (int l = 0; l < LL; ++l) {
        float mk = mask[b * LL + l];
        s1 += hbuf[((size_t)b * LL + l) * FP + t] * mk;
        s2 += act[((size_t)b * LL + l) * FP + t] * mk;
    }
    o_unb0[b * FP + t] = s1;
    o_mfv0[b * FP + t] = s2;
    molF[b * FP + t] = s2;
    MOLFb[b * FP + t] = f2bf(s2);

    for (int l = wave; l < LL; l += 4) {
        float v2 = 0.f;
#pragma unroll
        for (int q = 0; q < 4; ++q) {
            int i = lane + 64 * q;
            v2 += act[((size_t)b * LL + l) * FP + i] * malW[FP + i];
        }
        v2 = wred64(v2);
        if (lane == 0) { sS2[l] = v2; S2g[b * LL + l] = v2; }
    }

    float am = fmaxf(s2, 0.f);
    float v = am * malW[t];
    v = wred64(v);
    if (lane == 0) red[wave] = v;
    __syncthreads();
    float s_self = red[0] + red[1] + red[2] + red[3];

    if (t < LL) {
        float s = fmaxf(s_self + sS2[t] + malb[0], 0.f);
        if (mask[b * LL + t] == 0.f) s += -9e8f;
        sS[t] = s;
    }
    __syncthreads();

    float m = -1e30f;
    for (int l = 0; l < LL; ++l) m = fmaxf(m, sS[l]);
    float den = 0.f;
    for (int l = 0; l < LL; ++l) den += expf(sS[l] - m);
    if (t < LL) {
        float w = expf(sS[t] - m) / den * mask[b * LL + t];
        mwS[t] = w;
        o_mawv[b * LL + t] = w;   // step 0
    }
    __syncthreads();

    float sumaw = 0.f;
    for (int l = 0; l < LL; ++l) sumaw += mwS[l];

    float wa = 0.f;
    for (int l = 0; l < LL; ++l) wa += mwS[l] * act[((size_t)b * LL + l) * FP + t];
    waS[t] = wa;
    __syncthreads();

    float acc = sumaw * matb[t];
    for (int i = 0; i < FP; ++i) acc += waS[i] * MWaT[i * FP + t];
    MCTXb[b * FP + t] = f2bf(fmaxf(acc, 0.f));
}

// ---------------- mol step (step>=1) ----------------
__global__ __launch_bounds__(256) void k_mstep(int step,
        const float* __restrict__ act,
        const float* __restrict__ molF,
        const float* __restrict__ mask,
        const float* __restrict__ S2g,
        const float* __restrict__ malW, const float* __restrict__ malb,
        const float* __restrict__ MWaT, const float* __restrict__ matb,
        short* __restrict__ MCTXb,
        float* __restrict__ o_mawv) {
    int b = blockIdx.x, t = threadIdx.x;
    int wave = t >> 6, lane = t & 63;
    __shared__ float sS[LL], mwS[LL], waS[FP];
    __shared__ float red[4];

    float hprev = molF[b * FP + t];
    float am = fmaxf(hprev, 0.f);

    float v = am * malW[t];
    v = wred64(v);
    if (lane == 0) red[wave] = v;
    __syncthreads();
    float s_self = red[0] + red[1] + red[2] + red[3];

    if (t < LL) {
        float s = fmaxf(s_self + S2g[b * LL + t] + malb[0], 0.f);
        if (mask[b * LL + t] == 0.f) s += -9e8f;
        sS[t] = s;
    }
    __syncthreads();

    float m = -1e30f;
    for (int l = 0; l < LL; ++l) m = fmaxf(m, sS[l]);
    float den = 0.f;
    for (int l = 0; l < LL; ++l) den += expf(sS[l] - m);
    if (t < LL) {
        float w = expf(sS[t] - m) / den * mask[b * LL + t];
        mwS[t] = w;
        o_mawv[(size_t)step * (BB * LL) + b * LL + t] = w;
    }
    __syncthreads();

    float sumaw = 0.f;
    for (int l = 0; l < LL; ++l) sumaw += mwS[l];

    float wa = 0.f;
    for (int l = 0; l < LL; ++l) wa += mwS[l] * act[((size_t)b * LL + l) * FP + t];
    waS[t] = wa;
    __syncthreads();

    float acc = sumaw * matb[t];
    for (int i = 0; i < FP; ++i) acc += waS[i] * MWaT[i * FP + t];
    MCTXb[b * FP + t] = f2bf(fmaxf(acc, 0.f));
}

// ---------------- mol GRU as 256-row MFMA GEMM (4 blocks x 64 rows) ----------
__global__ __launch_bounds__(512) void k_mol_gru(int step,
        const short* __restrict__ XB,     // mctx bf16 (256,FP)
        const short* __restrict__ HBl,    // molF bf16
        const short* __restrict__ Bih,    // frag-major (8,48,64,8)
        const short* __restrict__ Bhh,
        const float* __restrict__ bih, const float* __restrict__ bhh,
        float* __restrict__ o_unb, float* __restrict__ o_mfv,
        float* __restrict__ molF, short* __restrict__ MOLFb,
        float* __restrict__ o_molfeat) {
    __shared__ short ldsB[3][12288];
    const int t = threadIdx.x;
    const int wave = t >> 6, lane = t & 63;
    const int rh = wave >> 2;
    const int wn = wave & 3;
    const int lr = lane & 15, lk = lane >> 4;
    const int bid = blockIdx.x;
    const int kofs = bid & 7;
    const int abase = bid * 64;

#define PKS(p)  ((((p) >> 2) + kofs) & 7)
#define STAGEP(p) do { \
        const short* base_ = ((((p) >> 1) & 1) ? Bhh : Bih) + (size_t)PKS(p) * 24576; \
        const int h_ = (p) & 1; \
        _Pragma("unroll") \
        for (int e = 0; e < 3; ++e) { \
            int j = wave * 3 + e; \
            int nt = 4 * (j >> 1) + 2 * h_ + (j & 1); \
            GLL(base_ + nt * 512 + lane * 8, &ldsB[(p) % 3][j * 512]); \
        } } while (0)

    const short8* xrow0 = (const short8*)(XB + (size_t)(abase + rh * 32 + lr) * FP);
    const short8* hrow0 = (const short8*)(HBl + (size_t)(abase + rh * 32 + lr) * FP);
    const short8* xrow1 = (const short8*)(XB + (size_t)(abase + rh * 32 + 16 + lr) * FP);
    const short8* hrow1 = (const short8*)(HBl + (size_t)(abase + rh * 32 + 16 + lr) * FP);

    STAGEP(0);
    STAGEP(1);

    f32x4 acc_rz[2][8] = {};
    f32x4 acc_in[2][4] = {};
    f32x4 acc_hn[2][4] = {};

    short8 ax0{}, ah0{}, ax1{}, ah1{};
#pragma unroll
    for (int p = 0; p < 32; ++p) {
        if (p < 31) { asm volatile("s_waitcnt vmcnt(3)" ::: "memory"); }
        else        { asm volatile("s_waitcnt vmcnt(0)" ::: "memory"); }
        __builtin_amdgcn_s_barrier();
        __builtin_amdgcn_sched_barrier(0);
        const int h_ = p & 1;
        const int mat = (p >> 1) & 1;
        if ((p & 3) == 0) {
            int ks = PKS(p);
            ax0 = xrow0[ks * 4 + lk];
            ah0 = hrow0[ks * 4 + lk];
            ax1 = xrow1[ks * 4 + lk];
            ah1 = hrow1[ks * 4 + lk];
            __builtin_amdgcn_sched_barrier(0);
        }
        if (p < 30) STAGEP(p + 2);
#pragma unroll
        for (int rg = 0; rg < 2; ++rg) {
            const short8 a8 = mat ? (rg ? ah1 : ah0) : (rg ? ax1 : ax0);
#pragma unroll
            for (int g = 0; g < 3; ++g) {
#pragma unroll
                for (int s2 = 0; s2 < 2; ++s2) {
                    const int sub = 2 * h_ + s2;
                    const int j = ((4 * g + wn) << 1) | s2;
                    short8 bf = *(const short8*)(&ldsB[p % 3][j * 512 + lane * 8]);
                    if (g < 2)
                        acc_rz[rg][g * 4 + sub] = __builtin_amdgcn_mfma_f32_16x16x32_bf16(a8, bf, acc_rz[rg][g * 4 + sub], 0, 0, 0);
                    else if (mat)
                        acc_hn[rg][sub] = __builtin_amdgcn_mfma_f32_16x16x32_bf16(a8, bf, acc_hn[rg][sub], 0, 0, 0);
                    else
                        acc_in[rg][sub] = __builtin_amdgcn_mfma_f32_16x16x32_bf16(a8, bf, acc_in[rg][sub], 0, 0, 0);
                }
            }
        }
    }
#undef STAGEP
#undef PKS
    __syncthreads();   // loop reads of HBl done before MOLFb writes

#pragma unroll
    for (int sub = 0; sub < 4; ++sub) {
        int c = wn * 64 + sub * 16 + lr;
        float brz_r = bih[c] + bhh[c];
        float brz_z = bih[FP + c] + bhh[FP + c];
        float bin_ = bih[2 * FP + c];
        float bhn = bhh[2 * FP + c];
#pragma unroll
        for (int rg = 0; rg < 2; ++rg) {
#pragma unroll
            for (int q = 0; q < 4; ++q) {
                int row = rh * 32 + rg * 16 + lk * 4 + q;
                int m = abase + row;                     // molecule index
                size_t idx = (size_t)m * FP + c;
                float hold = bf2f(HBl[idx]);
                float r = 1.f / (1.f + expf(-(acc_rz[rg][0 * 4 + sub][q] + brz_r)));
                float z = 1.f / (1.f + expf(-(acc_rz[rg][1 * 4 + sub][q] + brz_z)));
                float n = tanhf(acc_in[rg][sub][q] + bin_ + r * (acc_hn[rg][sub][q] + bhn));
                float hn = (1.f - z) * n + z * hold;
                o_unb[(size_t)(step + 1) * (BB * FP) + idx] = hn;
                o_mfv[(size_t)(step + 1) * (BB * FP) + idx] = fmaxf(hn, 0.f);
                molF[idx] = hn;
                MOLFb[idx] = f2bf(hn);
                if (step == TT - 1) o_molfeat[idx] = hn;
            }
        }
    }
}

extern "C" void kernel_launch(void* const* d_in, const int* in_sizes, int n_in,
                              void* d_out, int out_size, void* d_ws, size_t ws_size,
                              hipStream_t stream) {
    const float* atom_list = (const float*)d_in[0];
    const float* bond_list = (const float*)d_in[1];
    const int*   adeg      = (const int*)d_in[2];
    const int*   bdeg      = (const int*)d_in[3];
    const float* amask     = (const float*)d_in[4];
    const float* atom_fc_W = (const float*)d_in[5];
    const float* atom_fc_b = (const float*)d_in[6];
    const float* nfc_W     = (const float*)d_in[7];
    const float* nfc_b     = (const float*)d_in[8];
    const float* gwih      = (const float*)d_in[9];
    const float* gwhh      = (const float*)d_in[10];
    const float* gbih      = (const float*)d_in[11];
    const float* gbhh      = (const float*)d_in[12];
    const float* alW       = (const float*)d_in[13];
    const float* alb       = (const float*)d_in[14];
    const float* atW       = (const float*)d_in[15];
    const float* atb       = (const float*)d_in[16];
    const float* mgwih     = (const float*)d_in[17];
    const float* mgwhh     = (const float*)d_in[18];
    const float* mgbih     = (const float*)d_in[19];
    const float* mgbhh     = (const float*)d_in[20];
    const float* malW      = (const float*)d_in[21];
    const float* malb      = (const float*)d_in[22];
    const float* matW      = (const float*)d_in[23];
    const float* matb      = (const float*)d_in[24];

    const size_t BLF = (size_t)BB * LL * FP;
    float* out = (float*)d_out;
    float* O0 = out;                                 // atom_feature / h (fp32)
    float* O1 = out + BLF;                           // afv (4,B,L,FP)
    float* O2 = O1 + 4 * BLF;                        // awv (3,B,L,K)
    float* O3 = O2 + (size_t)RR * BB * LL * KK;      // mfv
    float* O4 = O3 + (size_t)(TT + 1) * BB * FP;     // mol_unb
    float* O5 = O4 + (size_t)(TT + 1) * BB * FP;     // mawv
    float* O6 = O5 + (size_t)TT * BB * LL;           // mol_feature

    // ws layout
    float* ws = (float*)d_ws;
    short* XB   = (short*)ws;                        // (spare)
    short* XB2  = XB + BLF;                          // BLF shorts: ctx bf16
    short* HBb  = XB + 2 * BLF;                      // BLF shorts: h bf16
    short* ACTB = XB + 3 * BLF;                      // BLF shorts: relu(h) bf16
    float* rest = ws + 2 * BLF;
    short* ApreB = (short*)rest;                     // BLF shorts
    float* SW    = rest + BLF / 2;                   // (unused, kept for layout)
    float* MOLF  = SW + (size_t)BB * LL;
    float* WafcT = MOLF + (size_t)BB * FP;
    float* WnT   = WafcT + AA * FP;
    float* MWaT  = WnT + (AA + BDD) * FP;
    short* MolGW = (short*)(MWaT + (size_t)FP * FP);    // 2*(8*48*512) shorts
    short* GW    = MolGW + (size_t)2 * 8 * 48 * 512;    // RR*2*(8*48*512) shorts
    short* WaF   = GW + (size_t)RR * 2 * 8 * 48 * 512;  // RR*(8*16*512) shorts
    short* MCTXb = WaF + (size_t)RR * 8 * 16 * 512;     // BB*FP shorts
    short* MOLFb = MCTXb + (size_t)BB * FP;             // BB*FP shorts
    float* S2g   = (float*)(MOLFb + (size_t)BB * FP);   // BB*LL floats
    (void)ws_size; (void)in_sizes; (void)n_in; (void)out_size;

    {
        int nT = FP * AA + FP * (AA + BDD) + FP * FP;
        k_prep_trans<<<(nT + 255) / 256, 256, 0, stream>>>(atom_fc_W, nfc_W, matW,
                                                           WafcT, WnT, MWaT);
        int nP = RR * 2 * 8 * 48 * 512 + RR * 8 * 16 * 512 + 2 * 8 * 48 * 512;
        k_prep_pack<<<(nP + 255) / 256, 256, 0, stream>>>(gwih, gwhh, atW,
                                                          mgwih, mgwhh, GW, WaF, MolGW);
    }

    k_atom_pre<<<BB * LL / 8, 256, 0, stream>>>(atom_list, WafcT, atom_fc_b,
                                                WnT, nfc_b, O1, HBb, ApreB);

    const size_t wblk = (size_t)8 * 48 * 512;
    for (int d = 0; d < RR; ++d) {
        if (d == 0) {
            k_actx_d0<<<BB, 512, 0, stream>>>(HBb, ApreB, bond_list, adeg, bdeg,
                    WnT, alW, alb, WaF, atb, XB2, O2);
        } else {
            k_actx<<<BB, 512, 0, stream>>>(d, ACTB, adeg,
                    alW, alb, WaF, atb,
                    XB2, O2 + (size_t)d * BB * LL * KK);
        }
        if (d == RR - 1) {
            k_gru_mfma<1><<<BB * LL / 64, 512, 0, stream>>>(XB2, HBb, O0,
                    GW + (size_t)(d * 2 + 0) * wblk, GW + (size_t)(d * 2 + 1) * wblk,
                    gbih + (size_t)d * 768, gbhh + (size_t)d * 768,
                    O1 + (size_t)(d + 1) * BLF, HBb, ACTB);
        } else {
            k_gru_mfma<0><<<BB * LL / 64, 512, 0, stream>>>(XB2, HBb, O0,
                    GW + (size_t)(d * 2 + 0) * wblk, GW + (size_t)(d * 2 + 1) * wblk,
                    gbih + (size_t)d * 768, gbhh + (size_t)d * 768,
                    O1 + (size_t)(d + 1) * BLF, HBb, ACTB);
        }
    }

    const float* actFin = O1 + (size_t)RR * BLF;
    k_mol_head<<<BB, 256, 0, stream>>>(O0, actFin, amask, malW, malb, MWaT, matb,
                                       O4, O3, MOLF, MOLFb, S2g, MCTXb, O5);
    k_mol_gru<<<4, 512, 0, stream>>>(0, MCTXb, MOLFb,
            MolGW, MolGW + wblk, mgbih, mgbhh,
            O4, O3, MOLF, MOLFb, O6);
    k_mstep<<<BB, 256, 0, stream>>>(1, actFin, MOLF, amask, S2g,
            malW, malb, MWaT, matb, MCTXb, O5);
    k_mol_gru<<<4, 512, 0, stream>>>(1, MCTXb, MOLFb,
            MolGW, MolGW + wblk, mgbih, mgbhh,
            O4, O3, MOLF, MOLFb, O6);
}